// Round 1
// baseline (2848.512 us; speedup 1.0000x reference)
//
#include <hip/hip_runtime.h>
#include <math.h>

#define BN 16384

// ---------------- workspace float offsets ----------------
#define WKA_OFF   0
#define WVA_OFF   8192
#define WKE_OFF   16384
#define WVE_OFF   24576
#define WKEF_OFF  32768
#define BKA_OFF   40960
#define BVA_OFF   41216
#define BKE_OFF   41472
#define BVE_OFF   41728
#define BKEF_OFF  41984
#define WMP_OFF   43008
#define BMP_OFF   44544
#define G_OFF     45056
#define BG_OFF    53248
#define WQB_OFF   53312
#define SC0_OFF   53568

#define QSRC_OFF  65536
#define BUF1_OFF  (QSRC_OFF + BN*256)
#define BUF2_OFF  (BUF1_OFF + BN*256)
#define BUF3_OFF  (BUF2_OFF + BN*256)
#define BUF4_OFF  (BUF3_OFF + BN*256)
#define BUF5_OFF  (BUF4_OFF + BN*256)

#define QHA_OFF   BUF1_OFF
#define QHE_OFF   BUF2_OFF
#define ZRAWA_OFF BUF3_OFF
#define ZRAWE_OFF BUF4_OFF
#define AOUTA_OFF BUF1_OFF
#define AOUTE_OFF BUF2_OFF
#define ZA_OFF    BUF3_OFF
#define ZE_OFF    BUF4_OFF
#define GBA_OFF   BUF5_OFF
#define GBE_OFF   (BUF5_OFF + BN*512)
#define U_OFF     BUF5_OFF
#define GI_OFF    BUF1_OFF            // spans BUF1..BUF3 (3*BN*256 = BN*768)
#define GH_OFF    BUF5_OFF            // overwrites u after gi consumed

#define HOFF      (BN*22)             // h output offset inside d_out

// ---------------- fused small-weight precompute ----------------
// WkA = attnA_W[1] @ W_ally   (256x32), bkA = attnA_W[1]@b_ally + attnA_b[1], etc.
__global__ __launch_bounds__(256) void k_fuse1(
    const float* __restrict__ attnA_W, const float* __restrict__ attnA_b,
    const float* __restrict__ attnE_W, const float* __restrict__ attnE_b,
    const float* __restrict__ W_ally,  const float* __restrict__ b_ally,
    const float* __restrict__ W_enemy, const float* __restrict__ b_enemy,
    const float* __restrict__ Wke,     const float* __restrict__ bke,
    float* __restrict__ FW) {
  int g = blockIdx.x * 256 + threadIdx.x;   // 5*8192 = 40960 items
  if (g >= 40960) return;
  int m = g >> 13;
  int r = g & 8191;
  int d = r >> 5, j = r & 31;
  const float *Wout, *Win, *bin, *bout; float *dst, *dstb;
  switch (m) {
    case 0: Wout = attnA_W + 65536;  Win = W_ally;  bin = b_ally;  bout = attnA_b + 256; dst = FW + WKA_OFF;  dstb = FW + BKA_OFF;  break;
    case 1: Wout = attnA_W + 131072; Win = W_ally;  bin = b_ally;  bout = attnA_b + 512; dst = FW + WVA_OFF;  dstb = FW + BVA_OFF;  break;
    case 2: Wout = attnE_W + 65536;  Win = W_enemy; bin = b_enemy; bout = attnE_b + 256; dst = FW + WKE_OFF;  dstb = FW + BKE_OFF;  break;
    case 3: Wout = attnE_W + 131072; Win = W_enemy; bin = b_enemy; bout = attnE_b + 512; dst = FW + WVE_OFF;  dstb = FW + BVE_OFF;  break;
    default:Wout = Wke;              Win = W_enemy; bin = b_enemy; bout = bke;           dst = FW + WKEF_OFF; dstb = FW + BKEF_OFF; break;
  }
  float acc = 0.f;
  for (int c = 0; c < 256; ++c) acc += Wout[d*256 + c] * Win[c*32 + j];
  dst[d*32 + j] = acc;
  if (j == 0) {
    float b = bout[d];
    for (int c = 0; c < 256; ++c) b += Wout[d*256 + c] * bin[c];
    dstb[d] = b;
  }
}

// second stage: folds that depend on WKe_f (and move-head fold)
__global__ __launch_bounds__(256) void k_fuse2(
    const float* __restrict__ protos, const float* __restrict__ Wmq,
    const float* __restrict__ bmq,    const float* __restrict__ Wqs,
    const float* __restrict__ bqs,    float* __restrict__ FW) {
  int g = blockIdx.x * 256 + threadIdx.x;   // 10023 items
  const float* WKe_f = FW + WKEF_OFF;
  const float* bKe_f = FW + BKEF_OFF;
  if (g < 1536) {                       // Wmp[i][c] = protos[i] . Wmq[:,c]
    int i = g >> 8, c = g & 255;
    float acc = 0.f;
    for (int d = 0; d < 256; ++d) acc += protos[i*256 + d] * Wmq[d*256 + c];
    FW[WMP_OFF + i*256 + c] = acc;
  } else if (g < 9728) {                // G[j][c] = sum_d WKe_f[d][j]*Wqs[d][c]
    int r = g - 1536;
    int j = r >> 8, c = r & 255;
    float acc = 0.f;
    for (int d = 0; d < 256; ++d) acc += WKe_f[d*32 + j] * Wqs[d*256 + c];
    FW[G_OFF + j*256 + c] = acc;
  } else if (g < 9984) {                // wqb[c] = sum_d Wqs[d][c]*bKe_f[d]
    int c = g - 9728;
    float acc = 0.f;
    for (int d = 0; d < 256; ++d) acc += Wqs[d*256 + c] * bKe_f[d];
    FW[WQB_OFF + c] = acc;
  } else if (g < 9990) {                // bmp[i] = protos[i].bmq
    int i = g - 9984;
    float acc = 0.f;
    for (int d = 0; d < 256; ++d) acc += protos[i*256 + d] * bmq[d];
    FW[BMP_OFF + i] = acc;
  } else if (g < 10022) {               // bg[j] = sum_d WKe_f[d][j]*bqs[d]
    int j = g - 9990;
    float acc = 0.f;
    for (int d = 0; d < 256; ++d) acc += WKe_f[d*32 + j] * bqs[d];
    FW[BG_OFF + j] = acc;
  } else if (g == 10022) {              // sc0 = bqs.bKe_f
    float acc = 0.f;
    for (int d = 0; d < 256; ++d) acc += bqs[d] * bKe_f[d];
    FW[SC0_OFF] = acc;
  }
}

// ---------------- generic dense: C[s][o] = bias[o] + A[s,:] . W[o,:] ----------------
// tile: 64 samples x 64 outputs per WG, 256 threads, 4x4 acc per thread
template<int K, int NOUT>
__global__ __launch_bounds__(256) void k_dense(
    const float* __restrict__ A, const float* __restrict__ W,
    const float* __restrict__ bias, float* __restrict__ C) {
  constexpr int KB = 32;
  constexpr int NCH = (K + KB - 1) / KB;
  __shared__ float As[64][36];
  const int tid = threadIdx.x;
  const int s0 = blockIdx.x * 64;
  const int o0 = blockIdx.y * 64;
  const int ox = (tid & 15) * 4;
  const int sy = (tid >> 4) * 4;
  float acc[4][4] = {};
  const float* Abase = A + (long)s0 * K;
  for (int ch = 0; ch < NCH; ++ch) {
    const int k0 = ch * KB;
    if (ch) __syncthreads();
    if constexpr ((K % 4) == 0) {
      #pragma unroll
      for (int r = 0; r < 2; ++r) {
        int f = tid + r * 256;
        int s = f >> 3, c = (f & 7) * 4;
        float4 v = *(const float4*)(Abase + (long)s * K + k0 + c);
        *(float4*)(&As[s][c]) = v;
      }
    } else {
      for (int idx = tid; idx < 64 * KB; idx += 256) {
        int s = idx >> 5, c = idx & 31;
        As[s][c] = (k0 + c < K) ? Abase[(long)s * K + k0 + c] : 0.f;
      }
    }
    __syncthreads();
    for (int kk = 0; kk < KB; kk += 4) {
      float a4[4][4];
      #pragma unroll
      for (int sj = 0; sj < 4; ++sj)
        *(float4*)a4[sj] = *(const float4*)&As[sy + sj][kk];
      #pragma unroll
      for (int oi = 0; oi < 4; ++oi) {
        float w4[4];
        if constexpr ((K % 4) == 0) {
          *(float4*)w4 = *(const float4*)&W[(long)(o0 + ox + oi) * K + k0 + kk];
        } else {
          #pragma unroll
          for (int kx = 0; kx < 4; ++kx) {
            int k = k0 + kk + kx;
            w4[kx] = (k < K) ? W[(long)(o0 + ox + oi) * K + k] : 0.f;
          }
        }
        #pragma unroll
        for (int sj = 0; sj < 4; ++sj)
          #pragma unroll
          for (int kx = 0; kx < 4; ++kx)
            acc[sj][oi] = fmaf(a4[sj][kx], w4[kx], acc[sj][oi]);
      }
    }
  }
  #pragma unroll
  for (int sj = 0; sj < 4; ++sj) {
    float4 o4;
    o4.x = acc[sj][0] + bias[o0 + ox + 0];
    o4.y = acc[sj][1] + bias[o0 + ox + 1];
    o4.z = acc[sj][2] + bias[o0 + ox + 2];
    o4.w = acc[sj][3] + bias[o0 + ox + 3];
    *(float4*)&C[(long)(s0 + sy + sj) * NOUT + o0 + ox] = o4;
  }
}

// ---------------- fused attention core (per-branch) ----------------
// computes z (pre-projection attention output) from qh + raw, using folded weights
__global__ __launch_bounds__(256) void k_core(
    const float* __restrict__ raw, const float* __restrict__ qh,
    const float* __restrict__ Wk, const float* __restrict__ bk,
    const float* __restrict__ Wv, const float* __restrict__ bv,
    const float* __restrict__ gt_w, const float* __restrict__ gt_b,
    int gidx, int N, float* __restrict__ zout) {
  __shared__ float ally[4][16][33];
  __shared__ float gbuf[4][4][32];
  __shared__ float pbuf[4][4][16];
  __shared__ float pal[4][4][32];
  __shared__ float qbk[4][4];
  __shared__ float mfv[4][16];
  const int tid = threadIdx.x;
  const int w = tid >> 6, l = tid & 63;
  const long s = (long)blockIdx.x * 4 + w;
  const int NR = N * 32;
  const float* rs = raw + s * NR;
  for (int i = l; i < NR; i += 64) ally[w][i >> 5][i & 31] = rs[i];
  __syncthreads();
  // mask + count + temperature
  bool valid = false;
  if (l < N) {
    #pragma unroll
    for (int j = 0; j < 32; ++j) valid |= (ally[w][l][j] != 0.f);
  }
  unsigned long long bal = __ballot(l < N && valid);
  float cnt = (float)__popcll(bal);
  float x = gt_w[gidx] * log1pf(cnt) + gt_b[gidx];
  float sp = fmaxf(x, 0.f) + log1pf(expf(-fabsf(x)));   // softplus
  float scale = 1.f / (8.f * (sp + 1.f));               // 1/(sqrt(DH)*temp)
  if (l < 16) mfv[w][l] = (l < N && valid) ? 1.f : 0.f;
  // fold g[h][j] = sum_d qh[h*64+d] * Wk[h*64+d][j]
  const float* qrow = qh + s * 256;
  #pragma unroll
  for (int rep = 0; rep < 2; ++rep) {
    int h = rep * 2 + (l >> 5);
    int j = l & 31;
    float acc = 0.f;
    for (int d = 0; d < 64; ++d)
      acc += qrow[h * 64 + d] * Wk[(h * 64 + d) * 32 + j];
    gbuf[w][h][j] = acc;
  }
  { // qbk[h] = qh_h . bk_h
    int h = l >> 4, i = l & 15;
    float acc = 0.f;
    #pragma unroll
    for (int t = 0; t < 4; ++t) {
      int d = h * 64 + i + t * 16;
      acc += qrow[d] * bk[d];
    }
    acc += __shfl_xor(acc, 8);
    acc += __shfl_xor(acc, 4);
    acc += __shfl_xor(acc, 2);
    acc += __shfl_xor(acc, 1);
    if (i == 0) qbk[w][h] = acc;
  }
  __syncthreads();
  { // scores + softmax over n within 16-lane groups
    int h = l >> 4, n = l & 15;
    float sv = -INFINITY;
    if (n < N && mfv[w][n] != 0.f) {
      float acc = 0.f;
      #pragma unroll
      for (int j = 0; j < 32; ++j) acc += gbuf[w][h][j] * ally[w][n][j];
      sv = (acc + qbk[w][h]) * scale;
    }
    float m = sv;
    m = fmaxf(m, __shfl_xor(m, 8));
    m = fmaxf(m, __shfl_xor(m, 4));
    m = fmaxf(m, __shfl_xor(m, 2));
    m = fmaxf(m, __shfl_xor(m, 1));
    float e = (sv == -INFINITY) ? 0.f : expf(sv - m);
    float su = e;
    su += __shfl_xor(su, 8);
    su += __shfl_xor(su, 4);
    su += __shfl_xor(su, 2);
    su += __shfl_xor(su, 1);
    pbuf[w][h][n] = e / su;
  }
  __syncthreads();
  #pragma unroll
  for (int rep = 0; rep < 2; ++rep) {  // pal[h][j] = sum_n p[h][n]*ally[n][j]
    int h = rep * 2 + (l >> 5);
    int j = l & 31;
    float acc = 0.f;
    for (int n = 0; n < N; ++n) acc += pbuf[w][h][n] * ally[w][n][j];
    pal[w][h][j] = acc;
  }
  __syncthreads();
  float* zrow = zout + s * 256;
  #pragma unroll
  for (int rep = 0; rep < 4; ++rep) {  // z[d] = bv[d] + Wv[d,:].pal[h(d)]
    int d = rep * 64 + l;
    float acc = bv[d];
    #pragma unroll
    for (int j = 0; j < 32; ++j) acc += Wv[d * 32 + j] * pal[w][rep][j];
    zrow[d] = acc;
  }
}

// ---------------- conditional layernorm ----------------
__global__ __launch_bounds__(256) void k_cln(
    const float* __restrict__ xin, const float* __restrict__ gb,
    float* __restrict__ out) {
  int w = threadIdx.x >> 6, l = threadIdx.x & 63;
  long s = (long)blockIdx.x * 4 + w;
  const float* xr = xin + s * 256;
  float v[4], sum = 0.f, ssq = 0.f;
  #pragma unroll
  for (int t = 0; t < 4; ++t) {
    v[t] = xr[l + t * 64];
    sum += v[t]; ssq += v[t] * v[t];
  }
  #pragma unroll
  for (int off = 32; off > 0; off >>= 1) {
    sum += __shfl_xor(sum, off);
    ssq += __shfl_xor(ssq, off);
  }
  float mu = sum * (1.f / 256.f);
  float var = ssq * (1.f / 256.f) - mu * mu;
  float rstd = rsqrtf(var + 1e-5f);
  const float* gbr = gb + s * 512;
  float* orow = out + s * 256;
  #pragma unroll
  for (int t = 0; t < 4; ++t) {
    int d = l + t * 64;
    orow[d] = (1.f + gbr[d]) * ((v[t] - mu) * rstd) + gbr[256 + d];
  }
}

// ---------------- LN over concat(q_src, zA, zE) -> u ----------------
__global__ __launch_bounds__(256) void k_ln3(
    const float* __restrict__ q, const float* __restrict__ zA,
    const float* __restrict__ zE, const float* __restrict__ g,
    const float* __restrict__ b, float* __restrict__ u) {
  int w = threadIdx.x >> 6, l = threadIdx.x & 63;
  long s = (long)blockIdx.x * 4 + w;
  float v[12], sum = 0.f, ssq = 0.f;
  #pragma unroll
  for (int t = 0; t < 12; ++t) {
    int i = l + t * 64;
    float val;
    if (i < 256)      val = q[s * 256 + i];
    else if (i < 512) val = zA[s * 256 + i - 256];
    else              val = zE[s * 256 + i - 512];
    v[t] = val; sum += val; ssq += val * val;
  }
  #pragma unroll
  for (int off = 32; off > 0; off >>= 1) {
    sum += __shfl_xor(sum, off);
    ssq += __shfl_xor(ssq, off);
  }
  float mu = sum * (1.f / 768.f);
  float var = ssq * (1.f / 768.f) - mu * mu;
  float rstd = rsqrtf(var + 1e-5f);
  #pragma unroll
  for (int t = 0; t < 12; ++t) {
    int i = l + t * 64;
    u[s * 768 + i] = (v[t] - mu) * rstd * g[i] + b[i];
  }
}

// ---------------- GRU elementwise combine ----------------
__global__ __launch_bounds__(256) void k_gru(
    const float* __restrict__ gi, const float* __restrict__ gh,
    const float* __restrict__ hid, float* __restrict__ hout) {
  long gidx = (long)blockIdx.x * 256 + threadIdx.x;
  long s = gidx >> 8; int d = gidx & 255;
  const float* gir = gi + s * 768;
  const float* ghr = gh + s * 768;
  float ir = gir[d], iz = gir[256 + d], inn = gir[512 + d];
  float hr = ghr[d], hz = ghr[256 + d], hn = ghr[512 + d];
  float r  = 1.f / (1.f + expf(-(ir + hr)));
  float zg = 1.f / (1.f + expf(-(iz + hz)));
  float n  = tanhf(inn + r * hn);
  hout[gidx] = (1.f - zg) * n + zg * hid[gidx];
}

// ---------------- Q heads ----------------
__global__ __launch_bounds__(256) void k_heads(
    const float* __restrict__ h, const float* __restrict__ eraw,
    const float* __restrict__ Wv_head, const float* __restrict__ bv_head,
    const float* __restrict__ Wtb, const float* __restrict__ btb,
    const float* __restrict__ log_tau, const float* __restrict__ FW,
    float* __restrict__ Qout) {
  __shared__ float hb[4][256];
  __shared__ float ob[4][48];
  int w = threadIdx.x >> 6, l = threadIdx.x & 63;
  long s = (long)blockIdx.x * 4 + w;
  const float* hr = h + s * 256;
  #pragma unroll
  for (int t = 0; t < 4; ++t) hb[w][l + t * 64] = hr[l + t * 64];
  __syncthreads();
  if (l < 42) {
    const float* wr; float b;
    if (l == 0)      { wr = Wv_head;                      b = bv_head[0]; }
    else if (l == 1) { wr = Wtb;                          b = btb[0]; }
    else if (l == 2) { wr = Wtb + 256;                    b = btb[1]; }
    else if (l < 9)  { wr = FW + WMP_OFF + (l - 3) * 256; b = FW[BMP_OFF + l - 3]; }
    else if (l < 41) { wr = FW + G_OFF + (l - 9) * 256;   b = FW[BG_OFF + l - 9]; }
    else             { wr = FW + WQB_OFF;                 b = FW[SC0_OFF]; }
    float acc = b;
    for (int c = 0; c < 256; ++c) acc += wr[c] * hb[w][c];
    ob[w][l] = acc;
  }
  __syncthreads();
  float itm = 1.f / (expf(log_tau[0]) + 1e-6f);
  float its = 1.f / (expf(log_tau[1]) + 1e-6f);
  float V = ob[w][0];
  if (l < 16) {                      // Q_shoot
    const float* er = eraw + s * 512 + l * 32;
    bool valid = false; float acc = 0.f;
    #pragma unroll
    for (int j = 0; j < 32; ++j) {
      float e = er[j];
      valid |= (e != 0.f);
      acc += ob[w][9 + j] * e;
    }
    float a = (acc + ob[w][41]) * 0.0625f;   // /sqrt(H)
    float sa = valid ? a : 0.f;
    float cv = valid ? 1.f : 0.f;
    #pragma unroll
    for (int off = 8; off > 0; off >>= 1) {
      sa += __shfl_xor(sa, off);
      cv += __shfl_xor(cv, off);
    }
    float me = sa / fmaxf(cv, 1.f);
    float qs = V + ob[w][2] + (valid ? (a - me) * its : -1e30f * its);
    Qout[s * 22 + 6 + l] = qs;
  } else if (l < 22) {               // Q_move
    int i = l - 16;
    float mean = 0.f;
    #pragma unroll
    for (int t = 0; t < 6; ++t) mean += ob[w][3 + t];
    mean *= (1.f / 6.f);
    float qm = V + ob[w][1] + (ob[w][3 + i] - mean) * 0.0625f * itm;
    Qout[s * 22 + i] = qm;
  }
}

// ---------------- launch ----------------
extern "C" void kernel_launch(void* const* d_in, const int* in_sizes, int n_in,
                              void* d_out, int out_size, void* d_ws, size_t ws_size,
                              hipStream_t stream) {
  const float* own_raw   = (const float*)d_in[0];
  const float* ally_raw  = (const float*)d_in[1];
  const float* enemy_raw = (const float*)d_in[2];
  const float* hidden    = (const float*)d_in[3];
  const float* W_own     = (const float*)d_in[4];
  const float* b_own     = (const float*)d_in[5];
  const float* W_ally    = (const float*)d_in[6];
  const float* b_ally    = (const float*)d_in[7];
  const float* W_enemy   = (const float*)d_in[8];
  const float* b_enemy   = (const float*)d_in[9];
  const float* gt_w      = (const float*)d_in[10];
  const float* gt_b      = (const float*)d_in[11];
  const float* attnA_W   = (const float*)d_in[12];
  const float* attnA_b   = (const float*)d_in[13];
  const float* attnE_W   = (const float*)d_in[14];
  const float* attnE_b   = (const float*)d_in[15];
  const float* clnA_W    = (const float*)d_in[16];
  const float* clnA_b    = (const float*)d_in[17];
  const float* clnE_W    = (const float*)d_in[18];
  const float* clnE_b    = (const float*)d_in[19];
  const float* ln3_g     = (const float*)d_in[20];
  const float* ln3_b     = (const float*)d_in[21];
  const float* gru_Wih   = (const float*)d_in[22];
  const float* gru_Whh   = (const float*)d_in[23];
  const float* gru_bih   = (const float*)d_in[24];
  const float* gru_bhh   = (const float*)d_in[25];
  const float* Wv_head   = (const float*)d_in[26];
  const float* bv_head   = (const float*)d_in[27];
  const float* Wtb       = (const float*)d_in[28];
  const float* btb       = (const float*)d_in[29];
  const float* log_tau   = (const float*)d_in[30];
  const float* Wmq       = (const float*)d_in[31];
  const float* bmq       = (const float*)d_in[32];
  const float* protos    = (const float*)d_in[33];
  const float* Wqs       = (const float*)d_in[34];
  const float* bqs       = (const float*)d_in[35];
  const float* Wke       = (const float*)d_in[36];
  const float* bke       = (const float*)d_in[37];

  float* ws  = (float*)d_ws;
  float* out = (float*)d_out;
  float* hout = out + HOFF;

  // 1. fused weight precompute
  k_fuse1<<<160, 256, 0, stream>>>(attnA_W, attnA_b, attnE_W, attnE_b,
                                   W_ally, b_ally, W_enemy, b_enemy, Wke, bke, ws);
  k_fuse2<<<40, 256, 0, stream>>>(protos, Wmq, bmq, Wqs, bqs, ws);

  // 2. q_src = own_raw @ W_own.T + b_own
  k_dense<30, 256><<<dim3(BN/64, 4), 256, 0, stream>>>(own_raw, W_own, b_own, ws + QSRC_OFF);

  // 3. qh for both branches; gamma/beta (cln) for both branches
  k_dense<256, 256><<<dim3(BN/64, 4), 256, 0, stream>>>(ws + QSRC_OFF, attnA_W, attnA_b, ws + QHA_OFF);
  k_dense<256, 256><<<dim3(BN/64, 4), 256, 0, stream>>>(ws + QSRC_OFF, attnE_W, attnE_b, ws + QHE_OFF);
  k_dense<256, 512><<<dim3(BN/64, 8), 256, 0, stream>>>(ws + QSRC_OFF, clnA_W, clnA_b, ws + GBA_OFF);
  k_dense<256, 512><<<dim3(BN/64, 8), 256, 0, stream>>>(ws + QSRC_OFF, clnE_W, clnE_b, ws + GBE_OFF);

  // 4. attention cores (folded)
  k_core<<<BN/4, 256, 0, stream>>>(ally_raw, ws + QHA_OFF, ws + WKA_OFF, ws + BKA_OFF,
                                   ws + WVA_OFF, ws + BVA_OFF, gt_w, gt_b, 0, 15, ws + ZRAWA_OFF);
  k_core<<<BN/4, 256, 0, stream>>>(enemy_raw, ws + QHE_OFF, ws + WKE_OFF, ws + BKE_OFF,
                                   ws + WVE_OFF, ws + BVE_OFF, gt_w, gt_b, 1, 16, ws + ZRAWE_OFF);

  // 5. output projections
  k_dense<256, 256><<<dim3(BN/64, 4), 256, 0, stream>>>(ws + ZRAWA_OFF, attnA_W + 3*65536, attnA_b + 768, ws + AOUTA_OFF);
  k_dense<256, 256><<<dim3(BN/64, 4), 256, 0, stream>>>(ws + ZRAWE_OFF, attnE_W + 3*65536, attnE_b + 768, ws + AOUTE_OFF);

  // 6. conditional layernorms
  k_cln<<<BN/4, 256, 0, stream>>>(ws + AOUTA_OFF, ws + GBA_OFF, ws + ZA_OFF);
  k_cln<<<BN/4, 256, 0, stream>>>(ws + AOUTE_OFF, ws + GBE_OFF, ws + ZE_OFF);

  // 7. u = LN(concat(q_src, zA, zE))
  k_ln3<<<BN/4, 256, 0, stream>>>(ws + QSRC_OFF, ws + ZA_OFF, ws + ZE_OFF, ln3_g, ln3_b, ws + U_OFF);

  // 8. GRU gates
  k_dense<768, 768><<<dim3(BN/64, 12), 256, 0, stream>>>(ws + U_OFF, gru_Wih, gru_bih, ws + GI_OFF);
  k_dense<256, 768><<<dim3(BN/64, 12), 256, 0, stream>>>(hidden, gru_Whh, gru_bhh, ws + GH_OFF);
  k_gru<<<BN, 256, 0, stream>>>(ws + GI_OFF, ws + GH_OFF, hidden, hout);

  // 9. dueling heads -> Q
  k_heads<<<BN/4, 256, 0, stream>>>(hout, enemy_raw, Wv_head, bv_head, Wtb, btb,
                                    log_tau, ws, out);
}

// Round 2
// 1337.039 us; speedup vs baseline: 2.1305x; 2.1305x over previous
//
#include <hip/hip_runtime.h>
#include <math.h>

#define BN 16384

// ---------------- workspace float offsets ----------------
#define WKA_OFF   0
#define WVA_OFF   8192
#define WKE_OFF   16384
#define WVE_OFF   24576
#define WKEF_OFF  32768
#define BKA_OFF   40960
#define BVA_OFF   41216
#define BKE_OFF   41472
#define BVE_OFF   41728
#define BKEF_OFF  41984
#define WMP_OFF   43008
#define BMP_OFF   44544
#define G_OFF     45056
#define BG_OFF    53248
#define WQB_OFF   53312
#define SC0_OFF   53568
#define BMG_OFF   53632
#define WQA_OFF   53888
#define CQA_OFF   54912
#define WQE_OFF   54976
#define CQE_OFF   56000

#define QSRC_OFF  65536
#define BUF1_OFF  (QSRC_OFF + BN*256)
#define BUF2_OFF  (BUF1_OFF + BN*256)
#define BUF3_OFF  (BUF2_OFF + BN*256)
#define BUF4_OFF  (BUF3_OFF + BN*256)
#define BUF5_OFF  (BUF4_OFF + BN*256)

#define GBUF_OFF  BUF1_OFF           // d_g output (gA|gE), consumed by cores
#define MG_OFF    BUF2_OFF           // folded q_src->g matrix, consumed by d_g
#define ZRAWA_OFF BUF3_OFF
#define ZRAWE_OFF BUF4_OFF
#define AOUTA_OFF BUF1_OFF
#define AOUTE_OFF BUF2_OFF
#define ZA_OFF    BUF3_OFF
#define ZE_OFF    BUF4_OFF
#define GBA_OFF   BUF5_OFF
#define GBE_OFF   (BUF5_OFF + BN*512)
#define U_OFF     BUF5_OFF
#define GI_OFF    BUF1_OFF           // spans BUF1..BUF3 (BN*768)
#define GH_OFF    BUF4_OFF           // spans BUF4 + first 512 of BUF5 (u consumed)

#define HOFF      (BN*22)

// ---------------- fused small-weight precompute ----------------
__global__ __launch_bounds__(256) void k_fuse1(
    const float* __restrict__ attnA_W, const float* __restrict__ attnA_b,
    const float* __restrict__ attnE_W, const float* __restrict__ attnE_b,
    const float* __restrict__ W_ally,  const float* __restrict__ b_ally,
    const float* __restrict__ W_enemy, const float* __restrict__ b_enemy,
    const float* __restrict__ Wke,     const float* __restrict__ bke,
    float* __restrict__ FW) {
  int g = blockIdx.x * 256 + threadIdx.x;   // 5*8192 = 40960 items
  if (g >= 40960) return;
  int m = g >> 13;
  int r = g & 8191;
  int d = r >> 5, j = r & 31;
  const float *Wout, *Win, *bin, *bout; float *dst, *dstb;
  switch (m) {
    case 0: Wout = attnA_W + 65536;  Win = W_ally;  bin = b_ally;  bout = attnA_b + 256; dst = FW + WKA_OFF;  dstb = FW + BKA_OFF;  break;
    case 1: Wout = attnA_W + 131072; Win = W_ally;  bin = b_ally;  bout = attnA_b + 512; dst = FW + WVA_OFF;  dstb = FW + BVA_OFF;  break;
    case 2: Wout = attnE_W + 65536;  Win = W_enemy; bin = b_enemy; bout = attnE_b + 256; dst = FW + WKE_OFF;  dstb = FW + BKE_OFF;  break;
    case 3: Wout = attnE_W + 131072; Win = W_enemy; bin = b_enemy; bout = attnE_b + 512; dst = FW + WVE_OFF;  dstb = FW + BVE_OFF;  break;
    default:Wout = Wke;              Win = W_enemy; bin = b_enemy; bout = bke;           dst = FW + WKEF_OFF; dstb = FW + BKEF_OFF; break;
  }
  float acc = 0.f;
  for (int c = 0; c < 256; ++c) acc += Wout[d*256 + c] * Win[c*32 + j];
  dst[d*32 + j] = acc;
  if (j == 0) {
    float b = bout[d];
    for (int c = 0; c < 256; ++c) b += Wout[d*256 + c] * bin[c];
    dstb[d] = b;
  }
}

__global__ __launch_bounds__(256) void k_fuse2(
    const float* __restrict__ protos, const float* __restrict__ Wmq,
    const float* __restrict__ bmq,    const float* __restrict__ Wqs,
    const float* __restrict__ bqs,    float* __restrict__ FW) {
  int g = blockIdx.x * 256 + threadIdx.x;   // 10023 items
  const float* WKe_f = FW + WKEF_OFF;
  const float* bKe_f = FW + BKEF_OFF;
  if (g < 1536) {
    int i = g >> 8, c = g & 255;
    float acc = 0.f;
    for (int d = 0; d < 256; ++d) acc += protos[i*256 + d] * Wmq[d*256 + c];
    FW[WMP_OFF + i*256 + c] = acc;
  } else if (g < 9728) {
    int r = g - 1536;
    int j = r >> 8, c = r & 255;
    float acc = 0.f;
    for (int d = 0; d < 256; ++d) acc += WKe_f[d*32 + j] * Wqs[d*256 + c];
    FW[G_OFF + j*256 + c] = acc;
  } else if (g < 9984) {
    int c = g - 9728;
    float acc = 0.f;
    for (int d = 0; d < 256; ++d) acc += Wqs[d*256 + c] * bKe_f[d];
    FW[WQB_OFF + c] = acc;
  } else if (g < 9990) {
    int i = g - 9984;
    float acc = 0.f;
    for (int d = 0; d < 256; ++d) acc += protos[i*256 + d] * bmq[d];
    FW[BMP_OFF + i] = acc;
  } else if (g < 10022) {
    int j = g - 9990;
    float acc = 0.f;
    for (int d = 0; d < 256; ++d) acc += WKe_f[d*32 + j] * bqs[d];
    FW[BG_OFF + j] = acc;
  } else if (g == 10022) {
    float acc = 0.f;
    for (int d = 0; d < 256; ++d) acc += bqs[d] * bKe_f[d];
    FW[SC0_OFF] = acc;
  }
}

// fold q_src->g: Mg[r][c], bias; and qbk vectors wq/cq (per branch)
__global__ __launch_bounds__(256) void k_fuse3(
    const float* __restrict__ attnA_W, const float* __restrict__ attnA_b,
    const float* __restrict__ attnE_W, const float* __restrict__ attnE_b,
    float* __restrict__ FW, float* __restrict__ MG) {
  int g = blockIdx.x * 256 + threadIdx.x;   // 67848 items
  if (g < 65536) {
    int r = g >> 8, c = g & 255;
    int br = r >> 7, jj = r & 127, h = jj >> 5, jc = jj & 31;
    const float* W0 = br ? attnE_W : attnA_W;
    const float* Wk = FW + (br ? WKE_OFF : WKA_OFF);
    float acc = 0.f;
    for (int d = 0; d < 64; ++d)
      acc += W0[(h*64+d)*256 + c] * Wk[(h*64+d)*32 + jc];
    MG[r*256 + c] = acc;
  } else if (g < 65792) {
    int r = g - 65536;
    int br = r >> 7, jj = r & 127, h = jj >> 5, jc = jj & 31;
    const float* b0 = br ? attnE_b : attnA_b;
    const float* Wk = FW + (br ? WKE_OFF : WKA_OFF);
    float acc = 0.f;
    for (int d = 0; d < 64; ++d) acc += b0[h*64+d] * Wk[(h*64+d)*32 + jc];
    FW[BMG_OFF + r] = acc;
  } else if (g < 67840) {
    int r = g - 65792;
    int br = r >> 10, h = (r >> 8) & 3, c = r & 255;
    const float* W0 = br ? attnE_W : attnA_W;
    const float* bk = FW + (br ? BKE_OFF : BKA_OFF);
    float acc = 0.f;
    for (int d = 0; d < 64; ++d) acc += W0[(h*64+d)*256 + c] * bk[h*64+d];
    FW[(br ? WQE_OFF : WQA_OFF) + h*256 + c] = acc;
  } else if (g < 67848) {
    int r = g - 67840;
    int br = r >> 2, h = r & 3;
    const float* b0 = br ? attnE_b : attnA_b;
    const float* bk = FW + (br ? BKE_OFF : BKA_OFF);
    float acc = 0.f;
    for (int d = 0; d < 64; ++d) acc += b0[h*64+d] * bk[h*64+d];
    FW[(br ? CQE_OFF : CQA_OFF) + h] = acc;
  }
}

// ---------------- small-K dense (K=30 only) ----------------
template<int K, int NOUT>
__global__ __launch_bounds__(256) void k_densek(
    const float* __restrict__ A, const float* __restrict__ W,
    const float* __restrict__ bias, float* __restrict__ C) {
  constexpr int KB = 32;
  __shared__ float As[64][36];
  const int tid = threadIdx.x;
  const int s0 = blockIdx.x * 64;
  const int o0 = blockIdx.y * 64;
  const int ox = (tid & 15) * 4;
  const int sy = (tid >> 4) * 4;
  float acc[4][4] = {};
  const float* Abase = A + (long)s0 * K;
  for (int idx = tid; idx < 64 * KB; idx += 256) {
    int s = idx >> 5, c = idx & 31;
    As[s][c] = (c < K) ? Abase[(long)s * K + c] : 0.f;
  }
  __syncthreads();
  for (int kk = 0; kk < KB; kk += 4) {
    float a4[4][4];
    #pragma unroll
    for (int sj = 0; sj < 4; ++sj)
      *(float4*)a4[sj] = *(const float4*)&As[sy + sj][kk];
    #pragma unroll
    for (int oi = 0; oi < 4; ++oi) {
      float w4[4];
      #pragma unroll
      for (int kx = 0; kx < 4; ++kx) {
        int k = kk + kx;
        w4[kx] = (k < K) ? W[(long)(o0 + ox + oi) * K + k] : 0.f;
      }
      #pragma unroll
      for (int sj = 0; sj < 4; ++sj)
        #pragma unroll
        for (int kx = 0; kx < 4; ++kx)
          acc[sj][oi] = fmaf(a4[sj][kx], w4[kx], acc[sj][oi]);
    }
  }
  #pragma unroll
  for (int sj = 0; sj < 4; ++sj) {
    float4 o4;
    o4.x = acc[sj][0] + bias[o0 + ox + 0];
    o4.y = acc[sj][1] + bias[o0 + ox + 1];
    o4.z = acc[sj][2] + bias[o0 + ox + 2];
    o4.w = acc[sj][3] + bias[o0 + ox + 3];
    *(float4*)&C[(long)(s0 + sy + sj) * NOUT + o0 + ox] = o4;
  }
}

// ---------------- main dense: 128x128 tile, BK=32, LDS-staged A & W ----------------
// thread: outs {ox+16j}, samples {sy+16i} -> A reads broadcast, W reads 2-way
template<int K, int NOUT>
__global__ __launch_bounds__(256) void k_dense2(
    const float* __restrict__ A, const float* __restrict__ W,
    const float* __restrict__ bias, float* __restrict__ C) {
  constexpr int NCH = K / 32;
  __shared__ float As[128][36];
  __shared__ float Ws[128][36];
  const int tid = threadIdx.x;
  const int ox = tid & 15;
  const int sy = tid >> 4;
  const int o0 = blockIdx.x * 128;
  const long s0 = (long)blockIdx.y * 128;
  const int srow = tid >> 3;          // staging: rows srow+32r
  const int sc4 = (tid & 7) * 4;      // 4-float col within 32-wide chunk
  float acc[8][8];
  #pragma unroll
  for (int i = 0; i < 8; ++i)
    #pragma unroll
    for (int j = 0; j < 8; ++j) acc[i][j] = 0.f;
  float4 pa[4], pw[4];
  const float* Ab = A + (s0 + srow) * K + sc4;
  const float* Wb = W + (long)(o0 + srow) * K + sc4;
  #pragma unroll
  for (int r = 0; r < 4; ++r) {
    pa[r] = *(const float4*)(Ab + (long)32 * r * K);
    pw[r] = *(const float4*)(Wb + (long)32 * r * K);
  }
  for (int ch = 0; ch < NCH; ++ch) {
    __syncthreads();
    #pragma unroll
    for (int r = 0; r < 4; ++r) {
      *(float4*)&As[srow + 32*r][sc4] = pa[r];
      *(float4*)&Ws[srow + 32*r][sc4] = pw[r];
    }
    __syncthreads();
    if (ch + 1 < NCH) {
      const int k0 = (ch + 1) * 32;
      #pragma unroll
      for (int r = 0; r < 4; ++r) {
        pa[r] = *(const float4*)(Ab + k0 + (long)32 * r * K);
        pw[r] = *(const float4*)(Wb + k0 + (long)32 * r * K);
      }
    }
    #pragma unroll
    for (int kk = 0; kk < 32; kk += 4) {
      float4 a4[8];
      #pragma unroll
      for (int i = 0; i < 8; ++i) a4[i] = *(const float4*)&As[sy + 16*i][kk];
      #pragma unroll
      for (int j = 0; j < 8; ++j) {
        float4 w4 = *(const float4*)&Ws[ox + 16*j][kk];
        #pragma unroll
        for (int t = 0; t < 4; ++t) {
          const float wv = ((const float*)&w4)[t];
          #pragma unroll
          for (int i = 0; i < 8; ++i)
            acc[i][j] = fmaf(((const float*)&a4[i])[t], wv, acc[i][j]);
        }
      }
    }
  }
  #pragma unroll
  for (int j = 0; j < 8; ++j) {
    const float b = bias[o0 + ox + 16*j];
    #pragma unroll
    for (int i = 0; i < 8; ++i)
      C[(s0 + sy + 16*i) * (long)NOUT + (o0 + ox + 16*j)] = acc[i][j] + b;
  }
}

// ---------------- fused attention core ----------------
__global__ __launch_bounds__(256) void k_core(
    const float* __restrict__ raw, const float* __restrict__ qsrc,
    const float* __restrict__ g, const float* __restrict__ wq,
    const float* __restrict__ cq, const float* __restrict__ Wv,
    const float* __restrict__ bv, const float* __restrict__ gt_w,
    const float* __restrict__ gt_b, int gidx, int N,
    float* __restrict__ zout) {
  __shared__ float ally[4][16][33];
  __shared__ float gbuf[4][4][32];
  __shared__ float pbuf[4][4][16];
  __shared__ float pal[4][4][32];
  __shared__ float qbk[4][4];
  __shared__ float mfv[4][16];
  const int tid = threadIdx.x;
  const int w = tid >> 6, l = tid & 63;
  const long s = (long)blockIdx.x * 4 + w;
  const int NR = N * 32;
  const float* rs = raw + s * NR;
  for (int i = l; i < NR; i += 64) ally[w][i >> 5][i & 31] = rs[i];
  const float* grow = g + s * 256;
  for (int jj = l; jj < 128; jj += 64) gbuf[w][jj >> 5][jj & 31] = grow[jj];
  __syncthreads();
  // mask + count + temperature
  bool valid = false;
  if (l < N) {
    #pragma unroll
    for (int j = 0; j < 32; ++j) valid |= (ally[w][l][j] != 0.f);
  }
  unsigned long long bal = __ballot(l < N && valid);
  float cnt = (float)__popcll(bal);
  float x = gt_w[gidx] * log1pf(cnt) + gt_b[gidx];
  float sp = fmaxf(x, 0.f) + log1pf(expf(-fabsf(x)));   // softplus
  float scale = 1.f / (8.f * (sp + 1.f));               // 1/(sqrt(DH)*temp)
  if (l < 16) mfv[w][l] = (l < N && valid) ? 1.f : 0.f;
  // qbk[h] = q_src . wq[h] + cq[h]
  const float* qrow = qsrc + s * 256;
  {
    int h = l >> 4, i = l & 15;
    float acc = 0.f;
    #pragma unroll
    for (int t = 0; t < 16; ++t) {
      int c = i + t * 16;
      acc += qrow[c] * wq[h * 256 + c];
    }
    acc += __shfl_xor(acc, 8);
    acc += __shfl_xor(acc, 4);
    acc += __shfl_xor(acc, 2);
    acc += __shfl_xor(acc, 1);
    if (i == 0) qbk[w][h] = acc + cq[h];
  }
  __syncthreads();
  { // scores + softmax
    int h = l >> 4, n = l & 15;
    float sv = -INFINITY;
    if (n < N && mfv[w][n] != 0.f) {
      float acc = 0.f;
      #pragma unroll
      for (int j = 0; j < 32; ++j) acc += gbuf[w][h][j] * ally[w][n][j];
      sv = (acc + qbk[w][h]) * scale;
    }
    float m = sv;
    m = fmaxf(m, __shfl_xor(m, 8));
    m = fmaxf(m, __shfl_xor(m, 4));
    m = fmaxf(m, __shfl_xor(m, 2));
    m = fmaxf(m, __shfl_xor(m, 1));
    float e = (sv == -INFINITY) ? 0.f : expf(sv - m);
    float su = e;
    su += __shfl_xor(su, 8);
    su += __shfl_xor(su, 4);
    su += __shfl_xor(su, 2);
    su += __shfl_xor(su, 1);
    pbuf[w][h][n] = e / su;
  }
  __syncthreads();
  #pragma unroll
  for (int rep = 0; rep < 2; ++rep) {
    int h = rep * 2 + (l >> 5);
    int j = l & 31;
    float acc = 0.f;
    for (int n = 0; n < N; ++n) acc += pbuf[w][h][n] * ally[w][n][j];
    pal[w][h][j] = acc;
  }
  __syncthreads();
  float* zrow = zout + s * 256;
  #pragma unroll
  for (int rep = 0; rep < 4; ++rep) {
    int d = rep * 64 + l;
    float acc = bv[d];
    #pragma unroll
    for (int j = 0; j < 32; ++j) acc += Wv[d * 32 + j] * pal[w][rep][j];
    zrow[d] = acc;
  }
}

// ---------------- conditional layernorm ----------------
__global__ __launch_bounds__(256) void k_cln(
    const float* __restrict__ xin, const float* __restrict__ gb,
    float* __restrict__ out) {
  int w = threadIdx.x >> 6, l = threadIdx.x & 63;
  long s = (long)blockIdx.x * 4 + w;
  const float* xr = xin + s * 256;
  float v[4], sum = 0.f, ssq = 0.f;
  #pragma unroll
  for (int t = 0; t < 4; ++t) {
    v[t] = xr[l + t * 64];
    sum += v[t]; ssq += v[t] * v[t];
  }
  #pragma unroll
  for (int off = 32; off > 0; off >>= 1) {
    sum += __shfl_xor(sum, off);
    ssq += __shfl_xor(ssq, off);
  }
  float mu = sum * (1.f / 256.f);
  float var = ssq * (1.f / 256.f) - mu * mu;
  float rstd = rsqrtf(var + 1e-5f);
  const float* gbr = gb + s * 512;
  float* orow = out + s * 256;
  #pragma unroll
  for (int t = 0; t < 4; ++t) {
    int d = l + t * 64;
    orow[d] = (1.f + gbr[d]) * ((v[t] - mu) * rstd) + gbr[256 + d];
  }
}

// ---------------- LN over concat ----------------
__global__ __launch_bounds__(256) void k_ln3(
    const float* __restrict__ q, const float* __restrict__ zA,
    const float* __restrict__ zE, const float* __restrict__ g,
    const float* __restrict__ b, float* __restrict__ u) {
  int w = threadIdx.x >> 6, l = threadIdx.x & 63;
  long s = (long)blockIdx.x * 4 + w;
  float v[12], sum = 0.f, ssq = 0.f;
  #pragma unroll
  for (int t = 0; t < 12; ++t) {
    int i = l + t * 64;
    float val;
    if (i < 256)      val = q[s * 256 + i];
    else if (i < 512) val = zA[s * 256 + i - 256];
    else              val = zE[s * 256 + i - 512];
    v[t] = val; sum += val; ssq += val * val;
  }
  #pragma unroll
  for (int off = 32; off > 0; off >>= 1) {
    sum += __shfl_xor(sum, off);
    ssq += __shfl_xor(ssq, off);
  }
  float mu = sum * (1.f / 768.f);
  float var = ssq * (1.f / 768.f) - mu * mu;
  float rstd = rsqrtf(var + 1e-5f);
  #pragma unroll
  for (int t = 0; t < 12; ++t) {
    int i = l + t * 64;
    u[s * 768 + i] = (v[t] - mu) * rstd * g[i] + b[i];
  }
}

// ---------------- GRU elementwise ----------------
__global__ __launch_bounds__(256) void k_gru(
    const float* __restrict__ gi, const float* __restrict__ gh,
    const float* __restrict__ hid, float* __restrict__ hout) {
  long gidx = (long)blockIdx.x * 256 + threadIdx.x;
  long s = gidx >> 8; int d = gidx & 255;
  const float* gir = gi + s * 768;
  const float* ghr = gh + s * 768;
  float ir = gir[d], iz = gir[256 + d], inn = gir[512 + d];
  float hr = ghr[d], hz = ghr[256 + d], hn = ghr[512 + d];
  float r  = 1.f / (1.f + expf(-(ir + hr)));
  float zg = 1.f / (1.f + expf(-(iz + hz)));
  float n  = tanhf(inn + r * hn);
  hout[gidx] = (1.f - zg) * n + zg * hid[gidx];
}

// ---------------- Q heads ----------------
__global__ __launch_bounds__(256) void k_heads(
    const float* __restrict__ h, const float* __restrict__ eraw,
    const float* __restrict__ Wv_head, const float* __restrict__ bv_head,
    const float* __restrict__ Wtb, const float* __restrict__ btb,
    const float* __restrict__ log_tau, const float* __restrict__ FW,
    float* __restrict__ Qout) {
  __shared__ float hb[4][256];
  __shared__ float ob[4][48];
  int w = threadIdx.x >> 6, l = threadIdx.x & 63;
  long s = (long)blockIdx.x * 4 + w;
  const float* hr = h + s * 256;
  #pragma unroll
  for (int t = 0; t < 4; ++t) hb[w][l + t * 64] = hr[l + t * 64];
  __syncthreads();
  if (l < 42) {
    const float* wr; float b;
    if (l == 0)      { wr = Wv_head;                      b = bv_head[0]; }
    else if (l == 1) { wr = Wtb;                          b = btb[0]; }
    else if (l == 2) { wr = Wtb + 256;                    b = btb[1]; }
    else if (l < 9)  { wr = FW + WMP_OFF + (l - 3) * 256; b = FW[BMP_OFF + l - 3]; }
    else if (l < 41) { wr = FW + G_OFF + (l - 9) * 256;   b = FW[BG_OFF + l - 9]; }
    else             { wr = FW + WQB_OFF;                 b = FW[SC0_OFF]; }
    float acc = b;
    for (int c = 0; c < 256; ++c) acc += wr[c] * hb[w][c];
    ob[w][l] = acc;
  }
  __syncthreads();
  float itm = 1.f / (expf(log_tau[0]) + 1e-6f);
  float its = 1.f / (expf(log_tau[1]) + 1e-6f);
  float V = ob[w][0];
  if (l < 16) {
    const float* er = eraw + s * 512 + l * 32;
    bool valid = false; float acc = 0.f;
    #pragma unroll
    for (int j = 0; j < 32; ++j) {
      float e = er[j];
      valid |= (e != 0.f);
      acc += ob[w][9 + j] * e;
    }
    float a = (acc + ob[w][41]) * 0.0625f;
    float sa = valid ? a : 0.f;
    float cv = valid ? 1.f : 0.f;
    #pragma unroll
    for (int off = 8; off > 0; off >>= 1) {
      sa += __shfl_xor(sa, off);
      cv += __shfl_xor(cv, off);
    }
    float me = sa / fmaxf(cv, 1.f);
    float qs = V + ob[w][2] + (valid ? (a - me) * its : -1e30f * its);
    Qout[s * 22 + 6 + l] = qs;
  } else if (l < 22) {
    int i = l - 16;
    float mean = 0.f;
    #pragma unroll
    for (int t = 0; t < 6; ++t) mean += ob[w][3 + t];
    mean *= (1.f / 6.f);
    float qm = V + ob[w][1] + (ob[w][3 + i] - mean) * 0.0625f * itm;
    Qout[s * 22 + i] = qm;
  }
}

// ---------------- launch ----------------
extern "C" void kernel_launch(void* const* d_in, const int* in_sizes, int n_in,
                              void* d_out, int out_size, void* d_ws, size_t ws_size,
                              hipStream_t stream) {
  const float* own_raw   = (const float*)d_in[0];
  const float* ally_raw  = (const float*)d_in[1];
  const float* enemy_raw = (const float*)d_in[2];
  const float* hidden    = (const float*)d_in[3];
  const float* W_own     = (const float*)d_in[4];
  const float* b_own     = (const float*)d_in[5];
  const float* W_ally    = (const float*)d_in[6];
  const float* b_ally    = (const float*)d_in[7];
  const float* W_enemy   = (const float*)d_in[8];
  const float* b_enemy   = (const float*)d_in[9];
  const float* gt_w      = (const float*)d_in[10];
  const float* gt_b      = (const float*)d_in[11];
  const float* attnA_W   = (const float*)d_in[12];
  const float* attnA_b   = (const float*)d_in[13];
  const float* attnE_W   = (const float*)d_in[14];
  const float* attnE_b   = (const float*)d_in[15];
  const float* clnA_W    = (const float*)d_in[16];
  const float* clnA_b    = (const float*)d_in[17];
  const float* clnE_W    = (const float*)d_in[18];
  const float* clnE_b    = (const float*)d_in[19];
  const float* ln3_g     = (const float*)d_in[20];
  const float* ln3_b     = (const float*)d_in[21];
  const float* gru_Wih   = (const float*)d_in[22];
  const float* gru_Whh   = (const float*)d_in[23];
  const float* gru_bih   = (const float*)d_in[24];
  const float* gru_bhh   = (const float*)d_in[25];
  const float* Wv_head   = (const float*)d_in[26];
  const float* bv_head   = (const float*)d_in[27];
  const float* Wtb       = (const float*)d_in[28];
  const float* btb       = (const float*)d_in[29];
  const float* log_tau   = (const float*)d_in[30];
  const float* Wmq       = (const float*)d_in[31];
  const float* bmq       = (const float*)d_in[32];
  const float* protos    = (const float*)d_in[33];
  const float* Wqs       = (const float*)d_in[34];
  const float* bqs       = (const float*)d_in[35];
  const float* Wke       = (const float*)d_in[36];
  const float* bke       = (const float*)d_in[37];

  float* ws  = (float*)d_ws;
  float* out = (float*)d_out;
  float* hout = out + HOFF;

  k_fuse1<<<160, 256, 0, stream>>>(attnA_W, attnA_b, attnE_W, attnE_b,
                                   W_ally, b_ally, W_enemy, b_enemy, Wke, bke, ws);
  k_fuse2<<<40, 256, 0, stream>>>(protos, Wmq, bmq, Wqs, bqs, ws);
  k_fuse3<<<266, 256, 0, stream>>>(attnA_W, attnA_b, attnE_W, attnE_b, ws, ws + MG_OFF);

  // q_src
  k_densek<30, 256><<<dim3(BN/64, 4), 256, 0, stream>>>(own_raw, W_own, b_own, ws + QSRC_OFF);

  // g = q_src @ Mg.T + bMg (both branches)
  k_dense2<256, 256><<<dim3(2, 128), 256, 0, stream>>>(ws + QSRC_OFF, ws + MG_OFF, ws + BMG_OFF, ws + GBUF_OFF);
  // cln gamma/beta
  k_dense2<256, 512><<<dim3(4, 128), 256, 0, stream>>>(ws + QSRC_OFF, clnA_W, clnA_b, ws + GBA_OFF);
  k_dense2<256, 512><<<dim3(4, 128), 256, 0, stream>>>(ws + QSRC_OFF, clnE_W, clnE_b, ws + GBE_OFF);

  // attention cores
  k_core<<<BN/4, 256, 0, stream>>>(ally_raw, ws + QSRC_OFF, ws + GBUF_OFF,
                                   ws + WQA_OFF, ws + CQA_OFF, ws + WVA_OFF, ws + BVA_OFF,
                                   gt_w, gt_b, 0, 15, ws + ZRAWA_OFF);
  k_core<<<BN/4, 256, 0, stream>>>(enemy_raw, ws + QSRC_OFF, ws + GBUF_OFF + 128,
                                   ws + WQE_OFF, ws + CQE_OFF, ws + WVE_OFF, ws + BVE_OFF,
                                   gt_w, gt_b, 1, 16, ws + ZRAWE_OFF);

  // output projections
  k_dense2<256, 256><<<dim3(2, 128), 256, 0, stream>>>(ws + ZRAWA_OFF, attnA_W + 196608, attnA_b + 768, ws + AOUTA_OFF);
  k_dense2<256, 256><<<dim3(2, 128), 256, 0, stream>>>(ws + ZRAWE_OFF, attnE_W + 196608, attnE_b + 768, ws + AOUTE_OFF);

  // conditional layernorms
  k_cln<<<BN/4, 256, 0, stream>>>(ws + AOUTA_OFF, ws + GBA_OFF, ws + ZA_OFF);
  k_cln<<<BN/4, 256, 0, stream>>>(ws + AOUTE_OFF, ws + GBE_OFF, ws + ZE_OFF);

  // u = LN(concat)
  k_ln3<<<BN/4, 256, 0, stream>>>(ws + QSRC_OFF, ws + ZA_OFF, ws + ZE_OFF, ln3_g, ln3_b, ws + U_OFF);

  // GRU gates
  k_dense2<768, 768><<<dim3(6, 128), 256, 0, stream>>>(ws + U_OFF, gru_Wih, gru_bih, ws + GI_OFF);
  k_dense2<256, 768><<<dim3(6, 128), 256, 0, stream>>>(hidden, gru_Whh, gru_bhh, ws + GH_OFF);
  k_gru<<<BN, 256, 0, stream>>>(ws + GI_OFF, ws + GH_OFF, hidden, hout);

  // heads
  k_heads<<<BN/4, 256, 0, stream>>>(hout, enemy_raw, Wv_head, bv_head, Wtb, btb,
                                    log_tau, ws, out);
}

// Round 3
// 500.919 us; speedup vs baseline: 5.6866x; 2.6692x over previous
//
#include <hip/hip_runtime.h>
#include <math.h>

#define BN 16384

typedef float f32x4 __attribute__((ext_vector_type(4)));
typedef short bf16x8v __attribute__((ext_vector_type(8)));
typedef unsigned short u16x8 __attribute__((ext_vector_type(8)));
typedef unsigned short u16x4 __attribute__((ext_vector_type(4)));

static __device__ inline unsigned short f2bf(float f) {
  unsigned u = __float_as_uint(f);
  return (unsigned short)((u + 0x8000u) >> 16);
}

// ---------------- workspace float offsets (identical to round-1 layout) ----------------
#define WKA_OFF   0
#define WVA_OFF   8192
#define WKE_OFF   16384
#define WVE_OFF   24576
#define WKEF_OFF  32768
#define BKA_OFF   40960
#define BVA_OFF   41216
#define BKE_OFF   41472
#define BVE_OFF   41728
#define BKEF_OFF  41984
#define WMP_OFF   43008
#define BMP_OFF   44544
#define G_OFF     45056
#define BG_OFF    53248
#define WQB_OFF   53312
#define SC0_OFF   53568
#define BMG_OFF   53632
#define WQA_OFF   53888
#define CQA_OFF   54912
#define WQE_OFF   54976
#define CQE_OFF   56000

#define QSRC_OFF  65536
#define BUF1_OFF  (QSRC_OFF + BN*256)
#define BUF2_OFF  (BUF1_OFF + BN*256)
#define BUF3_OFF  (BUF2_OFF + BN*256)
#define BUF4_OFF  (BUF3_OFF + BN*256)
#define BUF5_OFF  (BUF4_OFF + BN*256)

#define GBUF_OFF  BUF1_OFF
#define ZRAWA_OFF BUF3_OFF
#define ZRAWE_OFF BUF4_OFF
#define AOUTA_OFF BUF1_OFF
#define AOUTE_OFF BUF2_OFF
#define ZA_OFF    BUF3_OFF
#define ZE_OFF    BUF4_OFF
#define GBA_OFF   BUF5_OFF
#define GBE_OFF   (BUF5_OFF + BN*512)
#define U_OFF     BUF5_OFF
#define GI_OFF    BUF1_OFF           // BN*768 across BUF1..BUF3
#define GH_OFF    BUF4_OFF           // BN*768 across BUF4 + BUF5[0:512]

#define HOFF      (BN*22)

// bf16 weight cache lives in d_out's h-region (dead until k_gru writes it)
// short offsets within WB:
#define WIH_S 0
#define WHH_S 589824
#define CLA_S 786432
#define CLE_S 917504
#define PJA_S 1048576
#define PJE_S 1114112
#define MGB_S 1179648

// ---------------- fused small-weight precompute ----------------
__global__ __launch_bounds__(256) void k_fuse1(
    const float* __restrict__ attnA_W, const float* __restrict__ attnA_b,
    const float* __restrict__ attnE_W, const float* __restrict__ attnE_b,
    const float* __restrict__ W_ally,  const float* __restrict__ b_ally,
    const float* __restrict__ W_enemy, const float* __restrict__ b_enemy,
    const float* __restrict__ Wke,     const float* __restrict__ bke,
    float* __restrict__ FW) {
  int g = blockIdx.x * 256 + threadIdx.x;
  if (g >= 40960) return;
  int m = g >> 13;
  int r = g & 8191;
  int d = r >> 5, j = r & 31;
  const float *Wout, *Win, *bin, *bout; float *dst, *dstb;
  switch (m) {
    case 0: Wout = attnA_W + 65536;  Win = W_ally;  bin = b_ally;  bout = attnA_b + 256; dst = FW + WKA_OFF;  dstb = FW + BKA_OFF;  break;
    case 1: Wout = attnA_W + 131072; Win = W_ally;  bin = b_ally;  bout = attnA_b + 512; dst = FW + WVA_OFF;  dstb = FW + BVA_OFF;  break;
    case 2: Wout = attnE_W + 65536;  Win = W_enemy; bin = b_enemy; bout = attnE_b + 256; dst = FW + WKE_OFF;  dstb = FW + BKE_OFF;  break;
    case 3: Wout = attnE_W + 131072; Win = W_enemy; bin = b_enemy; bout = attnE_b + 512; dst = FW + WVE_OFF;  dstb = FW + BVE_OFF;  break;
    default:Wout = Wke;              Win = W_enemy; bin = b_enemy; bout = bke;           dst = FW + WKEF_OFF; dstb = FW + BKEF_OFF; break;
  }
  float acc = 0.f;
  for (int c = 0; c < 256; ++c) acc += Wout[d*256 + c] * Win[c*32 + j];
  dst[d*32 + j] = acc;
  if (j == 0) {
    float b = bout[d];
    for (int c = 0; c < 256; ++c) b += Wout[d*256 + c] * bin[c];
    dstb[d] = b;
  }
}

__global__ __launch_bounds__(256) void k_fuse2(
    const float* __restrict__ protos, const float* __restrict__ Wmq,
    const float* __restrict__ bmq,    const float* __restrict__ Wqs,
    const float* __restrict__ bqs,    float* __restrict__ FW) {
  int g = blockIdx.x * 256 + threadIdx.x;
  const float* WKe_f = FW + WKEF_OFF;
  const float* bKe_f = FW + BKEF_OFF;
  if (g < 1536) {
    int i = g >> 8, c = g & 255;
    float acc = 0.f;
    for (int d = 0; d < 256; ++d) acc += protos[i*256 + d] * Wmq[d*256 + c];
    FW[WMP_OFF + i*256 + c] = acc;
  } else if (g < 9728) {
    int r = g - 1536;
    int j = r >> 8, c = r & 255;
    float acc = 0.f;
    for (int d = 0; d < 256; ++d) acc += WKe_f[d*32 + j] * Wqs[d*256 + c];
    FW[G_OFF + j*256 + c] = acc;
  } else if (g < 9984) {
    int c = g - 9728;
    float acc = 0.f;
    for (int d = 0; d < 256; ++d) acc += Wqs[d*256 + c] * bKe_f[d];
    FW[WQB_OFF + c] = acc;
  } else if (g < 9990) {
    int i = g - 9984;
    float acc = 0.f;
    for (int d = 0; d < 256; ++d) acc += protos[i*256 + d] * bmq[d];
    FW[BMP_OFF + i] = acc;
  } else if (g < 10022) {
    int j = g - 9990;
    float acc = 0.f;
    for (int d = 0; d < 256; ++d) acc += WKe_f[d*32 + j] * bqs[d];
    FW[BG_OFF + j] = acc;
  } else if (g == 10022) {
    float acc = 0.f;
    for (int d = 0; d < 256; ++d) acc += bqs[d] * bKe_f[d];
    FW[SC0_OFF] = acc;
  }
}

// fold q_src->g matrix (bf16 out) + bias; qbk vectors per branch
__global__ __launch_bounds__(256) void k_fuse3(
    const float* __restrict__ attnA_W, const float* __restrict__ attnA_b,
    const float* __restrict__ attnE_W, const float* __restrict__ attnE_b,
    float* __restrict__ FW, unsigned short* __restrict__ MGB) {
  int g = blockIdx.x * 256 + threadIdx.x;
  if (g < 65536) {
    int r = g >> 8, c = g & 255;
    int br = r >> 7, jj = r & 127, h = jj >> 5, jc = jj & 31;
    const float* W0 = br ? attnE_W : attnA_W;
    const float* Wk = FW + (br ? WKE_OFF : WKA_OFF);
    float acc = 0.f;
    for (int d = 0; d < 64; ++d)
      acc += W0[(h*64+d)*256 + c] * Wk[(h*64+d)*32 + jc];
    MGB[r*256 + c] = f2bf(acc);
  } else if (g < 65792) {
    int r = g - 65536;
    int br = r >> 7, jj = r & 127, h = jj >> 5, jc = jj & 31;
    const float* b0 = br ? attnE_b : attnA_b;
    const float* Wk = FW + (br ? WKE_OFF : WKA_OFF);
    float acc = 0.f;
    for (int d = 0; d < 64; ++d) acc += b0[h*64+d] * Wk[(h*64+d)*32 + jc];
    FW[BMG_OFF + r] = acc;
  } else if (g < 67840) {
    int r = g - 65792;
    int br = r >> 10, h = (r >> 8) & 3, c = r & 255;
    const float* W0 = br ? attnE_W : attnA_W;
    const float* bk = FW + (br ? BKE_OFF : BKA_OFF);
    float acc = 0.f;
    for (int d = 0; d < 64; ++d) acc += W0[(h*64+d)*256 + c] * bk[h*64+d];
    FW[(br ? WQE_OFF : WQA_OFF) + h*256 + c] = acc;
  } else if (g < 67848) {
    int r = g - 67840;
    int br = r >> 2, h = r & 3;
    const float* b0 = br ? attnE_b : attnA_b;
    const float* bk = FW + (br ? BKE_OFF : BKA_OFF);
    float acc = 0.f;
    for (int d = 0; d < 64; ++d) acc += b0[h*64+d] * bk[h*64+d];
    FW[(br ? CQE_OFF : CQA_OFF) + h] = acc;
  }
}

// ---------------- f32->bf16 weight conversion (6 fixed segments) ----------------
__global__ __launch_bounds__(256) void k_cvt(
    const float* __restrict__ w0, const float* __restrict__ w1,
    const float* __restrict__ w2, const float* __restrict__ w3,
    const float* __restrict__ w4, const float* __restrict__ w5,
    unsigned short* __restrict__ dst) {
  int e = (blockIdx.x * 256 + threadIdx.x) * 4;   // 1179648 shorts total
  const float* src; int off;
  if (e < 589824)       { src = w0; off = 0; }
  else if (e < 786432)  { src = w1; off = 589824; }
  else if (e < 917504)  { src = w2; off = 786432; }
  else if (e < 1048576) { src = w3; off = 917504; }
  else if (e < 1114112) { src = w4; off = 1048576; }
  else                  { src = w5; off = 1114112; }
  float4 v = *(const float4*)(src + (e - off));
  u16x4 b; b.x = f2bf(v.x); b.y = f2bf(v.y); b.z = f2bf(v.z); b.w = f2bf(v.w);
  *(u16x4*)&dst[e] = b;
}

// ---------------- small-K dense (K=30), dual f32+bf16 output ----------------
template<int K, int NOUT>
__global__ __launch_bounds__(256) void k_densek(
    const float* __restrict__ A, const float* __restrict__ W,
    const float* __restrict__ bias, float* __restrict__ C,
    unsigned short* __restrict__ Cb) {
  constexpr int KB = 32;
  __shared__ float As[64][36];
  const int tid = threadIdx.x;
  const int s0 = blockIdx.x * 64;
  const int o0 = blockIdx.y * 64;
  const int ox = (tid & 15) * 4;
  const int sy = (tid >> 4) * 4;
  float acc[4][4] = {};
  const float* Abase = A + (long)s0 * K;
  for (int idx = tid; idx < 64 * KB; idx += 256) {
    int s = idx >> 5, c = idx & 31;
    As[s][c] = (c < K) ? Abase[(long)s * K + c] : 0.f;
  }
  __syncthreads();
  for (int kk = 0; kk < KB; kk += 4) {
    float a4[4][4];
    #pragma unroll
    for (int sj = 0; sj < 4; ++sj)
      *(float4*)a4[sj] = *(const float4*)&As[sy + sj][kk];
    #pragma unroll
    for (int oi = 0; oi < 4; ++oi) {
      float w4[4];
      #pragma unroll
      for (int kx = 0; kx < 4; ++kx) {
        int k = kk + kx;
        w4[kx] = (k < K) ? W[(long)(o0 + ox + oi) * K + k] : 0.f;
      }
      #pragma unroll
      for (int sj = 0; sj < 4; ++sj)
        #pragma unroll
        for (int kx = 0; kx < 4; ++kx)
          acc[sj][oi] = fmaf(a4[sj][kx], w4[kx], acc[sj][oi]);
    }
  }
  #pragma unroll
  for (int sj = 0; sj < 4; ++sj) {
    float4 o4;
    o4.x = acc[sj][0] + bias[o0 + ox + 0];
    o4.y = acc[sj][1] + bias[o0 + ox + 1];
    o4.z = acc[sj][2] + bias[o0 + ox + 2];
    o4.w = acc[sj][3] + bias[o0 + ox + 3];
    *(float4*)&C[(long)(s0 + sy + sj) * NOUT + o0 + ox] = o4;
    u16x4 b4; b4.x = f2bf(o4.x); b4.y = f2bf(o4.y); b4.z = f2bf(o4.z); b4.w = f2bf(o4.w);
    *(u16x4*)&Cb[(long)(s0 + sy + sj) * NOUT + o0 + ox] = b4;
  }
}

// ---------------- MFMA dense: C[s][o] = bias[o] + A[s,:].W[o,:] (bf16 inputs) ----------------
// 128x128 tile, BK=32, 4 waves in 2x2 quadrants, XOR-swizzled LDS.
template<int K, int NOUT, bool ABF>
__global__ __launch_bounds__(256) void k_mm(
    const void* __restrict__ Ap, const unsigned short* __restrict__ W,
    const float* __restrict__ bias, float* __restrict__ C) {
  constexpr int NCH = K / 32;
  __shared__ __align__(16) unsigned short As[4096];
  __shared__ __align__(16) unsigned short Ws[4096];
  const int tid = threadIdx.x;
  const int o0 = blockIdx.x * 128;
  const long s0 = (long)blockIdx.y * 128;
  const int wv = tid >> 6, l = tid & 63;
  const int wm = (wv >> 1) * 64, wn = (wv & 1) * 64;
  const int lr = l & 15, lk = l >> 4;

  const int wrow = tid >> 2;       // staging row (p=0); p=1 adds 64
  const int wslot = tid & 3;       // 8-short slot for bf16 staging
  const int q = tid & 3;           // f32 staging quarter

  f32x4 acc[4][4] = {};
  u16x8 pw[2];
  u16x8 pa_b[2];
  float4 pa_f[2][2];

  const unsigned short* Wb = W + (long)o0 * K;
  const unsigned short* Abf = (const unsigned short*)Ap;
  const float* Aff = (const float*)Ap;

  #pragma unroll
  for (int p = 0; p < 2; ++p) {
    const int r = wrow + 64 * p;
    pw[p] = *(const u16x8*)(Wb + (long)r * K + wslot * 8);
    if constexpr (ABF) {
      pa_b[p] = *(const u16x8*)(Abf + (s0 + r) * K + wslot * 8);
    } else {
      const float* Af = Aff + (s0 + r) * K + q * 4;
      pa_f[p][0] = *(const float4*)(Af);
      pa_f[p][1] = *(const float4*)(Af + 16);
    }
  }

  for (int ch = 0; ch < NCH; ++ch) {
    if (ch) __syncthreads();
    #pragma unroll
    for (int p = 0; p < 2; ++p) {
      const int r = wrow + 64 * p;
      const int ps = (wslot ^ (r & 3)) * 8;
      *(u16x8*)&Ws[r * 32 + ps] = pw[p];
      if constexpr (ABF) {
        *(u16x8*)&As[r * 32 + ps] = pa_b[p];
      } else {
        #pragma unroll
        for (int j = 0; j < 2; ++j) {
          float4 v = pa_f[p][j];
          unsigned long long pk =
              (unsigned long long)f2bf(v.x) |
              ((unsigned long long)f2bf(v.y) << 16) |
              ((unsigned long long)f2bf(v.z) << 32) |
              ((unsigned long long)f2bf(v.w) << 48);
          const int slot = (j * 2 + (q >> 1)) ^ (r & 3);
          *(unsigned long long*)&As[r * 32 + slot * 8 + (q & 1) * 4] = pk;
        }
      }
    }
    __syncthreads();
    if (ch + 1 < NCH) {
      const int k0 = (ch + 1) * 32;
      #pragma unroll
      for (int p = 0; p < 2; ++p) {
        const int r = wrow + 64 * p;
        pw[p] = *(const u16x8*)(Wb + (long)r * K + k0 + wslot * 8);
        if constexpr (ABF) {
          pa_b[p] = *(const u16x8*)(Abf + (s0 + r) * K + k0 + wslot * 8);
        } else {
          const float* Af = Aff + (s0 + r) * K + k0 + q * 4;
          pa_f[p][0] = *(const float4*)(Af);
          pa_f[p][1] = *(const float4*)(Af + 16);
        }
      }
    }
    bf16x8v af[4], bw[4];
    #pragma unroll
    for (int m = 0; m < 4; ++m) {
      const int r = wm + m * 16 + lr;
      af[m] = *(const bf16x8v*)&As[r * 32 + ((lk ^ (r & 3)) * 8)];
    }
    #pragma unroll
    for (int n = 0; n < 4; ++n) {
      const int r = wn + n * 16 + lr;
      bw[n] = *(const bf16x8v*)&Ws[r * 32 + ((lk ^ (r & 3)) * 8)];
    }
    #pragma unroll
    for (int m = 0; m < 4; ++m)
      #pragma unroll
      for (int n = 0; n < 4; ++n)
        acc[m][n] = __builtin_amdgcn_mfma_f32_16x16x32_bf16(af[m], bw[n], acc[m][n], 0, 0, 0);
  }

  #pragma unroll
  for (int n = 0; n < 4; ++n) {
    const float b = bias[o0 + wn + n * 16 + lr];
    #pragma unroll
    for (int m = 0; m < 4; ++m) {
      const long rowb = s0 + wm + m * 16 + lk * 4;
      #pragma unroll
      for (int r = 0; r < 4; ++r)
        C[(rowb + r) * (long)NOUT + o0 + wn + n * 16 + lr] = acc[m][n][r] + b;
    }
  }
}

// ---------------- fused attention core ----------------
__global__ __launch_bounds__(256) void k_core(
    const float* __restrict__ raw, const float* __restrict__ qsrc,
    const float* __restrict__ g, const float* __restrict__ wq,
    const float* __restrict__ cq, const float* __restrict__ Wv,
    const float* __restrict__ bv, const float* __restrict__ gt_w,
    const float* __restrict__ gt_b, int gidx, int N,
    float* __restrict__ zout) {
  __shared__ float ally[4][16][33];
  __shared__ float gbuf[4][4][32];
  __shared__ float pbuf[4][4][16];
  __shared__ float pal[4][4][32];
  __shared__ float qbk[4][4];
  __shared__ float mfv[4][16];
  const int tid = threadIdx.x;
  const int w = tid >> 6, l = tid & 63;
  const long s = (long)blockIdx.x * 4 + w;
  const int NR = N * 32;
  const float* rs = raw + s * NR;
  for (int i = l; i < NR; i += 64) ally[w][i >> 5][i & 31] = rs[i];
  const float* grow = g + s * 256;
  for (int jj = l; jj < 128; jj += 64) gbuf[w][jj >> 5][jj & 31] = grow[jj];
  __syncthreads();
  bool valid = false;
  if (l < N) {
    #pragma unroll
    for (int j = 0; j < 32; ++j) valid |= (ally[w][l][j] != 0.f);
  }
  unsigned long long bal = __ballot(l < N && valid);
  float cnt = (float)__popcll(bal);
  float x = gt_w[gidx] * log1pf(cnt) + gt_b[gidx];
  float sp = fmaxf(x, 0.f) + log1pf(expf(-fabsf(x)));
  float scale = 1.f / (8.f * (sp + 1.f));
  if (l < 16) mfv[w][l] = (l < N && valid) ? 1.f : 0.f;
  const float* qrow = qsrc + s * 256;
  {
    int h = l >> 4, i = l & 15;
    float acc = 0.f;
    #pragma unroll
    for (int t = 0; t < 16; ++t) {
      int c = i + t * 16;
      acc += qrow[c] * wq[h * 256 + c];
    }
    acc += __shfl_xor(acc, 8);
    acc += __shfl_xor(acc, 4);
    acc += __shfl_xor(acc, 2);
    acc += __shfl_xor(acc, 1);
    if (i == 0) qbk[w][h] = acc + cq[h];
  }
  __syncthreads();
  {
    int h = l >> 4, n = l & 15;
    float sv = -INFINITY;
    if (n < N && mfv[w][n] != 0.f) {
      float acc = 0.f;
      #pragma unroll
      for (int j = 0; j < 32; ++j) acc += gbuf[w][h][j] * ally[w][n][j];
      sv = (acc + qbk[w][h]) * scale;
    }
    float m = sv;
    m = fmaxf(m, __shfl_xor(m, 8));
    m = fmaxf(m, __shfl_xor(m, 4));
    m = fmaxf(m, __shfl_xor(m, 2));
    m = fmaxf(m, __shfl_xor(m, 1));
    float e = (sv == -INFINITY) ? 0.f : expf(sv - m);
    float su = e;
    su += __shfl_xor(su, 8);
    su += __shfl_xor(su, 4);
    su += __shfl_xor(su, 2);
    su += __shfl_xor(su, 1);
    pbuf[w][h][n] = e / su;
  }
  __syncthreads();
  #pragma unroll
  for (int rep = 0; rep < 2; ++rep) {
    int h = rep * 2 + (l >> 5);
    int j = l & 31;
    float acc = 0.f;
    for (int n = 0; n < N; ++n) acc += pbuf[w][h][n] * ally[w][n][j];
    pal[w][h][j] = acc;
  }
  __syncthreads();
  float* zrow = zout + s * 256;
  #pragma unroll
  for (int rep = 0; rep < 4; ++rep) {
    int d = rep * 64 + l;
    float acc = bv[d];
    #pragma unroll
    for (int j = 0; j < 32; ++j) acc += Wv[d * 32 + j] * pal[w][rep][j];
    zrow[d] = acc;
  }
}

// ---------------- conditional layernorm ----------------
__global__ __launch_bounds__(256) void k_cln(
    const float* __restrict__ xin, const float* __restrict__ gb,
    float* __restrict__ out) {
  int w = threadIdx.x >> 6, l = threadIdx.x & 63;
  long s = (long)blockIdx.x * 4 + w;
  const float* xr = xin + s * 256;
  float v[4], sum = 0.f, ssq = 0.f;
  #pragma unroll
  for (int t = 0; t < 4; ++t) {
    v[t] = xr[l + t * 64];
    sum += v[t]; ssq += v[t] * v[t];
  }
  #pragma unroll
  for (int off = 32; off > 0; off >>= 1) {
    sum += __shfl_xor(sum, off);
    ssq += __shfl_xor(ssq, off);
  }
  float mu = sum * (1.f / 256.f);
  float var = ssq * (1.f / 256.f) - mu * mu;
  float rstd = rsqrtf(var + 1e-5f);
  const float* gbr = gb + s * 512;
  float* orow = out + s * 256;
  #pragma unroll
  for (int t = 0; t < 4; ++t) {
    int d = l + t * 64;
    orow[d] = (1.f + gbr[d]) * ((v[t] - mu) * rstd) + gbr[256 + d];
  }
}

// ---------------- LN over concat ----------------
__global__ __launch_bounds__(256) void k_ln3(
    const float* __restrict__ q, const float* __restrict__ zA,
    const float* __restrict__ zE, const float* __restrict__ g,
    const float* __restrict__ b, float* __restrict__ u) {
  int w = threadIdx.x >> 6, l = threadIdx.x & 63;
  long s = (long)blockIdx.x * 4 + w;
  float v[12], sum = 0.f, ssq = 0.f;
  #pragma unroll
  for (int t = 0; t < 12; ++t) {
    int i = l + t * 64;
    float val;
    if (i < 256)      val = q[s * 256 + i];
    else if (i < 512) val = zA[s * 256 + i - 256];
    else              val = zE[s * 256 + i - 512];
    v[t] = val; sum += val; ssq += val * val;
  }
  #pragma unroll
  for (int off = 32; off > 0; off >>= 1) {
    sum += __shfl_xor(sum, off);
    ssq += __shfl_xor(ssq, off);
  }
  float mu = sum * (1.f / 768.f);
  float var = ssq * (1.f / 768.f) - mu * mu;
  float rstd = rsqrtf(var + 1e-5f);
  #pragma unroll
  for (int t = 0; t < 12; ++t) {
    int i = l + t * 64;
    u[s * 768 + i] = (v[t] - mu) * rstd * g[i] + b[i];
  }
}

// ---------------- GRU elementwise ----------------
__global__ __launch_bounds__(256) void k_gru(
    const float* __restrict__ gi, const float* __restrict__ gh,
    const float* __restrict__ hid, float* __restrict__ hout) {
  long gidx = (long)blockIdx.x * 256 + threadIdx.x;
  long s = gidx >> 8; int d = gidx & 255;
  const float* gir = gi + s * 768;
  const float* ghr = gh + s * 768;
  float ir = gir[d], iz = gir[256 + d], inn = gir[512 + d];
  float hr = ghr[d], hz = ghr[256 + d], hn = ghr[512 + d];
  float r  = 1.f / (1.f + expf(-(ir + hr)));
  float zg = 1.f / (1.f + expf(-(iz + hz)));
  float n  = tanhf(inn + r * hn);
  hout[gidx] = (1.f - zg) * n + zg * hid[gidx];
}

// ---------------- Q heads ----------------
__global__ __launch_bounds__(256) void k_heads(
    const float* __restrict__ h, const float* __restrict__ eraw,
    const float* __restrict__ Wv_head, const float* __restrict__ bv_head,
    const float* __restrict__ Wtb, const float* __restrict__ btb,
    const float* __restrict__ log_tau, const float* __restrict__ FW,
    float* __restrict__ Qout) {
  __shared__ float hb[4][256];
  __shared__ float ob[4][48];
  int w = threadIdx.x >> 6, l = threadIdx.x & 63;
  long s = (long)blockIdx.x * 4 + w;
  const float* hr = h + s * 256;
  #pragma unroll
  for (int t = 0; t < 4; ++t) hb[w][l + t * 64] = hr[l + t * 64];
  __syncthreads();
  if (l < 42) {
    const float* wr; float b;
    if (l == 0)      { wr = Wv_head;                      b = bv_head[0]; }
    else if (l == 1) { wr = Wtb;                          b = btb[0]; }
    else if (l == 2) { wr = Wtb + 256;                    b = btb[1]; }
    else if (l < 9)  { wr = FW + WMP_OFF + (l - 3) * 256; b = FW[BMP_OFF + l - 3]; }
    else if (l < 41) { wr = FW + G_OFF + (l - 9) * 256;   b = FW[BG_OFF + l - 9]; }
    else             { wr = FW + WQB_OFF;                 b = FW[SC0_OFF]; }
    float acc = b;
    for (int c = 0; c < 256; ++c) acc += wr[c] * hb[w][c];
    ob[w][l] = acc;
  }
  __syncthreads();
  float itm = 1.f / (expf(log_tau[0]) + 1e-6f);
  float its = 1.f / (expf(log_tau[1]) + 1e-6f);
  float V = ob[w][0];
  if (l < 16) {
    const float* er = eraw + s * 512 + l * 32;
    bool valid = false; float acc = 0.f;
    #pragma unroll
    for (int j = 0; j < 32; ++j) {
      float e = er[j];
      valid |= (e != 0.f);
      acc += ob[w][9 + j] * e;
    }
    float a = (acc + ob[w][41]) * 0.0625f;
    float sa = valid ? a : 0.f;
    float cv = valid ? 1.f : 0.f;
    #pragma unroll
    for (int off = 8; off > 0; off >>= 1) {
      sa += __shfl_xor(sa, off);
      cv += __shfl_xor(cv, off);
    }
    float me = sa / fmaxf(cv, 1.f);
    float qs = V + ob[w][2] + (valid ? (a - me) * its : -1e30f * its);
    Qout[s * 22 + 6 + l] = qs;
  } else if (l < 22) {
    int i = l - 16;
    float mean = 0.f;
    #pragma unroll
    for (int t = 0; t < 6; ++t) mean += ob[w][3 + t];
    mean *= (1.f / 6.f);
    float qm = V + ob[w][1] + (ob[w][3 + i] - mean) * 0.0625f * itm;
    Qout[s * 22 + i] = qm;
  }
}

// ---------------- launch ----------------
extern "C" void kernel_launch(void* const* d_in, const int* in_sizes, int n_in,
                              void* d_out, int out_size, void* d_ws, size_t ws_size,
                              hipStream_t stream) {
  const float* own_raw   = (const float*)d_in[0];
  const float* ally_raw  = (const float*)d_in[1];
  const float* enemy_raw = (const float*)d_in[2];
  const float* hidden    = (const float*)d_in[3];
  const float* W_own     = (const float*)d_in[4];
  const float* b_own     = (const float*)d_in[5];
  const float* gt_w      = (const float*)d_in[10];
  const float* gt_b      = (const float*)d_in[11];
  const float* attnA_W   = (const float*)d_in[12];
  const float* attnA_b   = (const float*)d_in[13];
  const float* attnE_W   = (const float*)d_in[14];
  const float* attnE_b   = (const float*)d_in[15];
  const float* clnA_W    = (const float*)d_in[16];
  const float* clnA_b    = (const float*)d_in[17];
  const float* clnE_W    = (const float*)d_in[18];
  const float* clnE_b    = (const float*)d_in[19];
  const float* ln3_g     = (const float*)d_in[20];
  const float* ln3_b     = (const float*)d_in[21];
  const float* gru_Wih   = (const float*)d_in[22];
  const float* gru_Whh   = (const float*)d_in[23];
  const float* gru_bih   = (const float*)d_in[24];
  const float* gru_bhh   = (const float*)d_in[25];
  const float* Wv_head   = (const float*)d_in[26];
  const float* bv_head   = (const float*)d_in[27];
  const float* Wtb       = (const float*)d_in[28];
  const float* btb       = (const float*)d_in[29];
  const float* log_tau   = (const float*)d_in[30];
  const float* Wmq       = (const float*)d_in[31];
  const float* bmq       = (const float*)d_in[32];
  const float* protos    = (const float*)d_in[33];
  const float* Wqs       = (const float*)d_in[34];
  const float* bqs       = (const float*)d_in[35];
  const float* Wke       = (const float*)d_in[36];
  const float* bke       = (const float*)d_in[37];
  const float* W_ally    = (const float*)d_in[6];
  const float* b_ally    = (const float*)d_in[7];
  const float* W_enemy   = (const float*)d_in[8];
  const float* b_enemy   = (const float*)d_in[9];

  float* ws  = (float*)d_ws;
  float* out = (float*)d_out;
  float* hout = out + HOFF;
  // bf16 weight cache: scratch inside d_out's h region (overwritten by k_gru at the end)
  unsigned short* WB = (unsigned short*)hout;
  unsigned short* qsb = (unsigned short*)(ws + BUF2_OFF);

  k_fuse1<<<160, 256, 0, stream>>>(attnA_W, attnA_b, attnE_W, attnE_b,
                                   W_ally, b_ally, W_enemy, b_enemy, Wke, bke, ws);
  k_fuse2<<<40, 256, 0, stream>>>(protos, Wmq, bmq, Wqs, bqs, ws);
  k_fuse3<<<266, 256, 0, stream>>>(attnA_W, attnA_b, attnE_W, attnE_b, ws, WB + MGB_S);
  k_cvt<<<1152, 256, 0, stream>>>(gru_Wih, gru_Whh, clnA_W, clnE_W,
                                  attnA_W + 196608, attnE_W + 196608, WB);

  // q_src (f32 + bf16)
  k_densek<30, 256><<<dim3(BN/64, 4), 256, 0, stream>>>(own_raw, W_own, b_own,
                                                        ws + QSRC_OFF, qsb);

  // g = q_src @ Mg.T + bMg ; cln gamma/beta
  k_mm<256, 256, true><<<dim3(2, 128), 256, 0, stream>>>(qsb, WB + MGB_S, ws + BMG_OFF, ws + GBUF_OFF);
  k_mm<256, 512, true><<<dim3(4, 128), 256, 0, stream>>>(qsb, WB + CLA_S, clnA_b, ws + GBA_OFF);
  k_mm<256, 512, true><<<dim3(4, 128), 256, 0, stream>>>(qsb, WB + CLE_S, clnE_b, ws + GBE_OFF);

  // attention cores
  k_core<<<BN/4, 256, 0, stream>>>(ally_raw, ws + QSRC_OFF, ws + GBUF_OFF,
                                   ws + WQA_OFF, ws + CQA_OFF, ws + WVA_OFF, ws + BVA_OFF,
                                   gt_w, gt_b, 0, 15, ws + ZRAWA_OFF);
  k_core<<<BN/4, 256, 0, stream>>>(enemy_raw, ws + QSRC_OFF, ws + GBUF_OFF + 128,
                                   ws + WQE_OFF, ws + CQE_OFF, ws + WVE_OFF, ws + BVE_OFF,
                                   gt_w, gt_b, 1, 16, ws + ZRAWE_OFF);

  // output projections
  k_mm<256, 256, false><<<dim3(2, 128), 256, 0, stream>>>(ws + ZRAWA_OFF, WB + PJA_S, attnA_b + 768, ws + AOUTA_OFF);
  k_mm<256, 256, false><<<dim3(2, 128), 256, 0, stream>>>(ws + ZRAWE_OFF, WB + PJE_S, attnE_b + 768, ws + AOUTE_OFF);

  // conditional layernorms
  k_cln<<<BN/4, 256, 0, stream>>>(ws + AOUTA_OFF, ws + GBA_OFF, ws + ZA_OFF);
  k_cln<<<BN/4, 256, 0, stream>>>(ws + AOUTE_OFF, ws + GBE_OFF, ws + ZE_OFF);

  // u = LN(concat)
  k_ln3<<<BN/4, 256, 0, stream>>>(ws + QSRC_OFF, ws + ZA_OFF, ws + ZE_OFF, ln3_g, ln3_b, ws + U_OFF);

  // GRU gates
  k_mm<768, 768, false><<<dim3(6, 128), 256, 0, stream>>>(ws + U_OFF, WB + WIH_S, gru_bih, ws + GI_OFF);
  k_mm<256, 768, false><<<dim3(6, 128), 256, 0, stream>>>(hidden, WB + WHH_S, gru_bhh, ws + GH_OFF);
  k_gru<<<BN, 256, 0, stream>>>(ws + GI_OFF, ws + GH_OFF, hidden, hout);

  // heads
  k_heads<<<BN/4, 256, 0, stream>>>(hout, enemy_raw, Wv_head, bv_head, Wtb, btb,
                                    log_tau, ws, out);
}

// Round 4
// 410.884 us; speedup vs baseline: 6.9326x; 1.2191x over previous
//
#include <hip/hip_runtime.h>
#include <math.h>

#define BN 16384

typedef float f32x4 __attribute__((ext_vector_type(4)));
typedef short bf16x8v __attribute__((ext_vector_type(8)));
typedef unsigned short u16x8 __attribute__((ext_vector_type(8)));
typedef unsigned short u16x4 __attribute__((ext_vector_type(4)));

static __device__ inline unsigned short f2bf(float f) {
  unsigned u = __float_as_uint(f);
  return (unsigned short)((u + 0x8000u) >> 16);
}

// ---------------- workspace float offsets ----------------
#define WKA_OFF   0
#define WVA_OFF   8192
#define WKE_OFF   16384
#define WVE_OFF   24576
#define WKEF_OFF  32768
#define BKA_OFF   40960
#define BVA_OFF   41216
#define BKE_OFF   41472
#define BVE_OFF   41728
#define BKEF_OFF  41984
#define WMP_OFF   43008
#define BMP_OFF   44544
#define G_OFF     45056
#define BG_OFF    53248
#define WQB_OFF   53312
#define SC0_OFF   53568
#define BMG_OFF   53632
#define WQA_OFF   53888
#define CQA_OFF   54912
#define WQE_OFF   54976
#define CQE_OFF   56000
#define CLB_OFF   56064   /* 1024 floats: clnA_b ++ clnE_b */
// heads fold (written by k_fuse4 AFTER cores; overlaps WKA/WVA/WKE regions)
#define BHD_OFF   16384   /* 128 floats bias */
// WHD bf16 weights: shorts at float offset 0 (32768 shorts = 16384 floats)

#define QSRC_OFF  65536
#define BUF1_OFF  (QSRC_OFF + BN*256)
#define BUF2_OFF  (BUF1_OFF + BN*256)
#define BUF3_OFF  (BUF2_OFF + BN*256)
#define BUF4_OFF  (BUF3_OFF + BN*256)
#define BUF5_OFF  (BUF4_OFF + BN*256)   /* BN*1024 region */

#define GBUF_OFF  BUF1_OFF   // g (gA|gE) for cores
#define ZRAWA_OFF BUF3_OFF
#define ZRAWE_OFF BUF4_OFF
#define AOUTA_OFF BUF1_OFF
#define AOUTE_OFF BUF2_OFF
#define GB_OFF    BUF5_OFF   // [BN][1024] gamma/beta both branches; U written in-place stride 1024
#define U_OFF     BUF5_OFF
#define GI_OFF    BUF1_OFF   // BN*768 across BUF1..BUF3
#define GH_OFF    BUF4_OFF   // BN*768 across BUF4 + BUF5[0:512] (U dead by then)
#define OB_OFF    BUF1_OFF   // [BN][128] heads pre-products

#define HOFF      (BN*22)

// bf16 weight cache in d_out's h-region (dead until k_gru writes it)
#define WIH_S 0
#define WHH_S 589824
#define CLA_S 786432
#define CLE_S 917504
#define PJA_S 1048576
#define PJE_S 1114112
#define MGB_S 1179648

// ---------------- fused small-weight precompute ----------------
__global__ __launch_bounds__(256) void k_fuse1(
    const float* __restrict__ attnA_W, const float* __restrict__ attnA_b,
    const float* __restrict__ attnE_W, const float* __restrict__ attnE_b,
    const float* __restrict__ W_ally,  const float* __restrict__ b_ally,
    const float* __restrict__ W_enemy, const float* __restrict__ b_enemy,
    const float* __restrict__ Wke,     const float* __restrict__ bke,
    float* __restrict__ FW) {
  int g = blockIdx.x * 256 + threadIdx.x;
  if (g >= 40960) return;
  int m = g >> 13;
  int r = g & 8191;
  int d = r >> 5, j = r & 31;
  const float *Wout, *Win, *bin, *bout; float *dst, *dstb;
  switch (m) {
    case 0: Wout = attnA_W + 65536;  Win = W_ally;  bin = b_ally;  bout = attnA_b + 256; dst = FW + WKA_OFF;  dstb = FW + BKA_OFF;  break;
    case 1: Wout = attnA_W + 131072; Win = W_ally;  bin = b_ally;  bout = attnA_b + 512; dst = FW + WVA_OFF;  dstb = FW + BVA_OFF;  break;
    case 2: Wout = attnE_W + 65536;  Win = W_enemy; bin = b_enemy; bout = attnE_b + 256; dst = FW + WKE_OFF;  dstb = FW + BKE_OFF;  break;
    case 3: Wout = attnE_W + 131072; Win = W_enemy; bin = b_enemy; bout = attnE_b + 512; dst = FW + WVE_OFF;  dstb = FW + BVE_OFF;  break;
    default:Wout = Wke;              Win = W_enemy; bin = b_enemy; bout = bke;           dst = FW + WKEF_OFF; dstb = FW + BKEF_OFF; break;
  }
  float acc = 0.f;
  for (int c = 0; c < 256; ++c) acc += Wout[d*256 + c] * Win[c*32 + j];
  dst[d*32 + j] = acc;
  if (j == 0) {
    float b = bout[d];
    for (int c = 0; c < 256; ++c) b += Wout[d*256 + c] * bin[c];
    dstb[d] = b;
  }
}

__global__ __launch_bounds__(256) void k_fuse2(
    const float* __restrict__ protos, const float* __restrict__ Wmq,
    const float* __restrict__ bmq,    const float* __restrict__ Wqs,
    const float* __restrict__ bqs,    float* __restrict__ FW) {
  int g = blockIdx.x * 256 + threadIdx.x;
  const float* WKe_f = FW + WKEF_OFF;
  const float* bKe_f = FW + BKEF_OFF;
  if (g < 1536) {
    int i = g >> 8, c = g & 255;
    float acc = 0.f;
    for (int d = 0; d < 256; ++d) acc += protos[i*256 + d] * Wmq[d*256 + c];
    FW[WMP_OFF + i*256 + c] = acc;
  } else if (g < 9728) {
    int r = g - 1536;
    int j = r >> 8, c = r & 255;
    float acc = 0.f;
    for (int d = 0; d < 256; ++d) acc += WKe_f[d*32 + j] * Wqs[d*256 + c];
    FW[G_OFF + j*256 + c] = acc;
  } else if (g < 9984) {
    int c = g - 9728;
    float acc = 0.f;
    for (int d = 0; d < 256; ++d) acc += Wqs[d*256 + c] * bKe_f[d];
    FW[WQB_OFF + c] = acc;
  } else if (g < 9990) {
    int i = g - 9984;
    float acc = 0.f;
    for (int d = 0; d < 256; ++d) acc += protos[i*256 + d] * bmq[d];
    FW[BMP_OFF + i] = acc;
  } else if (g < 10022) {
    int j = g - 9990;
    float acc = 0.f;
    for (int d = 0; d < 256; ++d) acc += WKe_f[d*32 + j] * bqs[d];
    FW[BG_OFF + j] = acc;
  } else if (g == 10022) {
    float acc = 0.f;
    for (int d = 0; d < 256; ++d) acc += bqs[d] * bKe_f[d];
    FW[SC0_OFF] = acc;
  }
}

// fold q_src->g matrix (bf16) + bias; qbk vectors; CLB bias concat
__global__ __launch_bounds__(256) void k_fuse3(
    const float* __restrict__ attnA_W, const float* __restrict__ attnA_b,
    const float* __restrict__ attnE_W, const float* __restrict__ attnE_b,
    const float* __restrict__ clnA_b,  const float* __restrict__ clnE_b,
    float* __restrict__ FW, unsigned short* __restrict__ MGB) {
  int g = blockIdx.x * 256 + threadIdx.x;
  if (g < 65536) {
    int r = g >> 8, c = g & 255;
    int br = r >> 7, jj = r & 127, h = jj >> 5, jc = jj & 31;
    const float* W0 = br ? attnE_W : attnA_W;
    const float* Wk = FW + (br ? WKE_OFF : WKA_OFF);
    float acc = 0.f;
    for (int d = 0; d < 64; ++d)
      acc += W0[(h*64+d)*256 + c] * Wk[(h*64+d)*32 + jc];
    MGB[r*256 + c] = f2bf(acc);
  } else if (g < 65792) {
    int r = g - 65536;
    int br = r >> 7, jj = r & 127, h = jj >> 5, jc = jj & 31;
    const float* b0 = br ? attnE_b : attnA_b;
    const float* Wk = FW + (br ? WKE_OFF : WKA_OFF);
    float acc = 0.f;
    for (int d = 0; d < 64; ++d) acc += b0[h*64+d] * Wk[(h*64+d)*32 + jc];
    FW[BMG_OFF + r] = acc;
  } else if (g < 67840) {
    int r = g - 65792;
    int br = r >> 10, h = (r >> 8) & 3, c = r & 255;
    const float* W0 = br ? attnE_W : attnA_W;
    const float* bk = FW + (br ? BKE_OFF : BKA_OFF);
    float acc = 0.f;
    for (int d = 0; d < 64; ++d) acc += W0[(h*64+d)*256 + c] * bk[h*64+d];
    FW[(br ? WQE_OFF : WQA_OFF) + h*256 + c] = acc;
  } else if (g < 67848) {
    int r = g - 67840;
    int br = r >> 2, h = r & 3;
    const float* b0 = br ? attnE_b : attnA_b;
    const float* bk = FW + (br ? BKE_OFF : BKA_OFF);
    float acc = 0.f;
    for (int d = 0; d < 64; ++d) acc += b0[h*64+d] * bk[h*64+d];
    FW[(br ? CQE_OFF : CQA_OFF) + h] = acc;
  } else if (g < 68872) {
    int c = g - 67848;
    FW[CLB_OFF + c] = (c < 512) ? clnA_b[c] : clnE_b[c - 512];
  }
}

// heads fold: WHD[128][256] bf16 + BHD[128] (runs AFTER cores; writes FW[0..16512))
__global__ __launch_bounds__(256) void k_fuse4(
    const float* __restrict__ Wv_head, const float* __restrict__ bv_head,
    const float* __restrict__ Wtb, const float* __restrict__ btb,
    float* __restrict__ FW, unsigned short* __restrict__ WHD) {
  int g = blockIdx.x * 256 + threadIdx.x;  // 32768 + 128
  if (g < 32768) {
    int r = g >> 8, c = g & 255;
    float v;
    if (r == 0)       v = Wv_head[c];
    else if (r == 1)  v = Wtb[c];
    else if (r == 2)  v = Wtb[256 + c];
    else if (r < 9)   v = FW[WMP_OFF + (r - 3) * 256 + c];
    else if (r < 41)  v = FW[G_OFF + (r - 9) * 256 + c];
    else if (r == 41) v = FW[WQB_OFF + c];
    else              v = 0.f;
    WHD[r * 256 + c] = f2bf(v);
  } else if (g < 32896) {
    int r = g - 32768;
    float v;
    if (r == 0)       v = bv_head[0];
    else if (r == 1)  v = btb[0];
    else if (r == 2)  v = btb[1];
    else if (r < 9)   v = FW[BMP_OFF + r - 3];
    else if (r < 41)  v = FW[BG_OFF + r - 9];
    else if (r == 41) v = FW[SC0_OFF];
    else              v = 0.f;
    FW[BHD_OFF + r] = v;
  }
}

// ---------------- f32->bf16 weight conversion ----------------
__global__ __launch_bounds__(256) void k_cvt(
    const float* __restrict__ w0, const float* __restrict__ w1,
    const float* __restrict__ w2, const float* __restrict__ w3,
    const float* __restrict__ w4, const float* __restrict__ w5,
    unsigned short* __restrict__ dst) {
  int e = (blockIdx.x * 256 + threadIdx.x) * 4;
  const float* src; int off;
  if (e < 589824)       { src = w0; off = 0; }
  else if (e < 786432)  { src = w1; off = 589824; }
  else if (e < 917504)  { src = w2; off = 786432; }
  else if (e < 1048576) { src = w3; off = 917504; }
  else if (e < 1114112) { src = w4; off = 1048576; }
  else                  { src = w5; off = 1114112; }
  float4 v = *(const float4*)(src + (e - off));
  u16x4 b; b.x = f2bf(v.x); b.y = f2bf(v.y); b.z = f2bf(v.z); b.w = f2bf(v.w);
  *(u16x4*)&dst[e] = b;
}

// ---------------- small-K dense (K=30), dual f32+bf16 output ----------------
template<int K, int NOUT>
__global__ __launch_bounds__(256) void k_densek(
    const float* __restrict__ A, const float* __restrict__ W,
    const float* __restrict__ bias, float* __restrict__ C,
    unsigned short* __restrict__ Cb) {
  constexpr int KB = 32;
  __shared__ float As[64][36];
  const int tid = threadIdx.x;
  const int s0 = blockIdx.x * 64;
  const int o0 = blockIdx.y * 64;
  const int ox = (tid & 15) * 4;
  const int sy = (tid >> 4) * 4;
  float acc[4][4] = {};
  const float* Abase = A + (long)s0 * K;
  for (int idx = tid; idx < 64 * KB; idx += 256) {
    int s = idx >> 5, c = idx & 31;
    As[s][c] = (c < K) ? Abase[(long)s * K + c] : 0.f;
  }
  __syncthreads();
  for (int kk = 0; kk < KB; kk += 4) {
    float a4[4][4];
    #pragma unroll
    for (int sj = 0; sj < 4; ++sj)
      *(float4*)a4[sj] = *(const float4*)&As[sy + sj][kk];
    #pragma unroll
    for (int oi = 0; oi < 4; ++oi) {
      float w4[4];
      #pragma unroll
      for (int kx = 0; kx < 4; ++kx) {
        int k = kk + kx;
        w4[kx] = (k < K) ? W[(long)(o0 + ox + oi) * K + k] : 0.f;
      }
      #pragma unroll
      for (int sj = 0; sj < 4; ++sj)
        #pragma unroll
        for (int kx = 0; kx < 4; ++kx)
          acc[sj][oi] = fmaf(a4[sj][kx], w4[kx], acc[sj][oi]);
    }
  }
  #pragma unroll
  for (int sj = 0; sj < 4; ++sj) {
    float4 o4;
    o4.x = acc[sj][0] + bias[o0 + ox + 0];
    o4.y = acc[sj][1] + bias[o0 + ox + 1];
    o4.z = acc[sj][2] + bias[o0 + ox + 2];
    o4.w = acc[sj][3] + bias[o0 + ox + 3];
    *(float4*)&C[(long)(s0 + sy + sj) * NOUT + o0 + ox] = o4;
    u16x4 b4; b4.x = f2bf(o4.x); b4.y = f2bf(o4.y); b4.z = f2bf(o4.z); b4.w = f2bf(o4.w);
    *(u16x4*)&Cb[(long)(s0 + sy + sj) * NOUT + o0 + ox] = b4;
  }
}

// ---------------- MFMA dense ----------------
template<int K, int LDA, int NOUT, bool ABF>
__global__ __launch_bounds__(256) void k_mm(
    const void* __restrict__ Ap, const unsigned short* __restrict__ W,
    const float* __restrict__ bias, float* __restrict__ C) {
  constexpr int NCH = K / 32;
  __shared__ __align__(16) unsigned short As[4096];
  __shared__ __align__(16) unsigned short Ws[4096];
  const int tid = threadIdx.x;
  const int o0 = blockIdx.x * 128;
  const long s0 = (long)blockIdx.y * 128;
  const int wv = tid >> 6, l = tid & 63;
  const int wm = (wv >> 1) * 64, wn = (wv & 1) * 64;
  const int lr = l & 15, lk = l >> 4;

  const int wrow = tid >> 2;
  const int wslot = tid & 3;
  const int q = tid & 3;

  f32x4 acc[4][4] = {};
  u16x8 pw[2];
  u16x8 pa_b[2];
  float4 pa_f[2][2];

  const unsigned short* Wb = W + (long)o0 * K;
  const unsigned short* Abf = (const unsigned short*)Ap;
  const float* Aff = (const float*)Ap;

  #pragma unroll
  for (int p = 0; p < 2; ++p) {
    const int r = wrow + 64 * p;
    pw[p] = *(const u16x8*)(Wb + (long)r * K + wslot * 8);
    if constexpr (ABF) {
      pa_b[p] = *(const u16x8*)(Abf + (s0 + r) * LDA + wslot * 8);
    } else {
      const float* Af = Aff + (s0 + r) * LDA + q * 4;
      pa_f[p][0] = *(const float4*)(Af);
      pa_f[p][1] = *(const float4*)(Af + 16);
    }
  }

  for (int ch = 0; ch < NCH; ++ch) {
    if (ch) __syncthreads();
    #pragma unroll
    for (int p = 0; p < 2; ++p) {
      const int r = wrow + 64 * p;
      const int ps = (wslot ^ (r & 3)) * 8;
      *(u16x8*)&Ws[r * 32 + ps] = pw[p];
      if constexpr (ABF) {
        *(u16x8*)&As[r * 32 + ps] = pa_b[p];
      } else {
        #pragma unroll
        for (int j = 0; j < 2; ++j) {
          float4 v = pa_f[p][j];
          unsigned long long pk =
              (unsigned long long)f2bf(v.x) |
              ((unsigned long long)f2bf(v.y) << 16) |
              ((unsigned long long)f2bf(v.z) << 32) |
              ((unsigned long long)f2bf(v.w) << 48);
          const int slot = (j * 2 + (q >> 1)) ^ (r & 3);
          *(unsigned long long*)&As[r * 32 + slot * 8 + (q & 1) * 4] = pk;
        }
      }
    }
    __syncthreads();
    if (ch + 1 < NCH) {
      const int k0 = (ch + 1) * 32;
      #pragma unroll
      for (int p = 0; p < 2; ++p) {
        const int r = wrow + 64 * p;
        pw[p] = *(const u16x8*)(Wb + (long)r * K + k0 + wslot * 8);
        if constexpr (ABF) {
          pa_b[p] = *(const u16x8*)(Abf + (s0 + r) * LDA + k0 + wslot * 8);
        } else {
          const float* Af = Aff + (s0 + r) * LDA + k0 + q * 4;
          pa_f[p][0] = *(const float4*)(Af);
          pa_f[p][1] = *(const float4*)(Af + 16);
        }
      }
    }
    bf16x8v af[4], bw[4];
    #pragma unroll
    for (int m = 0; m < 4; ++m) {
      const int r = wm + m * 16 + lr;
      af[m] = *(const bf16x8v*)&As[r * 32 + ((lk ^ (r & 3)) * 8)];
    }
    #pragma unroll
    for (int n = 0; n < 4; ++n) {
      const int r = wn + n * 16 + lr;
      bw[n] = *(const bf16x8v*)&Ws[r * 32 + ((lk ^ (r & 3)) * 8)];
    }
    #pragma unroll
    for (int m = 0; m < 4; ++m)
      #pragma unroll
      for (int n = 0; n < 4; ++n)
        acc[m][n] = __builtin_amdgcn_mfma_f32_16x16x32_bf16(af[m], bw[n], acc[m][n], 0, 0, 0);
  }

  #pragma unroll
  for (int n = 0; n < 4; ++n) {
    const float b = bias[o0 + wn + n * 16 + lr];
    #pragma unroll
    for (int m = 0; m < 4; ++m) {
      const long rowb = s0 + wm + m * 16 + lk * 4;
      #pragma unroll
      for (int r = 0; r < 4; ++r)
        C[(rowb + r) * (long)NOUT + o0 + wn + n * 16 + lr] = acc[m][n][r] + b;
    }
  }
}

// ---------------- fused attention core ----------------
__global__ __launch_bounds__(256) void k_core(
    const float* __restrict__ raw, const float* __restrict__ qsrc,
    const float* __restrict__ g, const float* __restrict__ wq,
    const float* __restrict__ cq, const float* __restrict__ Wv,
    const float* __restrict__ bv, const float* __restrict__ gt_w,
    const float* __restrict__ gt_b, int gidx, int N,
    float* __restrict__ zout) {
  __shared__ float ally[4][16][33];
  __shared__ float gbuf[4][4][32];
  __shared__ float pbuf[4][4][16];
  __shared__ float pal[4][4][32];
  __shared__ float qbk[4][4];
  __shared__ float mfv[4][16];
  const int tid = threadIdx.x;
  const int w = tid >> 6, l = tid & 63;
  const long s = (long)blockIdx.x * 4 + w;
  const int NR = N * 32;
  const float* rs = raw + s * NR;
  for (int i = l; i < NR; i += 64) ally[w][i >> 5][i & 31] = rs[i];
  const float* grow = g + s * 256;
  for (int jj = l; jj < 128; jj += 64) gbuf[w][jj >> 5][jj & 31] = grow[jj];
  __syncthreads();
  bool valid = false;
  if (l < N) {
    #pragma unroll
    for (int j = 0; j < 32; ++j) valid |= (ally[w][l][j] != 0.f);
  }
  unsigned long long bal = __ballot(l < N && valid);
  float cnt = (float)__popcll(bal);
  float x = gt_w[gidx] * log1pf(cnt) + gt_b[gidx];
  float sp = fmaxf(x, 0.f) + log1pf(expf(-fabsf(x)));
  float scale = 1.f / (8.f * (sp + 1.f));
  if (l < 16) mfv[w][l] = (l < N && valid) ? 1.f : 0.f;
  const float* qrow = qsrc + s * 256;
  {
    int h = l >> 4, i = l & 15;
    float acc = 0.f;
    #pragma unroll
    for (int t = 0; t < 16; ++t) {
      int c = i + t * 16;
      acc += qrow[c] * wq[h * 256 + c];
    }
    acc += __shfl_xor(acc, 8);
    acc += __shfl_xor(acc, 4);
    acc += __shfl_xor(acc, 2);
    acc += __shfl_xor(acc, 1);
    if (i == 0) qbk[w][h] = acc + cq[h];
  }
  __syncthreads();
  {
    int h = l >> 4, n = l & 15;
    float sv = -INFINITY;
    if (n < N && mfv[w][n] != 0.f) {
      float acc = 0.f;
      #pragma unroll
      for (int j = 0; j < 32; ++j) acc += gbuf[w][h][j] * ally[w][n][j];
      sv = (acc + qbk[w][h]) * scale;
    }
    float m = sv;
    m = fmaxf(m, __shfl_xor(m, 8));
    m = fmaxf(m, __shfl_xor(m, 4));
    m = fmaxf(m, __shfl_xor(m, 2));
    m = fmaxf(m, __shfl_xor(m, 1));
    float e = (sv == -INFINITY) ? 0.f : expf(sv - m);
    float su = e;
    su += __shfl_xor(su, 8);
    su += __shfl_xor(su, 4);
    su += __shfl_xor(su, 2);
    su += __shfl_xor(su, 1);
    pbuf[w][h][n] = e / su;
  }
  __syncthreads();
  #pragma unroll
  for (int rep = 0; rep < 2; ++rep) {
    int h = rep * 2 + (l >> 5);
    int j = l & 31;
    float acc = 0.f;
    for (int n = 0; n < N; ++n) acc += pbuf[w][h][n] * ally[w][n][j];
    pal[w][h][j] = acc;
  }
  __syncthreads();
  float* zrow = zout + s * 256;
  #pragma unroll
  for (int rep = 0; rep < 4; ++rep) {
    int d = rep * 64 + l;
    float acc = bv[d];
    #pragma unroll
    for (int j = 0; j < 32; ++j) acc += Wv[d * 32 + j] * pal[w][rep][j];
    zrow[d] = acc;
  }
}

// ---------------- fused CLN(A)+CLN(E)+LN3 -> u (in-place into GB rows, stride 1024) ----------------
__global__ __launch_bounds__(256) void k_clnln(
    const float* __restrict__ aA, const float* __restrict__ aE,
    const float* __restrict__ qsrc, float* gbu,
    const float* __restrict__ g, const float* __restrict__ b) {
  int w = threadIdx.x >> 6, l = threadIdx.x & 63;
  long s = (long)blockIdx.x * 4 + w;
  const float* xA = aA + s * 256;
  const float* xE = aE + s * 256;
  const float* qr = qsrc + s * 256;
  float* gbr = gbu + s * 1024;

  float vA[4], vE[4], sumA = 0.f, ssqA = 0.f, sumE = 0.f, ssqE = 0.f;
  #pragma unroll
  for (int t = 0; t < 4; ++t) {
    vA[t] = xA[l + t * 64]; sumA += vA[t]; ssqA += vA[t] * vA[t];
    vE[t] = xE[l + t * 64]; sumE += vE[t]; ssqE += vE[t] * vE[t];
  }
  #pragma unroll
  for (int off = 32; off > 0; off >>= 1) {
    sumA += __shfl_xor(sumA, off); ssqA += __shfl_xor(ssqA, off);
    sumE += __shfl_xor(sumE, off); ssqE += __shfl_xor(ssqE, off);
  }
  float muA = sumA * (1.f / 256.f);
  float rstdA = rsqrtf(ssqA * (1.f / 256.f) - muA * muA + 1e-5f);
  float muE = sumE * (1.f / 256.f);
  float rstdE = rsqrtf(ssqE * (1.f / 256.f) - muE * muE + 1e-5f);

  float v[12], sum = 0.f, ssq = 0.f;
  #pragma unroll
  for (int t = 0; t < 4; ++t) {
    int d = l + t * 64;
    float qv = qr[d];
    float zA = (1.f + gbr[d])       * ((vA[t] - muA) * rstdA) + gbr[256 + d];
    float zE = (1.f + gbr[512 + d]) * ((vE[t] - muE) * rstdE) + gbr[768 + d];
    v[t] = qv; v[4 + t] = zA; v[8 + t] = zE;
    sum += qv + zA + zE;
    ssq += qv * qv + zA * zA + zE * zE;
  }
  #pragma unroll
  for (int off = 32; off > 0; off >>= 1) {
    sum += __shfl_xor(sum, off); ssq += __shfl_xor(ssq, off);
  }
  float mu = sum * (1.f / 768.f);
  float rstd = rsqrtf(ssq * (1.f / 768.f) - mu * mu + 1e-5f);
  #pragma unroll
  for (int seg = 0; seg < 3; ++seg)
    #pragma unroll
    for (int t = 0; t < 4; ++t) {
      int i = seg * 256 + l + t * 64;
      gbr[i] = (v[seg * 4 + t] - mu) * rstd * g[i] + b[i];
    }
}

// ---------------- GRU elementwise ----------------
__global__ __launch_bounds__(256) void k_gru(
    const float* __restrict__ gi, const float* __restrict__ gh,
    const float* __restrict__ hid, float* __restrict__ hout) {
  long gidx = (long)blockIdx.x * 256 + threadIdx.x;
  long s = gidx >> 8; int d = gidx & 255;
  const float* gir = gi + s * 768;
  const float* ghr = gh + s * 768;
  float ir = gir[d], iz = gir[256 + d], inn = gir[512 + d];
  float hr = ghr[d], hz = ghr[256 + d], hn = ghr[512 + d];
  float r  = 1.f / (1.f + expf(-(ir + hr)));
  float zg = 1.f / (1.f + expf(-(iz + hz)));
  float n  = tanhf(inn + r * hn);
  hout[gidx] = (1.f - zg) * n + zg * hid[gidx];
}

// ---------------- heads epilogue ----------------
__global__ __launch_bounds__(256) void k_heads2(
    const float* __restrict__ OB, const float* __restrict__ eraw,
    const float* __restrict__ log_tau, float* __restrict__ Qout) {
  __shared__ float obs[16][48];
  const int tid = threadIdx.x;
  const long s0 = (long)blockIdx.x * 16;
  for (int idx = tid; idx < 768; idx += 256)
    obs[idx / 48][idx % 48] = OB[(s0 + idx / 48) * 128 + idx % 48];
  __syncthreads();
  const int w = tid >> 4, i = tid & 15;
  const long s = s0 + w;
  const float itm = 1.f / (expf(log_tau[0]) + 1e-6f);
  const float its = 1.f / (expf(log_tau[1]) + 1e-6f);
  const float V = obs[w][0];
  // shoot: enemy i
  const float* er = eraw + s * 512 + i * 32;
  bool valid = false; float acc = 0.f;
  #pragma unroll
  for (int jb = 0; jb < 8; ++jb) {
    float4 e4 = *(const float4*)(er + jb * 4);
    valid |= (e4.x != 0.f) | (e4.y != 0.f) | (e4.z != 0.f) | (e4.w != 0.f);
    acc += obs[w][9 + jb * 4 + 0] * e4.x + obs[w][9 + jb * 4 + 1] * e4.y +
           obs[w][9 + jb * 4 + 2] * e4.z + obs[w][9 + jb * 4 + 3] * e4.w;
  }
  float a = (acc + obs[w][41]) * 0.0625f;
  float sa = valid ? a : 0.f;
  float cv = valid ? 1.f : 0.f;
  #pragma unroll
  for (int off = 8; off > 0; off >>= 1) {
    sa += __shfl_xor(sa, off);
    cv += __shfl_xor(cv, off);
  }
  float me = sa / fmaxf(cv, 1.f);
  Qout[s * 22 + 6 + i] = V + obs[w][2] + (valid ? (a - me) * its : -1e30f * its);
  if (i < 6) {
    float mean = 0.f;
    #pragma unroll
    for (int t = 0; t < 6; ++t) mean += obs[w][3 + t];
    mean *= (1.f / 6.f);
    Qout[s * 22 + i] = V + obs[w][1] + (obs[w][3 + i] - mean) * 0.0625f * itm;
  }
}

// ---------------- launch ----------------
extern "C" void kernel_launch(void* const* d_in, const int* in_sizes, int n_in,
                              void* d_out, int out_size, void* d_ws, size_t ws_size,
                              hipStream_t stream) {
  const float* own_raw   = (const float*)d_in[0];
  const float* ally_raw  = (const float*)d_in[1];
  const float* enemy_raw = (const float*)d_in[2];
  const float* hidden    = (const float*)d_in[3];
  const float* W_own     = (const float*)d_in[4];
  const float* b_own     = (const float*)d_in[5];
  const float* W_ally    = (const float*)d_in[6];
  const float* b_ally    = (const float*)d_in[7];
  const float* W_enemy   = (const float*)d_in[8];
  const float* b_enemy   = (const float*)d_in[9];
  const float* gt_w      = (const float*)d_in[10];
  const float* gt_b      = (const float*)d_in[11];
  const float* attnA_W   = (const float*)d_in[12];
  const float* attnA_b   = (const float*)d_in[13];
  const float* attnE_W   = (const float*)d_in[14];
  const float* attnE_b   = (const float*)d_in[15];
  const float* clnA_W    = (const float*)d_in[16];
  const float* clnA_b    = (const float*)d_in[17];
  const float* clnE_W    = (const float*)d_in[18];
  const float* clnE_b    = (const float*)d_in[19];
  const float* ln3_g     = (const float*)d_in[20];
  const float* ln3_b     = (const float*)d_in[21];
  const float* gru_Wih   = (const float*)d_in[22];
  const float* gru_Whh   = (const float*)d_in[23];
  const float* gru_bih   = (const float*)d_in[24];
  const float* gru_bhh   = (const float*)d_in[25];
  const float* Wv_head   = (const float*)d_in[26];
  const float* bv_head   = (const float*)d_in[27];
  const float* Wtb       = (const float*)d_in[28];
  const float* btb       = (const float*)d_in[29];
  const float* log_tau   = (const float*)d_in[30];
  const float* Wmq       = (const float*)d_in[31];
  const float* bmq       = (const float*)d_in[32];
  const float* protos    = (const float*)d_in[33];
  const float* Wqs       = (const float*)d_in[34];
  const float* bqs       = (const float*)d_in[35];
  const float* Wke       = (const float*)d_in[36];
  const float* bke       = (const float*)d_in[37];

  float* ws  = (float*)d_ws;
  float* out = (float*)d_out;
  float* hout = out + HOFF;
  unsigned short* WB  = (unsigned short*)hout;       // bf16 weight cache (dead until k_gru)
  unsigned short* qsb = (unsigned short*)(ws + BUF2_OFF);
  unsigned short* WHD = (unsigned short*)ws;          // heads weights (after cores)

  k_fuse1<<<160, 256, 0, stream>>>(attnA_W, attnA_b, attnE_W, attnE_b,
                                   W_ally, b_ally, W_enemy, b_enemy, Wke, bke, ws);
  k_fuse2<<<40, 256, 0, stream>>>(protos, Wmq, bmq, Wqs, bqs, ws);
  k_fuse3<<<270, 256, 0, stream>>>(attnA_W, attnA_b, attnE_W, attnE_b,
                                   clnA_b, clnE_b, ws, WB + MGB_S);
  k_cvt<<<1152, 256, 0, stream>>>(gru_Wih, gru_Whh, clnA_W, clnE_W,
                                  attnA_W + 196608, attnE_W + 196608, WB);

  // q_src (f32 + bf16)
  k_densek<30, 256><<<dim3(BN/64, 4), 256, 0, stream>>>(own_raw, W_own, b_own,
                                                        ws + QSRC_OFF, qsb);

  // g (both branches) ; cln gamma/beta (both branches, one GEMM)
  k_mm<256, 256, 256, true><<<dim3(2, 128), 256, 0, stream>>>(qsb, WB + MGB_S, ws + BMG_OFF, ws + GBUF_OFF);
  k_mm<256, 256, 1024, true><<<dim3(8, 128), 256, 0, stream>>>(qsb, WB + CLA_S, ws + CLB_OFF, ws + GB_OFF);

  // attention cores
  k_core<<<BN/4, 256, 0, stream>>>(ally_raw, ws + QSRC_OFF, ws + GBUF_OFF,
                                   ws + WQA_OFF, ws + CQA_OFF, ws + WVA_OFF, ws + BVA_OFF,
                                   gt_w, gt_b, 0, 15, ws + ZRAWA_OFF);
  k_core<<<BN/4, 256, 0, stream>>>(enemy_raw, ws + QSRC_OFF, ws + GBUF_OFF + 128,
                                   ws + WQE_OFF, ws + CQE_OFF, ws + WVE_OFF, ws + BVE_OFF,
                                   gt_w, gt_b, 1, 16, ws + ZRAWE_OFF);

  // heads weight fold (reuses FW space freed by cores)
  k_fuse4<<<129, 256, 0, stream>>>(Wv_head, bv_head, Wtb, btb, ws, WHD);

  // output projections
  k_mm<256, 256, 256, false><<<dim3(2, 128), 256, 0, stream>>>(ws + ZRAWA_OFF, WB + PJA_S, attnA_b + 768, ws + AOUTA_OFF);
  k_mm<256, 256, 256, false><<<dim3(2, 128), 256, 0, stream>>>(ws + ZRAWE_OFF, WB + PJE_S, attnE_b + 768, ws + AOUTE_OFF);

  // fused cln+cln+ln3 -> u (in-place into GB rows, stride 1024)
  k_clnln<<<BN/4, 256, 0, stream>>>(ws + AOUTA_OFF, ws + AOUTE_OFF, ws + QSRC_OFF,
                                    ws + GB_OFF, ln3_g, ln3_b);

  // GRU gates
  k_mm<768, 1024, 768, false><<<dim3(6, 128), 256, 0, stream>>>(ws + U_OFF, WB + WIH_S, gru_bih, ws + GI_OFF);
  k_mm<256, 256, 768, false><<<dim3(6, 128), 256, 0, stream>>>(hidden, WB + WHH_S, gru_bhh, ws + GH_OFF);
  k_gru<<<BN, 256, 0, stream>>>(ws + GI_OFF, ws + GH_OFF, hidden, hout);

  // heads: OB = h @ WHD.T, then epilogue
  k_mm<256, 256, 128, false><<<dim3(1, 128), 256, 0, stream>>>(hout, WHD, ws + BHD_OFF, ws + OB_OFF);
  k_heads2<<<BN/16, 256, 0, stream>>>(ws + OB_OFF, enemy_raw, log_tau, out);
}

// Round 5
// 286.414 us; speedup vs baseline: 9.9454x; 1.4346x over previous
//
#include <hip/hip_runtime.h>
#include <math.h>

#define BN 16384

typedef float f32x4 __attribute__((ext_vector_type(4)));
typedef short bf16x8v __attribute__((ext_vector_type(8)));
typedef unsigned short u16x8 __attribute__((ext_vector_type(8)));
typedef unsigned short u16x4 __attribute__((ext_vector_type(4)));

static __device__ inline unsigned short f2bf(float f) {
  unsigned u = __float_as_uint(f);
  return (unsigned short)((u + 0x8000u) >> 16);
}

// ---------------- workspace float offsets ----------------
#define WKA_OFF   0
#define WVA_OFF   8192
#define WKE_OFF   16384
#define WVE_OFF   24576
#define WKEF_OFF  32768
#define BKA_OFF   40960
#define BVA_OFF   41216
#define BKE_OFF   41472
#define BVE_OFF   41728
#define BKEF_OFF  41984
#define WMP_OFF   43008
#define BMP_OFF   44544
#define G_OFF     45056
#define BG_OFF    53248
#define WQB_OFF   53312
#define SC0_OFF   53568
#define BMG_OFF   53632
#define CLB_OFF   56064   /* 1024 floats: clnA_b ++ clnE_b */
#define BPJA_OFF  57088   /* 256 folded proj biases (A) */
#define BPJE_OFF  57344   /* 256 folded proj biases (E) */
// heads fold (written by k_fuse4 AFTER fuse3/fuse5)
#define BHD_OFF   16384   /* 128 floats bias (over dead WKE) */
// WHD bf16 heads weights: shorts at float offset 0

#define QSRC_OFF  65536
#define BUF1_OFF  (QSRC_OFF + BN*256)
#define BUF2_OFF  (BUF1_OFF + BN*256)
#define BUF3_OFF  (BUF2_OFF + BN*256)
#define BUF4_OFF  (BUF3_OFF + BN*256)
#define BUF5_OFF  (BUF4_OFF + BN*256)   /* BN*1024 region */

#define GBUF_OFF  BUF1_OFF   // g (gA|gE) f32 for core
#define PAL_OFF   BUF2_OFF   // pal bf16 [BN][256] (overwrites dead qsb)
#define AOUTA_OFF BUF3_OFF
#define AOUTE_OFF BUF4_OFF
#define GB_OFF    BUF5_OFF   // [BN][1024] gamma/beta; U written in-place
#define U_OFF     BUF5_OFF
#define GI_OFF    BUF1_OFF   // BN*768 across BUF1..BUF3
#define GH_OFF    BUF4_OFF   // BN*768 across BUF4 + BUF5[0:512]
#define OB_OFF    BUF1_OFF   // [BN][128] heads pre-products

#define HOFF      (BN*22)

// bf16 weight cache in d_out's h-region (dead until k_gru writes it)
#define WIH_S 0
#define WHH_S 589824
#define CLA_S 786432
#define CLE_S 917504
#define PJA_S 1048576      /* PVA folded 256x128 bf16 */
#define PJE_S 1081344      /* PVE folded 256x128 bf16 */
#define MGB_S 1179648

// ---------------- fused small-weight precompute ----------------
__global__ __launch_bounds__(256) void k_fuse1(
    const float* __restrict__ attnA_W, const float* __restrict__ attnA_b,
    const float* __restrict__ attnE_W, const float* __restrict__ attnE_b,
    const float* __restrict__ W_ally,  const float* __restrict__ b_ally,
    const float* __restrict__ W_enemy, const float* __restrict__ b_enemy,
    const float* __restrict__ Wke,     const float* __restrict__ bke,
    float* __restrict__ FW) {
  int g = blockIdx.x * 256 + threadIdx.x;
  if (g >= 40960) return;
  int m = g >> 13;
  int r = g & 8191;
  int d = r >> 5, j = r & 31;
  const float *Wout, *Win, *bin, *bout; float *dst, *dstb;
  switch (m) {
    case 0: Wout = attnA_W + 65536;  Win = W_ally;  bin = b_ally;  bout = attnA_b + 256; dst = FW + WKA_OFF;  dstb = FW + BKA_OFF;  break;
    case 1: Wout = attnA_W + 131072; Win = W_ally;  bin = b_ally;  bout = attnA_b + 512; dst = FW + WVA_OFF;  dstb = FW + BVA_OFF;  break;
    case 2: Wout = attnE_W + 65536;  Win = W_enemy; bin = b_enemy; bout = attnE_b + 256; dst = FW + WKE_OFF;  dstb = FW + BKE_OFF;  break;
    case 3: Wout = attnE_W + 131072; Win = W_enemy; bin = b_enemy; bout = attnE_b + 512; dst = FW + WVE_OFF;  dstb = FW + BVE_OFF;  break;
    default:Wout = Wke;              Win = W_enemy; bin = b_enemy; bout = bke;           dst = FW + WKEF_OFF; dstb = FW + BKEF_OFF; break;
  }
  float acc = 0.f;
  for (int c = 0; c < 256; ++c) acc += Wout[d*256 + c] * Win[c*32 + j];
  dst[d*32 + j] = acc;
  if (j == 0) {
    float b = bout[d];
    for (int c = 0; c < 256; ++c) b += Wout[d*256 + c] * bin[c];
    dstb[d] = b;
  }
}

__global__ __launch_bounds__(256) void k_fuse2(
    const float* __restrict__ protos, const float* __restrict__ Wmq,
    const float* __restrict__ bmq,    const float* __restrict__ Wqs,
    const float* __restrict__ bqs,    float* __restrict__ FW) {
  int g = blockIdx.x * 256 + threadIdx.x;
  const float* WKe_f = FW + WKEF_OFF;
  const float* bKe_f = FW + BKEF_OFF;
  if (g < 1536) {
    int i = g >> 8, c = g & 255;
    float acc = 0.f;
    for (int d = 0; d < 256; ++d) acc += protos[i*256 + d] * Wmq[d*256 + c];
    FW[WMP_OFF + i*256 + c] = acc;
  } else if (g < 9728) {
    int r = g - 1536;
    int j = r >> 8, c = r & 255;
    float acc = 0.f;
    for (int d = 0; d < 256; ++d) acc += WKe_f[d*32 + j] * Wqs[d*256 + c];
    FW[G_OFF + j*256 + c] = acc;
  } else if (g < 9984) {
    int c = g - 9728;
    float acc = 0.f;
    for (int d = 0; d < 256; ++d) acc += Wqs[d*256 + c] * bKe_f[d];
    FW[WQB_OFF + c] = acc;
  } else if (g < 9990) {
    int i = g - 9984;
    float acc = 0.f;
    for (int d = 0; d < 256; ++d) acc += protos[i*256 + d] * bmq[d];
    FW[BMP_OFF + i] = acc;
  } else if (g < 10022) {
    int j = g - 9990;
    float acc = 0.f;
    for (int d = 0; d < 256; ++d) acc += WKe_f[d*32 + j] * bqs[d];
    FW[BG_OFF + j] = acc;
  } else if (g == 10022) {
    float acc = 0.f;
    for (int d = 0; d < 256; ++d) acc += bqs[d] * bKe_f[d];
    FW[SC0_OFF] = acc;
  }
}

// fold q_src->g matrix (bf16) + bias; CLB bias concat  (qbk removed: softmax shift-invariant)
__global__ __launch_bounds__(256) void k_fuse3(
    const float* __restrict__ attnA_W, const float* __restrict__ attnA_b,
    const float* __restrict__ attnE_W, const float* __restrict__ attnE_b,
    const float* __restrict__ clnA_b,  const float* __restrict__ clnE_b,
    float* __restrict__ FW, unsigned short* __restrict__ MGB) {
  int g = blockIdx.x * 256 + threadIdx.x;   // 66816 items
  if (g < 65536) {
    int r = g >> 8, c = g & 255;
    int br = r >> 7, jj = r & 127, h = jj >> 5, jc = jj & 31;
    const float* W0 = br ? attnE_W : attnA_W;
    const float* Wk = FW + (br ? WKE_OFF : WKA_OFF);
    float acc = 0.f;
    for (int d = 0; d < 64; ++d)
      acc += W0[(h*64+d)*256 + c] * Wk[(h*64+d)*32 + jc];
    MGB[r*256 + c] = f2bf(acc);
  } else if (g < 65792) {
    int r = g - 65536;
    int br = r >> 7, jj = r & 127, h = jj >> 5, jc = jj & 31;
    const float* b0 = br ? attnE_b : attnA_b;
    const float* Wk = FW + (br ? WKE_OFF : WKA_OFF);
    float acc = 0.f;
    for (int d = 0; d < 64; ++d) acc += b0[h*64+d] * Wk[(h*64+d)*32 + jc];
    FW[BMG_OFF + r] = acc;
  } else if (g < 66816) {
    int c = g - 65792;
    FW[CLB_OFF + c] = (c < 512) ? clnA_b[c] : clnE_b[c - 512];
  }
}

// fold PV = proj ∘ Wv (per branch, 256x128 bf16, transposed for k_mm) + folded proj bias
__global__ __launch_bounds__(256) void k_fuse5(
    const float* __restrict__ attnA_W, const float* __restrict__ attnA_b,
    const float* __restrict__ attnE_W, const float* __restrict__ attnE_b,
    float* __restrict__ FW, unsigned short* __restrict__ PVA,
    unsigned short* __restrict__ PVE) {
  int g = blockIdx.x * 256 + threadIdx.x;   // 66048 items
  if (g < 65536) {
    int br = g >> 15;
    int r0 = g & 32767;
    int o = r0 >> 7, r = r0 & 127, h = r >> 5, j = r & 31;
    const float* Wp = (br ? attnE_W : attnA_W) + 196608;
    const float* Wv = FW + (br ? WVE_OFF : WVA_OFF);
    float acc = 0.f;
    for (int d = 0; d < 64; ++d)
      acc += Wp[o*256 + h*64 + d] * Wv[(h*64+d)*32 + j];
    (br ? PVE : PVA)[o*128 + r] = f2bf(acc);
  } else if (g < 66048) {
    int r0 = g - 65536;
    int br = r0 >> 8, c = r0 & 255;
    const float* Wp = (br ? attnE_W : attnA_W) + 196608;
    const float* bv = FW + (br ? BVE_OFF : BVA_OFF);
    const float* pb = (br ? attnE_b : attnA_b) + 768;
    float acc = pb[c];
    for (int d = 0; d < 256; ++d) acc += Wp[c*256 + d] * bv[d];
    FW[(br ? BPJE_OFF : BPJA_OFF) + c] = acc;
  }
}

// heads fold: WHD[128][256] bf16 + BHD[128]
__global__ __launch_bounds__(256) void k_fuse4(
    const float* __restrict__ Wv_head, const float* __restrict__ bv_head,
    const float* __restrict__ Wtb, const float* __restrict__ btb,
    float* __restrict__ FW, unsigned short* __restrict__ WHD) {
  int g = blockIdx.x * 256 + threadIdx.x;
  if (g < 32768) {
    int r = g >> 8, c = g & 255;
    float v;
    if (r == 0)       v = Wv_head[c];
    else if (r == 1)  v = Wtb[c];
    else if (r == 2)  v = Wtb[256 + c];
    else if (r < 9)   v = FW[WMP_OFF + (r - 3) * 256 + c];
    else if (r < 41)  v = FW[G_OFF + (r - 9) * 256 + c];
    else if (r == 41) v = FW[WQB_OFF + c];
    else              v = 0.f;
    WHD[r * 256 + c] = f2bf(v);
  } else if (g < 32896) {
    int r = g - 32768;
    float v;
    if (r == 0)       v = bv_head[0];
    else if (r == 1)  v = btb[0];
    else if (r == 2)  v = btb[1];
    else if (r < 9)   v = FW[BMP_OFF + r - 3];
    else if (r < 41)  v = FW[BG_OFF + r - 9];
    else if (r == 41) v = FW[SC0_OFF];
    else              v = 0.f;
    FW[BHD_OFF + r] = v;
  }
}

// ---------------- f32->bf16 weight conversion (4 segments) ----------------
__global__ __launch_bounds__(256) void k_cvt(
    const float* __restrict__ w0, const float* __restrict__ w1,
    const float* __restrict__ w2, const float* __restrict__ w3,
    unsigned short* __restrict__ dst) {
  int e = (blockIdx.x * 256 + threadIdx.x) * 4;   // 1048576 shorts total
  const float* src; int off;
  if (e < 589824)       { src = w0; off = 0; }
  else if (e < 786432)  { src = w1; off = 589824; }
  else if (e < 917504)  { src = w2; off = 786432; }
  else                  { src = w3; off = 917504; }
  float4 v = *(const float4*)(src + (e - off));
  u16x4 b; b.x = f2bf(v.x); b.y = f2bf(v.y); b.z = f2bf(v.z); b.w = f2bf(v.w);
  *(u16x4*)&dst[e] = b;
}

// ---------------- small-K dense (K=30), dual f32+bf16 output ----------------
template<int K, int NOUT>
__global__ __launch_bounds__(256) void k_densek(
    const float* __restrict__ A, const float* __restrict__ W,
    const float* __restrict__ bias, float* __restrict__ C,
    unsigned short* __restrict__ Cb) {
  constexpr int KB = 32;
  __shared__ float As[64][36];
  const int tid = threadIdx.x;
  const int s0 = blockIdx.x * 64;
  const int o0 = blockIdx.y * 64;
  const int ox = (tid & 15) * 4;
  const int sy = (tid >> 4) * 4;
  float acc[4][4] = {};
  const float* Abase = A + (long)s0 * K;
  for (int idx = tid; idx < 64 * KB; idx += 256) {
    int s = idx >> 5, c = idx & 31;
    As[s][c] = (c < K) ? Abase[(long)s * K + c] : 0.f;
  }
  __syncthreads();
  for (int kk = 0; kk < KB; kk += 4) {
    float a4[4][4];
    #pragma unroll
    for (int sj = 0; sj < 4; ++sj)
      *(float4*)a4[sj] = *(const float4*)&As[sy + sj][kk];
    #pragma unroll
    for (int oi = 0; oi < 4; ++oi) {
      float w4[4];
      #pragma unroll
      for (int kx = 0; kx < 4; ++kx) {
        int k = kk + kx;
        w4[kx] = (k < K) ? W[(long)(o0 + ox + oi) * K + k] : 0.f;
      }
      #pragma unroll
      for (int sj = 0; sj < 4; ++sj)
        #pragma unroll
        for (int kx = 0; kx < 4; ++kx)
          acc[sj][oi] = fmaf(a4[sj][kx], w4[kx], acc[sj][oi]);
    }
  }
  #pragma unroll
  for (int sj = 0; sj < 4; ++sj) {
    float4 o4;
    o4.x = acc[sj][0] + bias[o0 + ox + 0];
    o4.y = acc[sj][1] + bias[o0 + ox + 1];
    o4.z = acc[sj][2] + bias[o0 + ox + 2];
    o4.w = acc[sj][3] + bias[o0 + ox + 3];
    *(float4*)&C[(long)(s0 + sy + sj) * NOUT + o0 + ox] = o4;
    u16x4 b4; b4.x = f2bf(o4.x); b4.y = f2bf(o4.y); b4.z = f2bf(o4.z); b4.w = f2bf(o4.w);
    *(u16x4*)&Cb[(long)(s0 + sy + sj) * NOUT + o0 + ox] = b4;
  }
}

// ---------------- MFMA dense ----------------
template<int K, int LDA, int NOUT, bool ABF>
__global__ __launch_bounds__(256) void k_mm(
    const void* __restrict__ Ap, const unsigned short* __restrict__ W,
    const float* __restrict__ bias, float* __restrict__ C) {
  constexpr int NCH = K / 32;
  __shared__ __align__(16) unsigned short As[4096];
  __shared__ __align__(16) unsigned short Ws[4096];
  const int tid = threadIdx.x;
  const int o0 = blockIdx.x * 128;
  const long s0 = (long)blockIdx.y * 128;
  const int wv = tid >> 6, l = tid & 63;
  const int wm = (wv >> 1) * 64, wn = (wv & 1) * 64;
  const int lr = l & 15, lk = l >> 4;

  const int wrow = tid >> 2;
  const int wslot = tid & 3;
  const int q = tid & 3;

  f32x4 acc[4][4] = {};
  u16x8 pw[2];
  u16x8 pa_b[2];
  float4 pa_f[2][2];

  const unsigned short* Wb = W + (long)o0 * K;
  const unsigned short* Abf = (const unsigned short*)Ap;
  const float* Aff = (const float*)Ap;

  #pragma unroll
  for (int p = 0; p < 2; ++p) {
    const int r = wrow + 64 * p;
    pw[p] = *(const u16x8*)(Wb + (long)r * K + wslot * 8);
    if constexpr (ABF) {
      pa_b[p] = *(const u16x8*)(Abf + (s0 + r) * LDA + wslot * 8);
    } else {
      const float* Af = Aff + (s0 + r) * LDA + q * 4;
      pa_f[p][0] = *(const float4*)(Af);
      pa_f[p][1] = *(const float4*)(Af + 16);
    }
  }

  for (int ch = 0; ch < NCH; ++ch) {
    if (ch) __syncthreads();
    #pragma unroll
    for (int p = 0; p < 2; ++p) {
      const int r = wrow + 64 * p;
      const int ps = (wslot ^ (r & 3)) * 8;
      *(u16x8*)&Ws[r * 32 + ps] = pw[p];
      if constexpr (ABF) {
        *(u16x8*)&As[r * 32 + ps] = pa_b[p];
      } else {
        #pragma unroll
        for (int j = 0; j < 2; ++j) {
          float4 v = pa_f[p][j];
          unsigned long long pk =
              (unsigned long long)f2bf(v.x) |
              ((unsigned long long)f2bf(v.y) << 16) |
              ((unsigned long long)f2bf(v.z) << 32) |
              ((unsigned long long)f2bf(v.w) << 48);
          const int slot = (j * 2 + (q >> 1)) ^ (r & 3);
          *(unsigned long long*)&As[r * 32 + slot * 8 + (q & 1) * 4] = pk;
        }
      }
    }
    __syncthreads();
    if (ch + 1 < NCH) {
      const int k0 = (ch + 1) * 32;
      #pragma unroll
      for (int p = 0; p < 2; ++p) {
        const int r = wrow + 64 * p;
        pw[p] = *(const u16x8*)(Wb + (long)r * K + k0 + wslot * 8);
        if constexpr (ABF) {
          pa_b[p] = *(const u16x8*)(Abf + (s0 + r) * LDA + k0 + wslot * 8);
        } else {
          const float* Af = Aff + (s0 + r) * LDA + k0 + q * 4;
          pa_f[p][0] = *(const float4*)(Af);
          pa_f[p][1] = *(const float4*)(Af + 16);
        }
      }
    }
    bf16x8v af[4], bw[4];
    #pragma unroll
    for (int m = 0; m < 4; ++m) {
      const int r = wm + m * 16 + lr;
      af[m] = *(const bf16x8v*)&As[r * 32 + ((lk ^ (r & 3)) * 8)];
    }
    #pragma unroll
    for (int n = 0; n < 4; ++n) {
      const int r = wn + n * 16 + lr;
      bw[n] = *(const bf16x8v*)&Ws[r * 32 + ((lk ^ (r & 3)) * 8)];
    }
    #pragma unroll
    for (int m = 0; m < 4; ++m)
      #pragma unroll
      for (int n = 0; n < 4; ++n)
        acc[m][n] = __builtin_amdgcn_mfma_f32_16x16x32_bf16(af[m], bw[n], acc[m][n], 0, 0, 0);
  }

  #pragma unroll
  for (int n = 0; n < 4; ++n) {
    const float b = bias[o0 + wn + n * 16 + lr];
    #pragma unroll
    for (int m = 0; m < 4; ++m) {
      const long rowb = s0 + wm + m * 16 + lk * 4;
      #pragma unroll
      for (int r = 0; r < 4; ++r)
        C[(rowb + r) * (long)NOUT + o0 + wn + n * 16 + lr] = acc[m][n][r] + b;
    }
  }
}

// ---------------- merged attention core: scores+softmax+pal for BOTH branches ----------------
__global__ __launch_bounds__(256) void k_core2(
    const float* __restrict__ rawA, const float* __restrict__ rawE,
    const float* __restrict__ g, const float* __restrict__ gt_w,
    const float* __restrict__ gt_b, unsigned short* __restrict__ pal) {
  __shared__ float A_[4][15][36];
  __shared__ float E_[4][16][36];
  __shared__ float G_[4][8][32];
  __shared__ float P_[4][8][16];
  const int tid = threadIdx.x;
  const int w = tid >> 6, l = tid & 63;
  const long s = (long)blockIdx.x * 4 + w;

  // float4 staging
  const float* ra = rawA + s * 480;
  const float* re = rawE + s * 512;
  const float* gr = g + s * 256;
  #pragma unroll
  for (int i = l; i < 120; i += 64) {
    float4 v = *(const float4*)(ra + i * 4);
    *(float4*)&A_[w][i >> 3][(i & 7) * 4] = v;
  }
  #pragma unroll
  for (int i = l; i < 128; i += 64) {
    float4 v = *(const float4*)(re + i * 4);
    *(float4*)&E_[w][i >> 3][(i & 7) * 4] = v;
  }
  {
    float4 v = *(const float4*)(gr + l * 4);
    *(float4*)&G_[w][l >> 3][(l & 7) * 4] = v;
  }
  __syncthreads();

  // masks (A rows on lanes 0..14, E rows on lanes 16..31) + temps
  bool mv = false;
  if (l < 15) {
    #pragma unroll
    for (int c = 0; c < 8; ++c) {
      float4 x = *(const float4*)&A_[w][l][c * 4];
      mv |= (x.x != 0.f) | (x.y != 0.f) | (x.z != 0.f) | (x.w != 0.f);
    }
  } else if (l >= 16 && l < 32) {
    #pragma unroll
    for (int c = 0; c < 8; ++c) {
      float4 x = *(const float4*)&E_[w][l - 16][c * 4];
      mv |= (x.x != 0.f) | (x.y != 0.f) | (x.z != 0.f) | (x.w != 0.f);
    }
  }
  unsigned long long bal = __ballot(mv);
  unsigned mA = (unsigned)bal & 0x7FFFu;
  unsigned mE = (unsigned)(bal >> 16) & 0xFFFFu;
  float xa = gt_w[0] * log1pf((float)__popc(mA)) + gt_b[0];
  float spa = fmaxf(xa, 0.f) + log1pf(expf(-fabsf(xa)));
  float scaleA = 1.f / (8.f * (spa + 1.f));
  float xe = gt_w[1] * log1pf((float)__popc(mE)) + gt_b[1];
  float spe = fmaxf(xe, 0.f) + log1pf(expf(-fabsf(xe)));
  float scaleE = 1.f / (8.f * (spe + 1.f));

  // scores + softmax (A and E interleaved; lane = (h, n))
  {
    const int h = l >> 4, n = l & 15;
    const bool okA = (n < 15) && ((mA >> n) & 1);
    const bool okE = (mE >> n) & 1;
    const float* arow = &A_[w][n < 15 ? n : 0][0];
    const float* erow = &E_[w][n][0];
    const float* garow = &G_[w][h][0];
    const float* gerow = &G_[w][4 + h][0];
    float accA = 0.f, accE = 0.f;
    #pragma unroll
    for (int j = 0; j < 32; ++j) {
      accA = fmaf(garow[j], arow[j], accA);
      accE = fmaf(gerow[j], erow[j], accE);
    }
    float sA = okA ? accA * scaleA : -INFINITY;
    float sE = okE ? accE * scaleE : -INFINITY;
    float mAx = sA, mEx = sE;
    #pragma unroll
    for (int off = 8; off; off >>= 1) {
      mAx = fmaxf(mAx, __shfl_xor(mAx, off));
      mEx = fmaxf(mEx, __shfl_xor(mEx, off));
    }
    float eA = okA ? expf(sA - mAx) : 0.f;
    float eE = okE ? expf(sE - mEx) : 0.f;
    float suA = eA, suE = eE;
    #pragma unroll
    for (int off = 8; off; off >>= 1) {
      suA += __shfl_xor(suA, off);
      suE += __shfl_xor(suE, off);
    }
    P_[w][h][n] = eA / suA;
    P_[w][4 + h][n] = eE / suE;
  }
  __syncthreads();

  // pal = p . raw (bf16 out); lane = (hh, j), 2 heads per lane per branch
  {
    const int j = l & 31, hh = l >> 5;
    unsigned short* po = pal + s * 256 + hh * 32 + j;
    #pragma unroll
    for (int r = 0; r < 2; ++r) {
      const int ha = r * 2 + hh;
      float a0 = 0.f, a1 = 0.f;
      #pragma unroll
      for (int n = 0; n < 15; ++n)
        a0 = fmaf(P_[w][ha][n], A_[w][n][j], a0);
      #pragma unroll
      for (int n = 0; n < 16; ++n)
        a1 = fmaf(P_[w][4 + ha][n], E_[w][n][j], a1);
      po[r * 64] = f2bf(a0);
      po[128 + r * 64] = f2bf(a1);
    }
  }
}

// ---------------- fused CLN(A)+CLN(E)+LN3 -> u (float4, in-place into GB rows) ----------------
__global__ __launch_bounds__(256) void k_clnln(
    const float* __restrict__ aA, const float* __restrict__ aE,
    const float* __restrict__ qsrc, float* gbu,
    const float* __restrict__ g, const float* __restrict__ b) {
  int w = threadIdx.x >> 6, l = threadIdx.x & 63;
  long s = (long)blockIdx.x * 4 + w;
  int d = l * 4;
  float4 vA = *(const float4*)(aA + s * 256 + d);
  float4 vE = *(const float4*)(aE + s * 256 + d);
  float4 vq = *(const float4*)(qsrc + s * 256 + d);
  float* gbr = gbu + s * 1024;
  float sumA = vA.x + vA.y + vA.z + vA.w;
  float ssqA = vA.x*vA.x + vA.y*vA.y + vA.z*vA.z + vA.w*vA.w;
  float sumE = vE.x + vE.y + vE.z + vE.w;
  float ssqE = vE.x*vE.x + vE.y*vE.y + vE.z*vE.z + vE.w*vE.w;
  #pragma unroll
  for (int off = 32; off > 0; off >>= 1) {
    sumA += __shfl_xor(sumA, off); ssqA += __shfl_xor(ssqA, off);
    sumE += __shfl_xor(sumE, off); ssqE += __shfl_xor(ssqE, off);
  }
  float muA = sumA * (1.f / 256.f);
  float rstdA = rsqrtf(ssqA * (1.f / 256.f) - muA * muA + 1e-5f);
  float muE = sumE * (1.f / 256.f);
  float rstdE = rsqrtf(ssqE * (1.f / 256.f) - muE * muE + 1e-5f);

  float4 gA4 = *(const float4*)(gbr + d);
  float4 bA4 = *(const float4*)(gbr + 256 + d);
  float4 gE4 = *(const float4*)(gbr + 512 + d);
  float4 bE4 = *(const float4*)(gbr + 768 + d);
  float4 zA, zE;
  zA.x = (1.f + gA4.x) * ((vA.x - muA) * rstdA) + bA4.x;
  zA.y = (1.f + gA4.y) * ((vA.y - muA) * rstdA) + bA4.y;
  zA.z = (1.f + gA4.z) * ((vA.z - muA) * rstdA) + bA4.z;
  zA.w = (1.f + gA4.w) * ((vA.w - muA) * rstdA) + bA4.w;
  zE.x = (1.f + gE4.x) * ((vE.x - muE) * rstdE) + bE4.x;
  zE.y = (1.f + gE4.y) * ((vE.y - muE) * rstdE) + bE4.y;
  zE.z = (1.f + gE4.z) * ((vE.z - muE) * rstdE) + bE4.z;
  zE.w = (1.f + gE4.w) * ((vE.w - muE) * rstdE) + bE4.w;

  float sum = vq.x+vq.y+vq.z+vq.w + zA.x+zA.y+zA.z+zA.w + zE.x+zE.y+zE.z+zE.w;
  float ssq = vq.x*vq.x+vq.y*vq.y+vq.z*vq.z+vq.w*vq.w
            + zA.x*zA.x+zA.y*zA.y+zA.z*zA.z+zA.w*zA.w
            + zE.x*zE.x+zE.y*zE.y+zE.z*zE.z+zE.w*zE.w;
  #pragma unroll
  for (int off = 32; off > 0; off >>= 1) {
    sum += __shfl_xor(sum, off); ssq += __shfl_xor(ssq, off);
  }
  float mu = sum * (1.f / 768.f);
  float rstd = rsqrtf(ssq * (1.f / 768.f) - mu * mu + 1e-5f);

  float4 g0 = *(const float4*)(g + d),       b0 = *(const float4*)(b + d);
  float4 g1 = *(const float4*)(g + 256 + d), b1 = *(const float4*)(b + 256 + d);
  float4 g2 = *(const float4*)(g + 512 + d), b2 = *(const float4*)(b + 512 + d);
  float4 o0, o1, o2;
  o0.x = (vq.x - mu) * rstd * g0.x + b0.x;
  o0.y = (vq.y - mu) * rstd * g0.y + b0.y;
  o0.z = (vq.z - mu) * rstd * g0.z + b0.z;
  o0.w = (vq.w - mu) * rstd * g0.w + b0.w;
  o1.x = (zA.x - mu) * rstd * g1.x + b1.x;
  o1.y = (zA.y - mu) * rstd * g1.y + b1.y;
  o1.z = (zA.z - mu) * rstd * g1.z + b1.z;
  o1.w = (zA.w - mu) * rstd * g1.w + b1.w;
  o2.x = (zE.x - mu) * rstd * g2.x + b2.x;
  o2.y = (zE.y - mu) * rstd * g2.y + b2.y;
  o2.z = (zE.z - mu) * rstd * g2.z + b2.z;
  o2.w = (zE.w - mu) * rstd * g2.w + b2.w;
  *(float4*)(gbr + d) = o0;
  *(float4*)(gbr + 256 + d) = o1;
  *(float4*)(gbr + 512 + d) = o2;
}

// ---------------- GRU elementwise (float4) ----------------
__global__ __launch_bounds__(256) void k_gru(
    const float* __restrict__ gi, const float* __restrict__ gh,
    const float* __restrict__ hid, float* __restrict__ hout) {
  long t = (long)blockIdx.x * 256 + threadIdx.x;
  long s = t >> 6; int d = (int)(t & 63) * 4;
  const float* gir = gi + s * 768 + d;
  const float* ghr = gh + s * 768 + d;
  float4 ir = *(const float4*)(gir);
  float4 iz = *(const float4*)(gir + 256);
  float4 inn = *(const float4*)(gir + 512);
  float4 hr = *(const float4*)(ghr);
  float4 hz = *(const float4*)(ghr + 256);
  float4 hn = *(const float4*)(ghr + 512);
  float4 hp = *(const float4*)(hid + s * 256 + d);
  float4 o;
#define GRUE(c) { \
  float r_ = 1.f / (1.f + expf(-(ir.c + hr.c))); \
  float z_ = 1.f / (1.f + expf(-(iz.c + hz.c))); \
  float n_ = tanhf(inn.c + r_ * hn.c); \
  o.c = (1.f - z_) * n_ + z_ * hp.c; }
  GRUE(x) GRUE(y) GRUE(z) GRUE(w)
#undef GRUE
  *(float4*)(hout + s * 256 + d) = o;
}

// ---------------- heads epilogue ----------------
__global__ __launch_bounds__(256) void k_heads2(
    const float* __restrict__ OB, const float* __restrict__ eraw,
    const float* __restrict__ log_tau, float* __restrict__ Qout) {
  __shared__ float obs[16][48];
  const int tid = threadIdx.x;
  const long s0 = (long)blockIdx.x * 16;
  for (int idx = tid; idx < 768; idx += 256)
    obs[idx / 48][idx % 48] = OB[(s0 + idx / 48) * 128 + idx % 48];
  __syncthreads();
  const int w = tid >> 4, i = tid & 15;
  const long s = s0 + w;
  const float itm = 1.f / (expf(log_tau[0]) + 1e-6f);
  const float its = 1.f / (expf(log_tau[1]) + 1e-6f);
  const float V = obs[w][0];
  const float* er = eraw + s * 512 + i * 32;
  bool valid = false; float acc = 0.f;
  #pragma unroll
  for (int jb = 0; jb < 8; ++jb) {
    float4 e4 = *(const float4*)(er + jb * 4);
    valid |= (e4.x != 0.f) | (e4.y != 0.f) | (e4.z != 0.f) | (e4.w != 0.f);
    acc += obs[w][9 + jb * 4 + 0] * e4.x + obs[w][9 + jb * 4 + 1] * e4.y +
           obs[w][9 + jb * 4 + 2] * e4.z + obs[w][9 + jb * 4 + 3] * e4.w;
  }
  float a = (acc + obs[w][41]) * 0.0625f;
  float sa = valid ? a : 0.f;
  float cv = valid ? 1.f : 0.f;
  #pragma unroll
  for (int off = 8; off > 0; off >>= 1) {
    sa += __shfl_xor(sa, off);
    cv += __shfl_xor(cv, off);
  }
  float me = sa / fmaxf(cv, 1.f);
  Qout[s * 22 + 6 + i] = V + obs[w][2] + (valid ? (a - me) * its : -1e30f * its);
  if (i < 6) {
    float mean = 0.f;
    #pragma unroll
    for (int t = 0; t < 6; ++t) mean += obs[w][3 + t];
    mean *= (1.f / 6.f);
    Qout[s * 22 + i] = V + obs[w][1] + (obs[w][3 + i] - mean) * 0.0625f * itm;
  }
}

// ---------------- launch ----------------
extern "C" void kernel_launch(void* const* d_in, const int* in_sizes, int n_in,
                              void* d_out, int out_size, void* d_ws, size_t ws_size,
                              hipStream_t stream) {
  const float* own_raw   = (const float*)d_in[0];
  const float* ally_raw  = (const float*)d_in[1];
  const float* enemy_raw = (const float*)d_in[2];
  const float* hidden    = (const float*)d_in[3];
  const float* W_own     = (const float*)d_in[4];
  const float* b_own     = (const float*)d_in[5];
  const float* W_ally    = (const float*)d_in[6];
  const float* b_ally    = (const float*)d_in[7];
  const float* W_enemy   = (const float*)d_in[8];
  const float* b_enemy   = (const float*)d_in[9];
  const float* gt_w      = (const float*)d_in[10];
  const float* gt_b      = (const float*)d_in[11];
  const float* attnA_W   = (const float*)d_in[12];
  const float* attnA_b   = (const float*)d_in[13];
  const float* attnE_W   = (const float*)d_in[14];
  const float* attnE_b   = (const float*)d_in[15];
  const float* clnA_W    = (const float*)d_in[16];
  const float* clnA_b    = (const float*)d_in[17];
  const float* clnE_W    = (const float*)d_in[18];
  const float* clnE_b    = (const float*)d_in[19];
  const float* ln3_g     = (const float*)d_in[20];
  const float* ln3_b     = (const float*)d_in[21];
  const float* gru_Wih   = (const float*)d_in[22];
  const float* gru_Whh   = (const float*)d_in[23];
  const float* gru_bih   = (const float*)d_in[24];
  const float* gru_bhh   = (const float*)d_in[25];
  const float* Wv_head   = (const float*)d_in[26];
  const float* bv_head   = (const float*)d_in[27];
  const float* Wtb       = (const float*)d_in[28];
  const float* btb       = (const float*)d_in[29];
  const float* log_tau   = (const float*)d_in[30];
  const float* Wmq       = (const float*)d_in[31];
  const float* bmq       = (const float*)d_in[32];
  const float* protos    = (const float*)d_in[33];
  const float* Wqs       = (const float*)d_in[34];
  const float* bqs       = (const float*)d_in[35];
  const float* Wke       = (const float*)d_in[36];
  const float* bke       = (const float*)d_in[37];

  float* ws  = (float*)d_ws;
  float* out = (float*)d_out;
  float* hout = out + HOFF;
  unsigned short* WB   = (unsigned short*)hout;
  unsigned short* qsb  = (unsigned short*)(ws + BUF2_OFF);
  unsigned short* palb = (unsigned short*)(ws + PAL_OFF);
  unsigned short* WHD  = (unsigned short*)ws;

  k_fuse1<<<160, 256, 0, stream>>>(attnA_W, attnA_b, attnE_W, attnE_b,
                                   W_ally, b_ally, W_enemy, b_enemy, Wke, bke, ws);
  k_fuse2<<<40, 256, 0, stream>>>(protos, Wmq, bmq, Wqs, bqs, ws);
  k_fuse3<<<261, 256, 0, stream>>>(attnA_W, attnA_b, attnE_W, attnE_b,
                                   clnA_b, clnE_b, ws, WB + MGB_S);
  k_fuse5<<<258, 256, 0, stream>>>(attnA_W, attnA_b, attnE_W, attnE_b,
                                   ws, WB + PJA_S, WB + PJE_S);
  k_fuse4<<<129, 256, 0, stream>>>(Wv_head, bv_head, Wtb, btb, ws, WHD);
  k_cvt<<<1024, 256, 0, stream>>>(gru_Wih, gru_Whh, clnA_W, clnE_W, WB);

  // q_src (f32 + bf16)
  k_densek<30, 256><<<dim3(BN/64, 4), 256, 0, stream>>>(own_raw, W_own, b_own,
                                                        ws + QSRC_OFF, qsb);

  // g (both branches) ; cln gamma/beta (both branches, one GEMM)
  k_mm<256, 256, 256, true><<<dim3(2, 128), 256, 0, stream>>>(qsb, WB + MGB_S, ws + BMG_OFF, ws + GBUF_OFF);
  k_mm<256, 256, 1024, true><<<dim3(8, 128), 256, 0, stream>>>(qsb, WB + CLA_S, ws + CLB_OFF, ws + GB_OFF);

  // merged attention core -> pal (bf16)
  k_core2<<<BN/4, 256, 0, stream>>>(ally_raw, enemy_raw, ws + GBUF_OFF,
                                    gt_w, gt_b, palb);

  // aout = pal @ PV + bpj (both branches, K=128)
  k_mm<128, 256, 256, true><<<dim3(2, 128), 256, 0, stream>>>(palb, WB + PJA_S, ws + BPJA_OFF, ws + AOUTA_OFF);
  k_mm<128, 256, 256, true><<<dim3(2, 128), 256, 0, stream>>>(palb + 128, WB + PJE_S, ws + BPJE_OFF, ws + AOUTE_OFF);

  // fused cln+cln+ln3 -> u
  k_clnln<<<BN/4, 256, 0, stream>>>(ws + AOUTA_OFF, ws + AOUTE_OFF, ws + QSRC_OFF,
                                    ws + GB_OFF, ln3_g, ln3_b);

  // GRU gates
  k_mm<768, 1024, 768, false><<<dim3(6, 128), 256, 0, stream>>>(ws + U_OFF, WB + WIH_S, gru_bih, ws + GI_OFF);
  k_mm<256, 256, 768, false><<<dim3(6, 128), 256, 0, stream>>>(hidden, WB + WHH_S, gru_bhh, ws + GH_OFF);
  k_gru<<<4096, 256, 0, stream>>>(ws + GI_OFF, ws + GH_OFF, hidden, hout);

  // heads: OB = h @ WHD.T, then epilogue
  k_mm<256, 256, 128, false><<<dim3(1, 128), 256, 0, stream>>>(hout, WHD, ws + BHD_OFF, ws + OB_OFF);
  k_heads2<<<BN/16, 256, 0, stream>>>(ws + OB_OFF, enemy_raw, log_tau, out);
}

// Round 6
// 247.430 us; speedup vs baseline: 11.5124x; 1.1576x over previous
//
#include <hip/hip_runtime.h>
#include <math.h>

#define BN 16384

typedef float f32x4 __attribute__((ext_vector_type(4)));
typedef short bf16x8v __attribute__((ext_vector_type(8)));
typedef unsigned short u16x8 __attribute__((ext_vector_type(8)));
typedef unsigned short u16x4 __attribute__((ext_vector_type(4)));

static __device__ inline unsigned short f2bf(float f) {
  unsigned u = __float_as_uint(f);
  return (unsigned short)((u + 0x8000u) >> 16);
}

// ---------------- workspace float offsets ----------------
#define WKA_OFF   0
#define WVA_OFF   8192
#define WKE_OFF   16384
#define WVE_OFF   24576
#define WKEF_OFF  32768
#define BKA_OFF   40960
#define BVA_OFF   41216
#define BKE_OFF   41472
#define BVE_OFF   41728
#define BKEF_OFF  41984
#define WMP_OFF   43008
#define BMP_OFF   44544
#define G_OFF     45056
#define BG_OFF    53248
#define WQB_OFF   53312
#define SC0_OFF   53568
#define BMG_OFF   53632
#define CLB_OFF   56064   /* 1024 floats: clnA_b ++ clnE_b */
#define BPJA_OFF  57088
#define BPJE_OFF  57344
#define BGRU_OFF  57600   /* 1024 floats folded GRU bias */
// heads fold (written by k_fuse4 AFTER fuse3/fuse5)
#define BHD_OFF   16384   /* over dead WKE */
// WHD bf16 heads weights: shorts at float offset 0

#define QSRC_OFF  65536
#define BUF1_OFF  (QSRC_OFF + BN*256)
#define BUF2_OFF  (BUF1_OFF + BN*256)
#define BUF3_OFF  (BUF2_OFF + BN*256)
#define BUF4_OFF  (BUF3_OFF + BN*256)
#define BUF5_OFF  (BUF4_OFF + BN*256)   /* BN*1024 region */

#define GBUF_OFF  BUF1_OFF   // g (gA|gE) f32 for core (dead after core2)
#define PAL_OFF   BUF2_OFF   // pal bf16 (overwrites dead qsb)
#define AOUTA_OFF BUF3_OFF
#define AOUTE_OFF BUF4_OFF
#define GB_OFF    BUF5_OFF   // [BN][1024] gamma/beta; U written in-place
#define U_OFF     BUF5_OFF
#define OB_OFF    BUF1_OFF   // [BN][128] heads pre-products (after mega)
// WGRU bf16 [1024][1024] lives at BUF1 (shorts), written after core2, read by mega

#define HOFF      (BN*22)

// bf16 weight cache in d_out's h-region (dead until mega writes h)
#define CLA_S 0
#define CLE_S 131072
#define PJA_S 262144
#define PJE_S 294912
#define MGB_S 327680

// ---------------- fused small-weight precompute ----------------
__global__ __launch_bounds__(256) void k_fuse1(
    const float* __restrict__ attnA_W, const float* __restrict__ attnA_b,
    const float* __restrict__ attnE_W, const float* __restrict__ attnE_b,
    const float* __restrict__ W_ally,  const float* __restrict__ b_ally,
    const float* __restrict__ W_enemy, const float* __restrict__ b_enemy,
    const float* __restrict__ Wke,     const float* __restrict__ bke,
    float* __restrict__ FW) {
  int g = blockIdx.x * 256 + threadIdx.x;
  if (g >= 40960) return;
  int m = g >> 13;
  int r = g & 8191;
  int d = r >> 5, j = r & 31;
  const float *Wout, *Win, *bin, *bout; float *dst, *dstb;
  switch (m) {
    case 0: Wout = attnA_W + 65536;  Win = W_ally;  bin = b_ally;  bout = attnA_b + 256; dst = FW + WKA_OFF;  dstb = FW + BKA_OFF;  break;
    case 1: Wout = attnA_W + 131072; Win = W_ally;  bin = b_ally;  bout = attnA_b + 512; dst = FW + WVA_OFF;  dstb = FW + BVA_OFF;  break;
    case 2: Wout = attnE_W + 65536;  Win = W_enemy; bin = b_enemy; bout = attnE_b + 256; dst = FW + WKE_OFF;  dstb = FW + BKE_OFF;  break;
    case 3: Wout = attnE_W + 131072; Win = W_enemy; bin = b_enemy; bout = attnE_b + 512; dst = FW + WVE_OFF;  dstb = FW + BVE_OFF;  break;
    default:Wout = Wke;              Win = W_enemy; bin = b_enemy; bout = bke;           dst = FW + WKEF_OFF; dstb = FW + BKEF_OFF; break;
  }
  float acc = 0.f;
  for (int c = 0; c < 256; ++c) acc += Wout[d*256 + c] * Win[c*32 + j];
  dst[d*32 + j] = acc;
  if (j == 0) {
    float b = bout[d];
    for (int c = 0; c < 256; ++c) b += Wout[d*256 + c] * bin[c];
    dstb[d] = b;
  }
}

__global__ __launch_bounds__(256) void k_fuse2(
    const float* __restrict__ protos, const float* __restrict__ Wmq,
    const float* __restrict__ bmq,    const float* __restrict__ Wqs,
    const float* __restrict__ bqs,    float* __restrict__ FW) {
  int g = blockIdx.x * 256 + threadIdx.x;
  const float* WKe_f = FW + WKEF_OFF;
  const float* bKe_f = FW + BKEF_OFF;
  if (g < 1536) {
    int i = g >> 8, c = g & 255;
    float acc = 0.f;
    for (int d = 0; d < 256; ++d) acc += protos[i*256 + d] * Wmq[d*256 + c];
    FW[WMP_OFF + i*256 + c] = acc;
  } else if (g < 9728) {
    int r = g - 1536;
    int j = r >> 8, c = r & 255;
    float acc = 0.f;
    for (int d = 0; d < 256; ++d) acc += WKe_f[d*32 + j] * Wqs[d*256 + c];
    FW[G_OFF + j*256 + c] = acc;
  } else if (g < 9984) {
    int c = g - 9728;
    float acc = 0.f;
    for (int d = 0; d < 256; ++d) acc += Wqs[d*256 + c] * bKe_f[d];
    FW[WQB_OFF + c] = acc;
  } else if (g < 9990) {
    int i = g - 9984;
    float acc = 0.f;
    for (int d = 0; d < 256; ++d) acc += protos[i*256 + d] * bmq[d];
    FW[BMP_OFF + i] = acc;
  } else if (g < 10022) {
    int j = g - 9990;
    float acc = 0.f;
    for (int d = 0; d < 256; ++d) acc += WKe_f[d*32 + j] * bqs[d];
    FW[BG_OFF + j] = acc;
  } else if (g == 10022) {
    float acc = 0.f;
    for (int d = 0; d < 256; ++d) acc += bqs[d] * bKe_f[d];
    FW[SC0_OFF] = acc;
  }
}

// fold q_src->g matrix (bf16) + bias; CLB bias concat
__global__ __launch_bounds__(256) void k_fuse3(
    const float* __restrict__ attnA_W, const float* __restrict__ attnA_b,
    const float* __restrict__ attnE_W, const float* __restrict__ attnE_b,
    const float* __restrict__ clnA_b,  const float* __restrict__ clnE_b,
    float* __restrict__ FW, unsigned short* __restrict__ MGB) {
  int g = blockIdx.x * 256 + threadIdx.x;
  if (g < 65536) {
    int r = g >> 8, c = g & 255;
    int br = r >> 7, jj = r & 127, h = jj >> 5, jc = jj & 31;
    const float* W0 = br ? attnE_W : attnA_W;
    const float* Wk = FW + (br ? WKE_OFF : WKA_OFF);
    float acc = 0.f;
    for (int d = 0; d < 64; ++d)
      acc += W0[(h*64+d)*256 + c] * Wk[(h*64+d)*32 + jc];
    MGB[r*256 + c] = f2bf(acc);
  } else if (g < 65792) {
    int r = g - 65536;
    int br = r >> 7, jj = r & 127, h = jj >> 5, jc = jj & 31;
    const float* b0 = br ? attnE_b : attnA_b;
    const float* Wk = FW + (br ? WKE_OFF : WKA_OFF);
    float acc = 0.f;
    for (int d = 0; d < 64; ++d) acc += b0[h*64+d] * Wk[(h*64+d)*32 + jc];
    FW[BMG_OFF + r] = acc;
  } else if (g < 66816) {
    int c = g - 65792;
    FW[CLB_OFF + c] = (c < 512) ? clnA_b[c] : clnE_b[c - 512];
  }
}

// fold PV = proj ∘ Wv (per branch) + folded proj bias
__global__ __launch_bounds__(256) void k_fuse5(
    const float* __restrict__ attnA_W, const float* __restrict__ attnA_b,
    const float* __restrict__ attnE_W, const float* __restrict__ attnE_b,
    float* __restrict__ FW, unsigned short* __restrict__ PVA,
    unsigned short* __restrict__ PVE) {
  int g = blockIdx.x * 256 + threadIdx.x;
  if (g < 65536) {
    int br = g >> 15;
    int r0 = g & 32767;
    int o = r0 >> 7, r = r0 & 127, h = r >> 5, j = r & 31;
    const float* Wp = (br ? attnE_W : attnA_W) + 196608;
    const float* Wv = FW + (br ? WVE_OFF : WVA_OFF);
    float acc = 0.f;
    for (int d = 0; d < 64; ++d)
      acc += Wp[o*256 + h*64 + d] * Wv[(h*64+d)*32 + j];
    (br ? PVE : PVA)[o*128 + r] = f2bf(acc);
  } else if (g < 66048) {
    int r0 = g - 65536;
    int br = r0 >> 8, c = r0 & 255;
    const float* Wp = (br ? attnE_W : attnA_W) + 196608;
    const float* bv = FW + (br ? BVE_OFF : BVA_OFF);
    const float* pb = (br ? attnE_b : attnA_b) + 768;
    float acc = pb[c];
    for (int d = 0; d < 256; ++d) acc += Wp[c*256 + d] * bv[d];
    FW[(br ? BPJE_OFF : BPJA_OFF) + c] = acc;
  }
}

// heads fold: WHD[128][256] bf16 + BHD[128]
__global__ __launch_bounds__(256) void k_fuse4(
    const float* __restrict__ Wv_head, const float* __restrict__ bv_head,
    const float* __restrict__ Wtb, const float* __restrict__ btb,
    float* __restrict__ FW, unsigned short* __restrict__ WHD) {
  int g = blockIdx.x * 256 + threadIdx.x;
  if (g < 32768) {
    int r = g >> 8, c = g & 255;
    float v;
    if (r == 0)       v = Wv_head[c];
    else if (r == 1)  v = Wtb[c];
    else if (r == 2)  v = Wtb[256 + c];
    else if (r < 9)   v = FW[WMP_OFF + (r - 3) * 256 + c];
    else if (r < 41)  v = FW[G_OFF + (r - 9) * 256 + c];
    else if (r == 41) v = FW[WQB_OFF + c];
    else              v = 0.f;
    WHD[r * 256 + c] = f2bf(v);
  } else if (g < 32896) {
    int r = g - 32768;
    float v;
    if (r == 0)       v = bv_head[0];
    else if (r == 1)  v = btb[0];
    else if (r == 2)  v = btb[1];
    else if (r < 9)   v = FW[BMP_OFF + r - 3];
    else if (r < 41)  v = FW[BG_OFF + r - 9];
    else if (r == 41) v = FW[SC0_OFF];
    else              v = 0.f;
    FW[BHD_OFF + r] = v;
  }
}

// ---------------- cln weights f32->bf16 ----------------
__global__ __launch_bounds__(256) void k_cvt(
    const float* __restrict__ wA, const float* __restrict__ wE,
    unsigned short* __restrict__ dst) {
  int e = (blockIdx.x * 256 + threadIdx.x) * 4;   // 262144 shorts
  const float* src = (e < 131072) ? wA : wE;
  int off = (e < 131072) ? 0 : 131072;
  float4 v = *(const float4*)(src + (e - off));
  u16x4 b; b.x = f2bf(v.x); b.y = f2bf(v.y); b.z = f2bf(v.z); b.w = f2bf(v.w);
  *(u16x4*)&dst[e] = b;
}

// ---------------- GRU fused weight fold: WGRU[1024][1024] bf16 + BGRU[1024] ----------------
// permuted rows: p = X*256 + df*64 + g*16 + i -> gate g of d = X*64+df*16+i
// cols: [0,768) = u (Wih), [768,1024) = hidden (Whh). g: 0=r 1=z 2=n_i 3=n_h
__global__ __launch_bounds__(256) void k_gruw(
    const float* __restrict__ Wih, const float* __restrict__ Whh,
    const float* __restrict__ bih, const float* __restrict__ bhh,
    unsigned short* __restrict__ WG, float* __restrict__ BG) {
  int t = blockIdx.x * 256 + threadIdx.x;
  if (t < 262144) {
    int e4 = t * 4;
    int p = e4 >> 10, c = e4 & 1023;
    int X = p >> 8, df = (p >> 6) & 3, g = (p >> 4) & 3, i = p & 15;
    int d = X * 64 + df * 16 + i;
    float4 v;
    if (c < 768) {
      if (g == 3) v = make_float4(0.f, 0.f, 0.f, 0.f);
      else        v = *(const float4*)(Wih + (long)(g * 256 + d) * 768 + c);
    } else {
      int ch = c - 768;
      if (g == 2) v = make_float4(0.f, 0.f, 0.f, 0.f);
      else {
        int row = (g == 3 ? 512 : g * 256) + d;
        v = *(const float4*)(Whh + (long)row * 256 + ch);
      }
    }
    u16x4 b; b.x = f2bf(v.x); b.y = f2bf(v.y); b.z = f2bf(v.z); b.w = f2bf(v.w);
    *(u16x4*)&WG[e4] = b;
  } else if (t < 263168) {
    int p = t - 262144;
    int X = p >> 8, df = (p >> 6) & 3, g = (p >> 4) & 3, i = p & 15;
    int d = X * 64 + df * 16 + i;
    float v;
    if (g == 0)      v = bih[d] + bhh[d];
    else if (g == 1) v = bih[256 + d] + bhh[256 + d];
    else if (g == 2) v = bih[512 + d];
    else             v = bhh[512 + d];
    BG[p] = v;
  }
}

// ---------------- small-K dense (K=30), dual f32+bf16 output ----------------
template<int K, int NOUT>
__global__ __launch_bounds__(256) void k_densek(
    const float* __restrict__ A, const float* __restrict__ W,
    const float* __restrict__ bias, float* __restrict__ C,
    unsigned short* __restrict__ Cb) {
  constexpr int KB = 32;
  __shared__ float As[64][36];
  const int tid = threadIdx.x;
  const int s0 = blockIdx.x * 64;
  const int o0 = blockIdx.y * 64;
  const int ox = (tid & 15) * 4;
  const int sy = (tid >> 4) * 4;
  float acc[4][4] = {};
  const float* Abase = A + (long)s0 * K;
  for (int idx = tid; idx < 64 * KB; idx += 256) {
    int s = idx >> 5, c = idx & 31;
    As[s][c] = (c < K) ? Abase[(long)s * K + c] : 0.f;
  }
  __syncthreads();
  for (int kk = 0; kk < KB; kk += 4) {
    float a4[4][4];
    #pragma unroll
    for (int sj = 0; sj < 4; ++sj)
      *(float4*)a4[sj] = *(const float4*)&As[sy + sj][kk];
    #pragma unroll
    for (int oi = 0; oi < 4; ++oi) {
      float w4[4];
      #pragma unroll
      for (int kx = 0; kx < 4; ++kx) {
        int k = kk + kx;
        w4[kx] = (k < K) ? W[(long)(o0 + ox + oi) * K + k] : 0.f;
      }
      #pragma unroll
      for (int sj = 0; sj < 4; ++sj)
        #pragma unroll
        for (int kx = 0; kx < 4; ++kx)
          acc[sj][oi] = fmaf(a4[sj][kx], w4[kx], acc[sj][oi]);
    }
  }
  #pragma unroll
  for (int sj = 0; sj < 4; ++sj) {
    float4 o4;
    o4.x = acc[sj][0] + bias[o0 + ox + 0];
    o4.y = acc[sj][1] + bias[o0 + ox + 1];
    o4.z = acc[sj][2] + bias[o0 + ox + 2];
    o4.w = acc[sj][3] + bias[o0 + ox + 3];
    *(float4*)&C[(long)(s0 + sy + sj) * NOUT + o0 + ox] = o4;
    u16x4 b4; b4.x = f2bf(o4.x); b4.y = f2bf(o4.y); b4.z = f2bf(o4.z); b4.w = f2bf(o4.w);
    *(u16x4*)&Cb[(long)(s0 + sy + sj) * NOUT + o0 + ox] = b4;
  }
}

// ---------------- MFMA dense (XCD-remapped blocks) ----------------
template<int K, int LDA, int NOUT, bool ABF>
__global__ __launch_bounds__(256) void k_mm(
    const void* __restrict__ Ap, const unsigned short* __restrict__ W,
    const float* __restrict__ bias, float* __restrict__ C) {
  constexpr int NCH = K / 32;
  __shared__ __align__(16) unsigned short As[4096];
  __shared__ __align__(16) unsigned short Ws[4096];
  const int tid = threadIdx.x;
  // XCD-aware remap: same-sample tiles land on same XCD (gy % 8 == 0)
  const int pid = blockIdx.y * gridDim.x + blockIdx.x;
  const int bx = (pid >> 3) % gridDim.x;
  const int by = ((pid >> 3) / gridDim.x) * 8 + (pid & 7);
  const int o0 = bx * 128;
  const long s0 = (long)by * 128;
  const int wv = tid >> 6, l = tid & 63;
  const int wm = (wv >> 1) * 64, wn = (wv & 1) * 64;
  const int lr = l & 15, lk = l >> 4;

  const int wrow = tid >> 2;
  const int wslot = tid & 3;
  const int q = tid & 3;

  f32x4 acc[4][4] = {};
  u16x8 pw[2];
  u16x8 pa_b[2];
  float4 pa_f[2][2];

  const unsigned short* Wb = W + (long)o0 * K;
  const unsigned short* Abf = (const unsigned short*)Ap;
  const float* Aff = (const float*)Ap;

  #pragma unroll
  for (int p = 0; p < 2; ++p) {
    const int r = wrow + 64 * p;
    pw[p] = *(const u16x8*)(Wb + (long)r * K + wslot * 8);
    if constexpr (ABF) {
      pa_b[p] = *(const u16x8*)(Abf + (s0 + r) * LDA + wslot * 8);
    } else {
      const float* Af = Aff + (s0 + r) * LDA + q * 4;
      pa_f[p][0] = *(const float4*)(Af);
      pa_f[p][1] = *(const float4*)(Af + 16);
    }
  }

  for (int ch = 0; ch < NCH; ++ch) {
    if (ch) __syncthreads();
    #pragma unroll
    for (int p = 0; p < 2; ++p) {
      const int r = wrow + 64 * p;
      const int ps = (wslot ^ (r & 3)) * 8;
      *(u16x8*)&Ws[r * 32 + ps] = pw[p];
      if constexpr (ABF) {
        *(u16x8*)&As[r * 32 + ps] = pa_b[p];
      } else {
        #pragma unroll
        for (int j = 0; j < 2; ++j) {
          float4 v = pa_f[p][j];
          unsigned long long pk =
              (unsigned long long)f2bf(v.x) |
              ((unsigned long long)f2bf(v.y) << 16) |
              ((unsigned long long)f2bf(v.z) << 32) |
              ((unsigned long long)f2bf(v.w) << 48);
          const int slot = (j * 2 + (q >> 1)) ^ (r & 3);
          *(unsigned long long*)&As[r * 32 + slot * 8 + (q & 1) * 4] = pk;
        }
      }
    }
    __syncthreads();
    if (ch + 1 < NCH) {
      const int k0 = (ch + 1) * 32;
      #pragma unroll
      for (int p = 0; p < 2; ++p) {
        const int r = wrow + 64 * p;
        pw[p] = *(const u16x8*)(Wb + (long)r * K + k0 + wslot * 8);
        if constexpr (ABF) {
          pa_b[p] = *(const u16x8*)(Abf + (s0 + r) * LDA + k0 + wslot * 8);
        } else {
          const float* Af = Aff + (s0 + r) * LDA + k0 + q * 4;
          pa_f[p][0] = *(const float4*)(Af);
          pa_f[p][1] = *(const float4*)(Af + 16);
        }
      }
    }
    bf16x8v af[4], bw[4];
    #pragma unroll
    for (int m = 0; m < 4; ++m) {
      const int r = wm + m * 16 + lr;
      af[m] = *(const bf16x8v*)&As[r * 32 + ((lk ^ (r & 3)) * 8)];
    }
    #pragma unroll
    for (int n = 0; n < 4; ++n) {
      const int r = wn + n * 16 + lr;
      bw[n] = *(const bf16x8v*)&Ws[r * 32 + ((lk ^ (r & 3)) * 8)];
    }
    #pragma unroll
    for (int m = 0; m < 4; ++m)
      #pragma unroll
      for (int n = 0; n < 4; ++n)
        acc[m][n] = __builtin_amdgcn_mfma_f32_16x16x32_bf16(af[m], bw[n], acc[m][n], 0, 0, 0);
  }

  #pragma unroll
  for (int n = 0; n < 4; ++n) {
    const float b = bias[o0 + wn + n * 16 + lr];
    #pragma unroll
    for (int m = 0; m < 4; ++m) {
      const long rowb = s0 + wm + m * 16 + lk * 4;
      #pragma unroll
      for (int r = 0; r < 4; ++r)
        C[(rowb + r) * (long)NOUT + o0 + wn + n * 16 + lr] = acc[m][n][r] + b;
    }
  }
}

// ---------------- fused GRU mega-GEMM: h = GRU(u, hidden) ----------------
// K=1024 ([u 768 | hidden 256]), out 1024 permuted gate rows, epilogue writes h.
__global__ __launch_bounds__(256) void k_gru_mm(
    const float* __restrict__ U, const float* __restrict__ hid,
    const unsigned short* __restrict__ WG, const float* __restrict__ BG,
    float* __restrict__ hout) {
  __shared__ __align__(16) unsigned short As[4096];
  __shared__ __align__(16) unsigned short Ws[8192];
  const int tid = threadIdx.x;
  const int pid = blockIdx.y * 4 + blockIdx.x;       // grid (4,128)
  const int bx = (pid >> 3) & 3;
  const int by = ((pid >> 3) >> 2) * 8 + (pid & 7);
  const long s0 = (long)by * 128;
  const int wv = tid >> 6, l = tid & 63;
  const int wm = (wv >> 1) * 64;
  const int lr = l & 15, lk = l >> 4;
  const int wrow = tid >> 2;
  const int q = tid & 3;

  f32x4 acc[4][8] = {};
  u16x8 pw[4];
  float4 pa[2][2];

  const unsigned short* Wb = WG + (long)(bx * 256) * 1024;

  #pragma unroll
  for (int p = 0; p < 4; ++p)
    pw[p] = *(const u16x8*)(Wb + (long)(wrow + 64 * p) * 1024 + q * 8);
  #pragma unroll
  for (int p = 0; p < 2; ++p) {
    const float* src = U + (s0 + wrow + 64 * p) * 1024 + q * 4;
    pa[p][0] = *(const float4*)(src);
    pa[p][1] = *(const float4*)(src + 16);
  }

  for (int ch = 0; ch < 32; ++ch) {
    if (ch) __syncthreads();
    #pragma unroll
    for (int p = 0; p < 4; ++p) {
      const int r = wrow + 64 * p;
      const int ps = (q ^ (r & 3)) * 8;
      *(u16x8*)&Ws[r * 32 + ps] = pw[p];
    }
    #pragma unroll
    for (int p = 0; p < 2; ++p) {
      const int r = wrow + 64 * p;
      #pragma unroll
      for (int j = 0; j < 2; ++j) {
        float4 v = pa[p][j];
        unsigned long long pk =
            (unsigned long long)f2bf(v.x) |
            ((unsigned long long)f2bf(v.y) << 16) |
            ((unsigned long long)f2bf(v.z) << 32) |
            ((unsigned long long)f2bf(v.w) << 48);
        const int slot = (j * 2 + (q >> 1)) ^ (r & 3);
        *(unsigned long long*)&As[r * 32 + slot * 8 + (q & 1) * 4] = pk;
      }
    }
    __syncthreads();
    if (ch + 1 < 32) {
      const int k0 = (ch + 1) * 32;
      #pragma unroll
      for (int p = 0; p < 4; ++p)
        pw[p] = *(const u16x8*)(Wb + (long)(wrow + 64 * p) * 1024 + k0 + q * 8);
      #pragma unroll
      for (int p = 0; p < 2; ++p) {
        const int r = wrow + 64 * p;
        const float* src;
        if (k0 < 768) src = U + (s0 + r) * 1024 + k0 + q * 4;
        else          src = hid + (s0 + r) * 256 + (k0 - 768) + q * 4;
        pa[p][0] = *(const float4*)(src);
        pa[p][1] = *(const float4*)(src + 16);
      }
    }
    bf16x8v af[4], bw[8];
    #pragma unroll
    for (int m = 0; m < 4; ++m) {
      const int r = wm + m * 16 + lr;
      af[m] = *(const bf16x8v*)&As[r * 32 + ((lk ^ (r & 3)) * 8)];
    }
    #pragma unroll
    for (int n = 0; n < 8; ++n) {
      const int r = (wv & 1) * 128 + n * 16 + lr;
      bw[n] = *(const bf16x8v*)&Ws[r * 32 + ((lk ^ (r & 3)) * 8)];
    }
    #pragma unroll
    for (int m = 0; m < 4; ++m)
      #pragma unroll
      for (int n = 0; n < 8; ++n)
        acc[m][n] = __builtin_amdgcn_mfma_f32_16x16x32_bf16(af[m], bw[n], acc[m][n], 0, 0, 0);
  }

  // GRU epilogue: frag F = (wv&1)*8 + n -> df = F>>2, gate g = F&3
  #pragma unroll
  for (int df2 = 0; df2 < 2; ++df2) {
    const int df = (wv & 1) * 2 + df2;
    const int d = bx * 64 + df * 16 + lr;
    const int bb = bx * 256 + df * 64 + lr;
    const float bR = BG[bb], bZ = BG[bb + 16], bNi = BG[bb + 32], bNh = BG[bb + 48];
    #pragma unroll
    for (int m = 0; m < 4; ++m) {
      const long srow = s0 + wm + m * 16 + lk * 4;
      #pragma unroll
      for (int rr = 0; rr < 4; ++rr) {
        const long s = srow + rr;
        const float r_ = 1.f / (1.f + expf(-(acc[m][df2 * 4 + 0][rr] + bR)));
        const float z_ = 1.f / (1.f + expf(-(acc[m][df2 * 4 + 1][rr] + bZ)));
        const float n_ = tanhf(acc[m][df2 * 4 + 2][rr] + bNi +
                               r_ * (acc[m][df2 * 4 + 3][rr] + bNh));
        const float hp = hid[s * 256 + d];
        hout[s * 256 + d] = (1.f - z_) * n_ + z_ * hp;
      }
    }
  }
}

// ---------------- merged attention core ----------------
__global__ __launch_bounds__(256) void k_core2(
    const float* __restrict__ rawA, const float* __restrict__ rawE,
    const float* __restrict__ g, const float* __restrict__ gt_w,
    const float* __restrict__ gt_b, unsigned short* __restrict__ pal) {
  __shared__ float A_[4][15][36];
  __shared__ float E_[4][16][36];
  __shared__ float G_[4][8][32];
  __shared__ float P_[4][8][16];
  const int tid = threadIdx.x;
  const int w = tid >> 6, l = tid & 63;
  const long s = (long)blockIdx.x * 4 + w;

  const float* ra = rawA + s * 480;
  const float* re = rawE + s * 512;
  const float* gr = g + s * 256;
  #pragma unroll
  for (int i = l; i < 120; i += 64) {
    float4 v = *(const float4*)(ra + i * 4);
    *(float4*)&A_[w][i >> 3][(i & 7) * 4] = v;
  }
  #pragma unroll
  for (int i = l; i < 128; i += 64) {
    float4 v = *(const float4*)(re + i * 4);
    *(float4*)&E_[w][i >> 3][(i & 7) * 4] = v;
  }
  {
    float4 v = *(const float4*)(gr + l * 4);
    *(float4*)&G_[w][l >> 3][(l & 7) * 4] = v;
  }
  __syncthreads();

  bool mv = false;
  if (l < 15) {
    #pragma unroll
    for (int c = 0; c < 8; ++c) {
      float4 x = *(const float4*)&A_[w][l][c * 4];
      mv |= (x.x != 0.f) | (x.y != 0.f) | (x.z != 0.f) | (x.w != 0.f);
    }
  } else if (l >= 16 && l < 32) {
    #pragma unroll
    for (int c = 0; c < 8; ++c) {
      float4 x = *(const float4*)&E_[w][l - 16][c * 4];
      mv |= (x.x != 0.f) | (x.y != 0.f) | (x.z != 0.f) | (x.w != 0.f);
    }
  }
  unsigned long long bal = __ballot(mv);
  unsigned mA = (unsigned)bal & 0x7FFFu;
  unsigned mE = (unsigned)(bal >> 16) & 0xFFFFu;
  float xa = gt_w[0] * log1pf((float)__popc(mA)) + gt_b[0];
  float spa = fmaxf(xa, 0.f) + log1pf(expf(-fabsf(xa)));
  float scaleA = 1.f / (8.f * (spa + 1.f));
  float xe = gt_w[1] * log1pf((float)__popc(mE)) + gt_b[1];
  float spe = fmaxf(xe, 0.f) + log1pf(expf(-fabsf(xe)));
  float scaleE = 1.f / (8.f * (spe + 1.f));

  {
    const int h = l >> 4, n = l & 15;
    const bool okA = (n < 15) && ((mA >> n) & 1);
    const bool okE = (mE >> n) & 1;
    const float* arow = &A_[w][n < 15 ? n : 0][0];
    const float* erow = &E_[w][n][0];
    const float* garow = &G_[w][h][0];
    const float* gerow = &G_[w][4 + h][0];
    float accA = 0.f, accE = 0.f;
    #pragma unroll
    for (int j = 0; j < 32; ++j) {
      accA = fmaf(garow[j], arow[j], accA);
      accE = fmaf(gerow[j], erow[j], accE);
    }
    float sA = okA ? accA * scaleA : -INFINITY;
    float sE = okE ? accE * scaleE : -INFINITY;
    float mAx = sA, mEx = sE;
    #pragma unroll
    for (int off = 8; off; off >>= 1) {
      mAx = fmaxf(mAx, __shfl_xor(mAx, off));
      mEx = fmaxf(mEx, __shfl_xor(mEx, off));
    }
    float eA = okA ? expf(sA - mAx) : 0.f;
    float eE = okE ? expf(sE - mEx) : 0.f;
    float suA = eA, suE = eE;
    #pragma unroll
    for (int off = 8; off; off >>= 1) {
      suA += __shfl_xor(suA, off);
      suE += __shfl_xor(suE, off);
    }
    P_[w][h][n] = eA / suA;
    P_[w][4 + h][n] = eE / suE;
  }
  __syncthreads();

  {
    const int j = l & 31, hh = l >> 5;
    unsigned short* po = pal + s * 256 + hh * 32 + j;
    #pragma unroll
    for (int r = 0; r < 2; ++r) {
      const int ha = r * 2 + hh;
      float a0 = 0.f, a1 = 0.f;
      #pragma unroll
      for (int n = 0; n < 15; ++n)
        a0 = fmaf(P_[w][ha][n], A_[w][n][j], a0);
      #pragma unroll
      for (int n = 0; n < 16; ++n)
        a1 = fmaf(P_[w][4 + ha][n], E_[w][n][j], a1);
      po[r * 64] = f2bf(a0);
      po[128 + r * 64] = f2bf(a1);
    }
  }
}

// ---------------- fused CLN+CLN+LN3 -> u ----------------
__global__ __launch_bounds__(256) void k_clnln(
    const float* __restrict__ aA, const float* __restrict__ aE,
    const float* __restrict__ qsrc, float* gbu,
    const float* __restrict__ g, const float* __restrict__ b) {
  int w = threadIdx.x >> 6, l = threadIdx.x & 63;
  long s = (long)blockIdx.x * 4 + w;
  int d = l * 4;
  float4 vA = *(const float4*)(aA + s * 256 + d);
  float4 vE = *(const float4*)(aE + s * 256 + d);
  float4 vq = *(const float4*)(qsrc + s * 256 + d);
  float* gbr = gbu + s * 1024;
  float sumA = vA.x + vA.y + vA.z + vA.w;
  float ssqA = vA.x*vA.x + vA.y*vA.y + vA.z*vA.z + vA.w*vA.w;
  float sumE = vE.x + vE.y + vE.z + vE.w;
  float ssqE = vE.x*vE.x + vE.y*vE.y + vE.z*vE.z + vE.w*vE.w;
  #pragma unroll
  for (int off = 32; off > 0; off >>= 1) {
    sumA += __shfl_xor(sumA, off); ssqA += __shfl_xor(ssqA, off);
    sumE += __shfl_xor(sumE, off); ssqE += __shfl_xor(ssqE, off);
  }
  float muA = sumA * (1.f / 256.f);
  float rstdA = rsqrtf(ssqA * (1.f / 256.f) - muA * muA + 1e-5f);
  float muE = sumE * (1.f / 256.f);
  float rstdE = rsqrtf(ssqE * (1.f / 256.f) - muE * muE + 1e-5f);

  float4 gA4 = *(const float4*)(gbr + d);
  float4 bA4 = *(const float4*)(gbr + 256 + d);
  float4 gE4 = *(const float4*)(gbr + 512 + d);
  float4 bE4 = *(const float4*)(gbr + 768 + d);
  float4 zA, zE;
  zA.x = (1.f + gA4.x) * ((vA.x - muA) * rstdA) + bA4.x;
  zA.y = (1.f + gA4.y) * ((vA.y - muA) * rstdA) + bA4.y;
  zA.z = (1.f + gA4.z) * ((vA.z - muA) * rstdA) + bA4.z;
  zA.w = (1.f + gA4.w) * ((vA.w - muA) * rstdA) + bA4.w;
  zE.x = (1.f + gE4.x) * ((vE.x - muE) * rstdE) + bE4.x;
  zE.y = (1.f + gE4.y) * ((vE.y - muE) * rstdE) + bE4.y;
  zE.z = (1.f + gE4.z) * ((vE.z - muE) * rstdE) + bE4.z;
  zE.w = (1.f + gE4.w) * ((vE.w - muE) * rstdE) + bE4.w;

  float sum = vq.x+vq.y+vq.z+vq.w + zA.x+zA.y+zA.z+zA.w + zE.x+zE.y+zE.z+zE.w;
  float ssq = vq.x*vq.x+vq.y*vq.y+vq.z*vq.z+vq.w*vq.w
            + zA.x*zA.x+zA.y*zA.y+zA.z*zA.z+zA.w*zA.w
            + zE.x*zE.x+zE.y*zE.y+zE.z*zE.z+zE.w*zE.w;
  #pragma unroll
  for (int off = 32; off > 0; off >>= 1) {
    sum += __shfl_xor(sum, off); ssq += __shfl_xor(ssq, off);
  }
  float mu = sum * (1.f / 768.f);
  float rstd = rsqrtf(ssq * (1.f / 768.f) - mu * mu + 1e-5f);

  float4 g0 = *(const float4*)(g + d),       b0 = *(const float4*)(b + d);
  float4 g1 = *(const float4*)(g + 256 + d), b1 = *(const float4*)(b + 256 + d);
  float4 g2 = *(const float4*)(g + 512 + d), b2 = *(const float4*)(b + 512 + d);
  float4 o0, o1, o2;
  o0.x = (vq.x - mu) * rstd * g0.x + b0.x;
  o0.y = (vq.y - mu) * rstd * g0.y + b0.y;
  o0.z = (vq.z - mu) * rstd * g0.z + b0.z;
  o0.w = (vq.w - mu) * rstd * g0.w + b0.w;
  o1.x = (zA.x - mu) * rstd * g1.x + b1.x;
  o1.y = (zA.y - mu) * rstd * g1.y + b1.y;
  o1.z = (zA.z - mu) * rstd * g1.z + b1.z;
  o1.w = (zA.w - mu) * rstd * g1.w + b1.w;
  o2.x = (zE.x - mu) * rstd * g2.x + b2.x;
  o2.y = (zE.y - mu) * rstd * g2.y + b2.y;
  o2.z = (zE.z - mu) * rstd * g2.z + b2.z;
  o2.w = (zE.w - mu) * rstd * g2.w + b2.w;
  *(float4*)(gbr + d) = o0;
  *(float4*)(gbr + 256 + d) = o1;
  *(float4*)(gbr + 512 + d) = o2;
}

// ---------------- heads epilogue ----------------
__global__ __launch_bounds__(256) void k_heads2(
    const float* __restrict__ OB, const float* __restrict__ eraw,
    const float* __restrict__ log_tau, float* __restrict__ Qout) {
  __shared__ float obs[16][48];
  const int tid = threadIdx.x;
  const long s0 = (long)blockIdx.x * 16;
  for (int idx = tid; idx < 768; idx += 256)
    obs[idx / 48][idx % 48] = OB[(s0 + idx / 48) * 128 + idx % 48];
  __syncthreads();
  const int w = tid >> 4, i = tid & 15;
  const long s = s0 + w;
  const float itm = 1.f / (expf(log_tau[0]) + 1e-6f);
  const float its = 1.f / (expf(log_tau[1]) + 1e-6f);
  const float V = obs[w][0];
  const float* er = eraw + s * 512 + i * 32;
  bool valid = false; float acc = 0.f;
  #pragma unroll
  for (int jb = 0; jb < 8; ++jb) {
    float4 e4 = *(const float4*)(er + jb * 4);
    valid |= (e4.x != 0.f) | (e4.y != 0.f) | (e4.z != 0.f) | (e4.w != 0.f);
    acc += obs[w][9 + jb * 4 + 0] * e4.x + obs[w][9 + jb * 4 + 1] * e4.y +
           obs[w][9 + jb * 4 + 2] * e4.z + obs[w][9 + jb * 4 + 3] * e4.w;
  }
  float a = (acc + obs[w][41]) * 0.0625f;
  float sa = valid ? a : 0.f;
  float cv = valid ? 1.f : 0.f;
  #pragma unroll
  for (int off = 8; off > 0; off >>= 1) {
    sa += __shfl_xor(sa, off);
    cv += __shfl_xor(cv, off);
  }
  float me = sa / fmaxf(cv, 1.f);
  Qout[s * 22 + 6 + i] = V + obs[w][2] + (valid ? (a - me) * its : -1e30f * its);
  if (i < 6) {
    float mean = 0.f;
    #pragma unroll
    for (int t = 0; t < 6; ++t) mean += obs[w][3 + t];
    mean *= (1.f / 6.f);
    Qout[s * 22 + i] = V + obs[w][1] + (obs[w][3 + i] - mean) * 0.0625f * itm;
  }
}

// ---------------- launch ----------------
extern "C" void kernel_launch(void* const* d_in, const int* in_sizes, int n_in,
                              void* d_out, int out_size, void* d_ws, size_t ws_size,
                              hipStream_t stream) {
  const float* own_raw   = (const float*)d_in[0];
  const float* ally_raw  = (const float*)d_in[1];
  const float* enemy_raw = (const float*)d_in[2];
  const float* hidden    = (const float*)d_in[3];
  const float* W_own     = (const float*)d_in[4];
  const float* b_own     = (const float*)d_in[5];
  const float* W_ally    = (const float*)d_in[6];
  const float* b_ally    = (const float*)d_in[7];
  const float* W_enemy   = (const float*)d_in[8];
  const float* b_enemy   = (const float*)d_in[9];
  const float* gt_w      = (const float*)d_in[10];
  const float* gt_b      = (const float*)d_in[11];
  const float* attnA_W   = (const float*)d_in[12];
  const float* attnA_b   = (const float*)d_in[13];
  const float* attnE_W   = (const float*)d_in[14];
  const float* attnE_b   = (const float*)d_in[15];
  const float* clnA_W    = (const float*)d_in[16];
  const float* clnA_b    = (const float*)d_in[17];
  const float* clnE_W    = (const float*)d_in[18];
  const float* clnE_b    = (const float*)d_in[19];
  const float* ln3_g     = (const float*)d_in[20];
  const float* ln3_b     = (const float*)d_in[21];
  const float* gru_Wih   = (const float*)d_in[22];
  const float* gru_Whh   = (const float*)d_in[23];
  const float* gru_bih   = (const float*)d_in[24];
  const float* gru_bhh   = (const float*)d_in[25];
  const float* Wv_head   = (const float*)d_in[26];
  const float* bv_head   = (const float*)d_in[27];
  const float* Wtb       = (const float*)d_in[28];
  const float* btb       = (const float*)d_in[29];
  const float* log_tau   = (const float*)d_in[30];
  const float* Wmq       = (const float*)d_in[31];
  const float* bmq       = (const float*)d_in[32];
  const float* protos    = (const float*)d_in[33];
  const float* Wqs       = (const float*)d_in[34];
  const float* bqs       = (const float*)d_in[35];
  const float* Wke       = (const float*)d_in[36];
  const float* bke       = (const float*)d_in[37];

  float* ws  = (float*)d_ws;
  float* out = (float*)d_out;
  float* hout = out + HOFF;
  unsigned short* WB   = (unsigned short*)hout;            // bf16 weight cache
  unsigned short* qsb  = (unsigned short*)(ws + BUF2_OFF);
  unsigned short* palb = (unsigned short*)(ws + BUF2_OFF);
  unsigned short* WHD  = (unsigned short*)ws;
  unsigned short* wgru = (unsigned short*)(ws + BUF1_OFF); // written after core2

  k_fuse1<<<160, 256, 0, stream>>>(attnA_W, attnA_b, attnE_W, attnE_b,
                                   W_ally, b_ally, W_enemy, b_enemy, Wke, bke, ws);
  k_fuse2<<<40, 256, 0, stream>>>(protos, Wmq, bmq, Wqs, bqs, ws);
  k_fuse3<<<261, 256, 0, stream>>>(attnA_W, attnA_b, attnE_W, attnE_b,
                                   clnA_b, clnE_b, ws, WB + MGB_S);
  k_fuse5<<<258, 256, 0, stream>>>(attnA_W, attnA_b, attnE_W, attnE_b,
                                   ws, WB + PJA_S, WB + PJE_S);
  k_fuse4<<<129, 256, 0, stream>>>(Wv_head, bv_head, Wtb, btb, ws, WHD);
  k_cvt<<<256, 256, 0, stream>>>(clnA_W, clnE_W, WB + CLA_S);

  // q_src (f32 + bf16)
  k_densek<30, 256><<<dim3(BN/64, 4), 256, 0, stream>>>(own_raw, W_own, b_own,
                                                        ws + QSRC_OFF, qsb);

  // g (both branches) ; cln gamma/beta (one GEMM)
  k_mm<256, 256, 256, true><<<dim3(2, 128), 256, 0, stream>>>(qsb, WB + MGB_S, ws + BMG_OFF, ws + GBUF_OFF);
  k_mm<256, 256, 1024, true><<<dim3(8, 128), 256, 0, stream>>>(qsb, WB + CLA_S, ws + CLB_OFF, ws + GB_OFF);

  // merged attention core -> pal (bf16)
  k_core2<<<BN/4, 256, 0, stream>>>(ally_raw, enemy_raw, ws + GBUF_OFF,
                                    gt_w, gt_b, palb);

  // GRU folded weights (into BUF1, now dead) + bias
  k_gruw<<<1028, 256, 0, stream>>>(gru_Wih, gru_Whh, gru_bih, gru_bhh,
                                   wgru, ws + BGRU_OFF);

  // aout = pal @ PV + bpj (both branches, K=128)
  k_mm<128, 256, 256, true><<<dim3(2, 128), 256, 0, stream>>>(palb, WB + PJA_S, ws + BPJA_OFF, ws + AOUTA_OFF);
  k_mm<128, 256, 256, true><<<dim3(2, 128), 256, 0, stream>>>(palb + 128, WB + PJE_S, ws + BPJE_OFF, ws + AOUTE_OFF);

  // fused cln+cln+ln3 -> u
  k_clnln<<<BN/4, 256, 0, stream>>>(ws + AOUTA_OFF, ws + AOUTE_OFF, ws + QSRC_OFF,
                                    ws + GB_OFF, ln3_g, ln3_b);

  // fused GRU mega-GEMM -> h
  k_gru_mm<<<dim3(4, 128), 256, 0, stream>>>(ws + U_OFF, hidden, wgru,
                                             ws + BGRU_OFF, hout);

  // heads: OB = h @ WHD.T, then epilogue
  k_mm<256, 256, 128, false><<<dim3(1, 128), 256, 0, stream>>>(hout, WHD, ws + BHD_OFF, ws + OB_OFF);
  k_heads2<<<BN/16, 256, 0, stream>>>(ws + OB_OFF, enemy_raw, log_tau, out);
}

// Round 7
// 219.595 us; speedup vs baseline: 12.9717x; 1.1268x over previous
//
#include <hip/hip_runtime.h>
#include <math.h>

#define BN 16384

typedef float f32x4 __attribute__((ext_vector_type(4)));
typedef short bf16x8v __attribute__((ext_vector_type(8)));
typedef unsigned short u16x8 __attribute__((ext_vector_type(8)));
typedef unsigned short u16x4 __attribute__((ext_vector_type(4)));

static __device__ inline unsigned short f2bf(float f) {
  unsigned u = __float_as_uint(f);
  return (unsigned short)((u + 0x8000u) >> 16);
}

// ---------------- workspace float offsets ----------------
#define WKA_OFF   0
#define WVA_OFF   8192
#define WKE_OFF   16384
#define WVE_OFF   24576
#define WKEF_OFF  32768
#define BKA_OFF   40960
#define BVA_OFF   41216
#define BKE_OFF   41472
#define BVE_OFF   41728
#define BKEF_OFF  41984
#define WMP_OFF   43008
#define BMP_OFF   44544
#define G_OFF     45056
#define BG_OFF    53248
#define WQB_OFF   53312
#define SC0_OFF   53568
#define BMG_OFF   53632   /* 256: folded g bias */
#define CLB_OFF   53888   /* 1024: clnA_b ++ clnE_b (contiguous after BMG) */
#define BPJA_OFF  57088   /* 256 */
#define BPJE_OFF  57344   /* 256 (contiguous) */
#define BGRU_OFF  57600   /* 1024 folded GRU bias */
#define BHD_OFF   16384   /* 128 heads bias (over dead WKE) */
// WHD bf16 heads weights: shorts at float offset 0 (written by k_fuse4)

#define QSRC_OFF  65536
#define BUF1_OFF  (QSRC_OFF + BN*256)
#define BUF2_OFF  (BUF1_OFF + BN*256)
#define BUF3_OFF  (BUF2_OFF + BN*256)
#define BUF4_OFF  (BUF3_OFF + BN*256)
#define BUF5_OFF  (BUF4_OFF + BN*256)   /* BN*1024 region */

#define GBUF_OFF  BUF1_OFF   // g (gA|gE) f32 for core (dead after core2)
#define AOUTA_OFF BUF3_OFF
#define AOUTE_OFF BUF4_OFF
#define GB_OFF    BUF5_OFF   // [BN][1024] f32 gamma/beta
#define OB_OFF    BUF1_OFF   // [BN][128] heads pre-products (after mega)
// qsb / pal bf16 at BUF2 (shorts)
// WGRU bf16 [1024][1024] shorts at BUF1 (after core2)
#define UB_OFF    (BUF1_OFF + 524288)   // u bf16 [BN][768] shorts (spans into BUF2; pal dead)

#define HOFF      (BN*22)

// bf16 weight cache in d_out's h-region (shorts; dead until mega writes h)
#define MGB_S 0         /* 256x256  */
#define CLA_S 65536     /* 512x256  */
#define CLE_S 196608    /* 512x256  */
#define PJA_S 327680    /* 256x128  */
#define PJE_S 360448    /* 256x128  (contiguous with PJA) */

// ---------------- fuseA: fuse1 + cln weight cvt ----------------
__global__ __launch_bounds__(256) void k_fuseA(
    const float* __restrict__ attnA_W, const float* __restrict__ attnA_b,
    const float* __restrict__ attnE_W, const float* __restrict__ attnE_b,
    const float* __restrict__ W_ally,  const float* __restrict__ b_ally,
    const float* __restrict__ W_enemy, const float* __restrict__ b_enemy,
    const float* __restrict__ Wke,     const float* __restrict__ bke,
    const float* __restrict__ clnA_W,  const float* __restrict__ clnE_W,
    float* __restrict__ FW, unsigned short* __restrict__ WBc) {
  int g = blockIdx.x * 256 + threadIdx.x;
  if (g < 40960) {
    int m = g >> 13;
    int r = g & 8191;
    int d = r >> 5, j = r & 31;
    const float *Wout, *Win, *bin, *bout; float *dst, *dstb;
    switch (m) {
      case 0: Wout = attnA_W + 65536;  Win = W_ally;  bin = b_ally;  bout = attnA_b + 256; dst = FW + WKA_OFF;  dstb = FW + BKA_OFF;  break;
      case 1: Wout = attnA_W + 131072; Win = W_ally;  bin = b_ally;  bout = attnA_b + 512; dst = FW + WVA_OFF;  dstb = FW + BVA_OFF;  break;
      case 2: Wout = attnE_W + 65536;  Win = W_enemy; bin = b_enemy; bout = attnE_b + 256; dst = FW + WKE_OFF;  dstb = FW + BKE_OFF;  break;
      case 3: Wout = attnE_W + 131072; Win = W_enemy; bin = b_enemy; bout = attnE_b + 512; dst = FW + WVE_OFF;  dstb = FW + BVE_OFF;  break;
      default:Wout = Wke;              Win = W_enemy; bin = b_enemy; bout = bke;           dst = FW + WKEF_OFF; dstb = FW + BKEF_OFF; break;
    }
    float acc = 0.f;
    for (int c = 0; c < 256; ++c) acc += Wout[d*256 + c] * Win[c*32 + j];
    dst[d*32 + j] = acc;
    if (j == 0) {
      float b = bout[d];
      for (int c = 0; c < 256; ++c) b += Wout[d*256 + c] * bin[c];
      dstb[d] = b;
    }
  } else {
    int t = g - 40960;
    if (t < 65536) {
      int e = t * 4;
      const float* src = (e < 131072) ? clnA_W : clnE_W;
      int off = (e < 131072) ? 0 : 131072;
      float4 v = *(const float4*)(src + (e - off));
      u16x4 b; b.x = f2bf(v.x); b.y = f2bf(v.y); b.z = f2bf(v.z); b.w = f2bf(v.w);
      *(u16x4*)&WBc[CLA_S + e] = b;
    }
  }
}

// ---------------- fuseB: fuse2 + fuse3 + fuse5 (all depend only on fuseA) ----------------
__global__ __launch_bounds__(256) void k_fuseB(
    const float* __restrict__ protos, const float* __restrict__ Wmq,
    const float* __restrict__ bmq,    const float* __restrict__ Wqs,
    const float* __restrict__ bqs,
    const float* __restrict__ attnA_W, const float* __restrict__ attnA_b,
    const float* __restrict__ attnE_W, const float* __restrict__ attnE_b,
    const float* __restrict__ clnA_b,  const float* __restrict__ clnE_b,
    float* __restrict__ FW, unsigned short* __restrict__ WBc) {
  int g = blockIdx.x * 256 + threadIdx.x;
  const float* WKe_f = FW + WKEF_OFF;
  const float* bKe_f = FW + BKEF_OFF;
  if (g < 10240) {
    if (g < 1536) {
      int i = g >> 8, c = g & 255;
      float acc = 0.f;
      for (int d = 0; d < 256; ++d) acc += protos[i*256 + d] * Wmq[d*256 + c];
      FW[WMP_OFF + i*256 + c] = acc;
    } else if (g < 9728) {
      int r = g - 1536;
      int j = r >> 8, c = r & 255;
      float acc = 0.f;
      for (int d = 0; d < 256; ++d) acc += WKe_f[d*32 + j] * Wqs[d*256 + c];
      FW[G_OFF + j*256 + c] = acc;
    } else if (g < 9984) {
      int c = g - 9728;
      float acc = 0.f;
      for (int d = 0; d < 256; ++d) acc += Wqs[d*256 + c] * bKe_f[d];
      FW[WQB_OFF + c] = acc;
    } else if (g < 9990) {
      int i = g - 9984;
      float acc = 0.f;
      for (int d = 0; d < 256; ++d) acc += protos[i*256 + d] * bmq[d];
      FW[BMP_OFF + i] = acc;
    } else if (g < 10022) {
      int j = g - 9990;
      float acc = 0.f;
      for (int d = 0; d < 256; ++d) acc += WKe_f[d*32 + j] * bqs[d];
      FW[BG_OFF + j] = acc;
    } else if (g == 10022) {
      float acc = 0.f;
      for (int d = 0; d < 256; ++d) acc += bqs[d] * bKe_f[d];
      FW[SC0_OFF] = acc;
    }
  } else if (g < 77056) {
    int t = g - 10240;     // fuse3
    if (t < 65536) {
      int r = t >> 8, c = t & 255;
      int br = r >> 7, jj = r & 127, h = jj >> 5, jc = jj & 31;
      const float* W0 = br ? attnE_W : attnA_W;
      const float* Wk = FW + (br ? WKE_OFF : WKA_OFF);
      float acc = 0.f;
      for (int d = 0; d < 64; ++d)
        acc += W0[(h*64+d)*256 + c] * Wk[(h*64+d)*32 + jc];
      WBc[MGB_S + r*256 + c] = f2bf(acc);
    } else if (t < 65792) {
      int r = t - 65536;
      int br = r >> 7, jj = r & 127, h = jj >> 5, jc = jj & 31;
      const float* b0 = br ? attnE_b : attnA_b;
      const float* Wk = FW + (br ? WKE_OFF : WKA_OFF);
      float acc = 0.f;
      for (int d = 0; d < 64; ++d) acc += b0[h*64+d] * Wk[(h*64+d)*32 + jc];
      FW[BMG_OFF + r] = acc;
    } else {
      int c = t - 65792;
      FW[CLB_OFF + c] = (c < 512) ? clnA_b[c] : clnE_b[c - 512];
    }
  } else {
    int t = g - 77056;     // fuse5
    if (t < 65536) {
      int br = t >> 15;
      int r0 = t & 32767;
      int o = r0 >> 7, r = r0 & 127, h = r >> 5, j = r & 31;
      const float* Wp = (br ? attnE_W : attnA_W) + 196608;
      const float* Wv = FW + (br ? WVE_OFF : WVA_OFF);
      float acc = 0.f;
      for (int d = 0; d < 64; ++d)
        acc += Wp[o*256 + h*64 + d] * Wv[(h*64+d)*32 + j];
      WBc[(br ? PJE_S : PJA_S) + o*128 + r] = f2bf(acc);
    } else if (t < 66048) {
      int r0 = t - 65536;
      int br = r0 >> 8, c = r0 & 255;
      const float* Wp = (br ? attnE_W : attnA_W) + 196608;
      const float* bv = FW + (br ? BVE_OFF : BVA_OFF);
      const float* pb = (br ? attnE_b : attnA_b) + 768;
      float acc = pb[c];
      for (int d = 0; d < 256; ++d) acc += Wp[c*256 + d] * bv[d];
      FW[(br ? BPJE_OFF : BPJA_OFF) + c] = acc;
    }
  }
}

// ---------------- heads fold: WHD[128][256] bf16 + BHD[128] ----------------
__global__ __launch_bounds__(256) void k_fuse4(
    const float* __restrict__ Wv_head, const float* __restrict__ bv_head,
    const float* __restrict__ Wtb, const float* __restrict__ btb,
    float* __restrict__ FW, unsigned short* __restrict__ WHD) {
  int g = blockIdx.x * 256 + threadIdx.x;
  if (g < 32768) {
    int r = g >> 8, c = g & 255;
    float v;
    if (r == 0)       v = Wv_head[c];
    else if (r == 1)  v = Wtb[c];
    else if (r == 2)  v = Wtb[256 + c];
    else if (r < 9)   v = FW[WMP_OFF + (r - 3) * 256 + c];
    else if (r < 41)  v = FW[G_OFF + (r - 9) * 256 + c];
    else if (r == 41) v = FW[WQB_OFF + c];
    else              v = 0.f;
    WHD[r * 256 + c] = f2bf(v);
  } else if (g < 32896) {
    int r = g - 32768;
    float v;
    if (r == 0)       v = bv_head[0];
    else if (r == 1)  v = btb[0];
    else if (r == 2)  v = btb[1];
    else if (r < 9)   v = FW[BMP_OFF + r - 3];
    else if (r < 41)  v = FW[BG_OFF + r - 9];
    else if (r == 41) v = FW[SC0_OFF];
    else              v = 0.f;
    FW[BHD_OFF + r] = v;
  }
}

// ---------------- GRU fused weight fold: WGRU[1024][1024] bf16 + BGRU[1024] ----------------
__global__ __launch_bounds__(256) void k_gruw(
    const float* __restrict__ Wih, const float* __restrict__ Whh,
    const float* __restrict__ bih, const float* __restrict__ bhh,
    unsigned short* __restrict__ WG, float* __restrict__ BG) {
  int t = blockIdx.x * 256 + threadIdx.x;
  if (t < 262144) {
    int e4 = t * 4;
    int p = e4 >> 10, c = e4 & 1023;
    int X = p >> 8, df = (p >> 6) & 3, g = (p >> 4) & 3, i = p & 15;
    int d = X * 64 + df * 16 + i;
    float4 v;
    if (c < 768) {
      if (g == 3) v = make_float4(0.f, 0.f, 0.f, 0.f);
      else        v = *(const float4*)(Wih + (long)(g * 256 + d) * 768 + c);
    } else {
      int ch = c - 768;
      if (g == 2) v = make_float4(0.f, 0.f, 0.f, 0.f);
      else {
        int row = (g == 3 ? 512 : g * 256) + d;
        v = *(const float4*)(Whh + (long)row * 256 + ch);
      }
    }
    u16x4 b; b.x = f2bf(v.x); b.y = f2bf(v.y); b.z = f2bf(v.z); b.w = f2bf(v.w);
    *(u16x4*)&WG[e4] = b;
  } else if (t < 263168) {
    int p = t - 262144;
    int X = p >> 8, df = (p >> 6) & 3, g = (p >> 4) & 3, i = p & 15;
    int d = X * 64 + df * 16 + i;
    float v;
    if (g == 0)      v = bih[d] + bhh[d];
    else if (g == 1) v = bih[256 + d] + bhh[256 + d];
    else if (g == 2) v = bih[512 + d];
    else             v = bhh[512 + d];
    BG[p] = v;
  }
}

// ---------------- small-K dense (K=30), dual f32+bf16 output ----------------
template<int K, int NOUT>
__global__ __launch_bounds__(256) void k_densek(
    const float* __restrict__ A, const float* __restrict__ W,
    const float* __restrict__ bias, float* __restrict__ C,
    unsigned short* __restrict__ Cb) {
  constexpr int KB = 32;
  __shared__ float As[64][36];
  const int tid = threadIdx.x;
  const int s0 = blockIdx.x * 64;
  const int o0 = blockIdx.y * 64;
  const int ox = (tid & 15) * 4;
  const int sy = (tid >> 4) * 4;
  float acc[4][4] = {};
  const float* Abase = A + (long)s0 * K;
  for (int idx = tid; idx < 64 * KB; idx += 256) {
    int s = idx >> 5, c = idx & 31;
    As[s][c] = (c < K) ? Abase[(long)s * K + c] : 0.f;
  }
  __syncthreads();
  for (int kk = 0; kk < KB; kk += 4) {
    float a4[4][4];
    #pragma unroll
    for (int sj = 0; sj < 4; ++sj)
      *(float4*)a4[sj] = *(const float4*)&As[sy + sj][kk];
    #pragma unroll
    for (int oi = 0; oi < 4; ++oi) {
      float w4[4];
      #pragma unroll
      for (int kx = 0; kx < 4; ++kx) {
        int k = kk + kx;
        w4[kx] = (k < K) ? W[(long)(o0 + ox + oi) * K + k] : 0.f;
      }
      #pragma unroll
      for (int sj = 0; sj < 4; ++sj)
        #pragma unroll
        for (int kx = 0; kx < 4; ++kx)
          acc[sj][oi] = fmaf(a4[sj][kx], w4[kx], acc[sj][oi]);
    }
  }
  #pragma unroll
  for (int sj = 0; sj < 4; ++sj) {
    float4 o4;
    o4.x = acc[sj][0] + bias[o0 + ox + 0];
    o4.y = acc[sj][1] + bias[o0 + ox + 1];
    o4.z = acc[sj][2] + bias[o0 + ox + 2];
    o4.w = acc[sj][3] + bias[o0 + ox + 3];
    *(float4*)&C[(long)(s0 + sy + sj) * NOUT + o0 + ox] = o4;
    u16x4 b4; b4.x = f2bf(o4.x); b4.y = f2bf(o4.y); b4.z = f2bf(o4.z); b4.w = f2bf(o4.w);
    *(u16x4*)&Cb[(long)(s0 + sy + sj) * NOUT + o0 + ox] = b4;
  }
}

// ---- shared MFMA inner machinery (bf16 A, bf16 W staged in LDS, acc[4][4]) ----
#define MM_PROLOG(GDX)                                                        \
  __shared__ __align__(16) unsigned short As[4096];                           \
  __shared__ __align__(16) unsigned short Ws[4096];                           \
  const int tid = threadIdx.x;                                                \
  const int pid = blockIdx.y * (GDX) + blockIdx.x;                            \
  const int bx = (pid >> 3) % (GDX);                                          \
  const int by = ((pid >> 3) / (GDX)) * 8 + (pid & 7);                        \
  const long s0 = (long)by * 128;                                             \
  const int wv = tid >> 6, l = tid & 63;                                      \
  const int wm = (wv >> 1) * 64, wn = (wv & 1) * 64;                          \
  const int lr = l & 15, lk = l >> 4;                                         \
  const int wrow = tid >> 2;                                                  \
  const int wslot = tid & 3;                                                  \
  f32x4 acc[4][4] = {};

#define MM_MFMA_STEP                                                          \
  {                                                                           \
    bf16x8v af[4], bw[4];                                                     \
    _Pragma("unroll")                                                         \
    for (int m = 0; m < 4; ++m) {                                             \
      const int r = wm + m * 16 + lr;                                         \
      af[m] = *(const bf16x8v*)&As[r * 32 + ((lk ^ (r & 3)) * 8)];            \
    }                                                                         \
    _Pragma("unroll")                                                         \
    for (int n = 0; n < 4; ++n) {                                             \
      const int r = wn + n * 16 + lr;                                         \
      bw[n] = *(const bf16x8v*)&Ws[r * 32 + ((lk ^ (r & 3)) * 8)];            \
    }                                                                         \
    _Pragma("unroll")                                                         \
    for (int m = 0; m < 4; ++m)                                               \
      _Pragma("unroll")                                                       \
      for (int n = 0; n < 4; ++n)                                             \
        acc[m][n] = __builtin_amdgcn_mfma_f32_16x16x32_bf16(af[m], bw[n], acc[m][n], 0, 0, 0); \
  }

// ---------------- generic MFMA dense (f32 A) for heads OB ----------------
template<int K, int LDA, int NOUT, int GDX>
__global__ __launch_bounds__(256) void k_mm(
    const float* __restrict__ Aff, const unsigned short* __restrict__ W,
    const float* __restrict__ bias, float* __restrict__ C) {
  constexpr int NCH = K / 32;
  MM_PROLOG(GDX)
  const int o0 = bx * 128;
  const int q = wslot;
  u16x8 pw[2];
  float4 pa_f[2][2];
  const unsigned short* Wb = W + (long)o0 * K;
  #pragma unroll
  for (int p = 0; p < 2; ++p) {
    const int r = wrow + 64 * p;
    pw[p] = *(const u16x8*)(Wb + (long)r * K + wslot * 8);
    const float* Af = Aff + (s0 + r) * LDA + q * 4;
    pa_f[p][0] = *(const float4*)(Af);
    pa_f[p][1] = *(const float4*)(Af + 16);
  }
  for (int ch = 0; ch < NCH; ++ch) {
    if (ch) __syncthreads();
    #pragma unroll
    for (int p = 0; p < 2; ++p) {
      const int r = wrow + 64 * p;
      const int ps = (wslot ^ (r & 3)) * 8;
      *(u16x8*)&Ws[r * 32 + ps] = pw[p];
      #pragma unroll
      for (int j = 0; j < 2; ++j) {
        float4 v = pa_f[p][j];
        unsigned long long pk =
            (unsigned long long)f2bf(v.x) |
            ((unsigned long long)f2bf(v.y) << 16) |
            ((unsigned long long)f2bf(v.z) << 32) |
            ((unsigned long long)f2bf(v.w) << 48);
        const int slot = (j * 2 + (q >> 1)) ^ (r & 3);
        *(unsigned long long*)&As[r * 32 + slot * 8 + (q & 1) * 4] = pk;
      }
    }
    __syncthreads();
    if (ch + 1 < NCH) {
      const int k0 = (ch + 1) * 32;
      #pragma unroll
      for (int p = 0; p < 2; ++p) {
        const int r = wrow + 64 * p;
        pw[p] = *(const u16x8*)(Wb + (long)r * K + k0 + wslot * 8);
        const float* Af = Aff + (s0 + r) * LDA + k0 + q * 4;
        pa_f[p][0] = *(const float4*)(Af);
        pa_f[p][1] = *(const float4*)(Af + 16);
      }
    }
    MM_MFMA_STEP
  }
  #pragma unroll
  for (int n = 0; n < 4; ++n) {
    const float b = bias[o0 + wn + n * 16 + lr];
    #pragma unroll
    for (int m = 0; m < 4; ++m) {
      const long rowb = s0 + wm + m * 16 + lk * 4;
      #pragma unroll
      for (int r = 0; r < 4; ++r)
        C[(rowb + r) * (long)NOUT + o0 + wn + n * 16 + lr] = acc[m][n][r] + b;
    }
  }
}

// ---------------- merged qsrc GEMM: 1280 outs -> g (256) + gamma/beta (1024) ----------------
__global__ __launch_bounds__(256) void k_mm_qs(
    const unsigned short* __restrict__ Abf, const unsigned short* __restrict__ W,
    const float* __restrict__ bias, float* __restrict__ Cg, float* __restrict__ Cgb) {
  MM_PROLOG(10)
  const int o0 = bx * 128;
  u16x8 pw[2], pa_b[2];
  const unsigned short* Wb = W + (long)o0 * 256;
  #pragma unroll
  for (int p = 0; p < 2; ++p) {
    const int r = wrow + 64 * p;
    pw[p]   = *(const u16x8*)(Wb + (long)r * 256 + wslot * 8);
    pa_b[p] = *(const u16x8*)(Abf + (s0 + r) * 256 + wslot * 8);
  }
  for (int ch = 0; ch < 8; ++ch) {
    if (ch) __syncthreads();
    #pragma unroll
    for (int p = 0; p < 2; ++p) {
      const int r = wrow + 64 * p;
      const int ps = (wslot ^ (r & 3)) * 8;
      *(u16x8*)&Ws[r * 32 + ps] = pw[p];
      *(u16x8*)&As[r * 32 + ps] = pa_b[p];
    }
    __syncthreads();
    if (ch + 1 < 8) {
      const int k0 = (ch + 1) * 32;
      #pragma unroll
      for (int p = 0; p < 2; ++p) {
        const int r = wrow + 64 * p;
        pw[p]   = *(const u16x8*)(Wb + (long)r * 256 + k0 + wslot * 8);
        pa_b[p] = *(const u16x8*)(Abf + (s0 + r) * 256 + k0 + wslot * 8);
      }
    }
    MM_MFMA_STEP
  }
  float* C; int NOUT, ob;
  if (bx < 2) { C = Cg;  NOUT = 256;  ob = bx * 128; }
  else        { C = Cgb; NOUT = 1024; ob = (bx - 2) * 128; }
  #pragma unroll
  for (int n = 0; n < 4; ++n) {
    const float b = bias[o0 + wn + n * 16 + lr];
    #pragma unroll
    for (int m = 0; m < 4; ++m) {
      const long rowb = s0 + wm + m * 16 + lk * 4;
      #pragma unroll
      for (int r = 0; r < 4; ++r)
        C[(rowb + r) * (long)NOUT + ob + wn + n * 16 + lr] = acc[m][n][r] + b;
    }
  }
}

// ---------------- merged pal@PV GEMM (both branches, K=128) ----------------
__global__ __launch_bounds__(256) void k_mm_pv(
    const unsigned short* __restrict__ pal, const unsigned short* __restrict__ W,
    const float* __restrict__ bias, float* __restrict__ CA, float* __restrict__ CE) {
  MM_PROLOG(4)
  const int o0 = bx * 128;
  const int br = bx >> 1;
  const unsigned short* Abf = pal + br * 128;
  u16x8 pw[2], pa_b[2];
  const unsigned short* Wb = W + (long)o0 * 128;
  #pragma unroll
  for (int p = 0; p < 2; ++p) {
    const int r = wrow + 64 * p;
    pw[p]   = *(const u16x8*)(Wb + (long)r * 128 + wslot * 8);
    pa_b[p] = *(const u16x8*)(Abf + (s0 + r) * 256 + wslot * 8);
  }
  for (int ch = 0; ch < 4; ++ch) {
    if (ch) __syncthreads();
    #pragma unroll
    for (int p = 0; p < 2; ++p) {
      const int r = wrow + 64 * p;
      const int ps = (wslot ^ (r & 3)) * 8;
      *(u16x8*)&Ws[r * 32 + ps] = pw[p];
      *(u16x8*)&As[r * 32 + ps] = pa_b[p];
    }
    __syncthreads();
    if (ch + 1 < 4) {
      const int k0 = (ch + 1) * 32;
      #pragma unroll
      for (int p = 0; p < 2; ++p) {
        const int r = wrow + 64 * p;
        pw[p]   = *(const u16x8*)(Wb + (long)r * 128 + k0 + wslot * 8);
        pa_b[p] = *(const u16x8*)(Abf + (s0 + r) * 256 + k0 + wslot * 8);
      }
    }
    MM_MFMA_STEP
  }
  float* C = br ? CE : CA;
  const int ob = (bx & 1) * 128;
  #pragma unroll
  for (int n = 0; n < 4; ++n) {
    const float b = bias[o0 + wn + n * 16 + lr];
    #pragma unroll
    for (int m = 0; m < 4; ++m) {
      const long rowb = s0 + wm + m * 16 + lk * 4;
      #pragma unroll
      for (int r = 0; r < 4; ++r)
        C[(rowb + r) * 256 + ob + wn + n * 16 + lr] = acc[m][n][r] + b;
    }
  }
}

// ---------------- GRU mega-GEMM v2: 128x128 tiles, gate=fragment, epilogue -> h ----------------
__global__ __launch_bounds__(256) void k_gru2(
    const unsigned short* __restrict__ UB, const float* __restrict__ hid,
    const unsigned short* __restrict__ WG, const float* __restrict__ BG,
    float* __restrict__ hout) {
  MM_PROLOG(8)
  const int o0 = bx * 128;
  const int q = wslot;
  u16x8 pw[2], pa_b[2];
  float4 pa_f[2][2];
  bool pf32 = false;
  const unsigned short* Wb = WG + (long)o0 * 1024;
  #pragma unroll
  for (int p = 0; p < 2; ++p) {
    const int r = wrow + 64 * p;
    pw[p]   = *(const u16x8*)(Wb + (long)r * 1024 + wslot * 8);
    pa_b[p] = *(const u16x8*)(UB + (s0 + r) * 768 + wslot * 8);
  }
  for (int ch = 0; ch < 32; ++ch) {
    if (ch) __syncthreads();
    #pragma unroll
    for (int p = 0; p < 2; ++p) {
      const int r = wrow + 64 * p;
      const int ps = (wslot ^ (r & 3)) * 8;
      *(u16x8*)&Ws[r * 32 + ps] = pw[p];
      if (!pf32) {
        *(u16x8*)&As[r * 32 + ps] = pa_b[p];
      } else {
        #pragma unroll
        for (int j = 0; j < 2; ++j) {
          float4 v = pa_f[p][j];
          unsigned long long pk =
              (unsigned long long)f2bf(v.x) |
              ((unsigned long long)f2bf(v.y) << 16) |
              ((unsigned long long)f2bf(v.z) << 32) |
              ((unsigned long long)f2bf(v.w) << 48);
          const int slot = (j * 2 + (q >> 1)) ^ (r & 3);
          *(unsigned long long*)&As[r * 32 + slot * 8 + (q & 1) * 4] = pk;
        }
      }
    }
    __syncthreads();
    if (ch + 1 < 32) {
      const int k0 = (ch + 1) * 32;
      pf32 = (k0 >= 768);
      #pragma unroll
      for (int p = 0; p < 2; ++p) {
        const int r = wrow + 64 * p;
        pw[p] = *(const u16x8*)(Wb + (long)r * 1024 + k0 + wslot * 8);
        if (!pf32) {
          pa_b[p] = *(const u16x8*)(UB + (s0 + r) * 768 + k0 + wslot * 8);
        } else {
          const float* Af = hid + (s0 + r) * 256 + (k0 - 768) + q * 4;
          pa_f[p][0] = *(const float4*)(Af);
          pa_f[p][1] = *(const float4*)(Af + 16);
        }
      }
    }
    MM_MFMA_STEP
  }
  // epilogue: fragment n == gate; d fixed per thread
  const int colb = bx * 128 + wn;
  const int d = (bx >> 1) * 64 + (((bx & 1) << 1) | (wv & 1)) * 16 + lr;
  const float bR  = BG[colb + lr];
  const float bZ  = BG[colb + 16 + lr];
  const float bNi = BG[colb + 32 + lr];
  const float bNh = BG[colb + 48 + lr];
  #pragma unroll
  for (int m = 0; m < 4; ++m) {
    const long srow = s0 + wm + m * 16 + lk * 4;
    #pragma unroll
    for (int rr = 0; rr < 4; ++rr) {
      const long s = srow + rr;
      const float r_ = 1.f / (1.f + expf(-(acc[m][0][rr] + bR)));
      const float z_ = 1.f / (1.f + expf(-(acc[m][1][rr] + bZ)));
      const float n_ = tanhf(acc[m][2][rr] + bNi + r_ * (acc[m][3][rr] + bNh));
      const float hp = hid[s * 256 + d];
      hout[s * 256 + d] = (1.f - z_) * n_ + z_ * hp;
    }
  }
}

// ---------------- merged attention core ----------------
__global__ __launch_bounds__(256) void k_core2(
    const float* __restrict__ rawA, const float* __restrict__ rawE,
    const float* __restrict__ g, const float* __restrict__ gt_w,
    const float* __restrict__ gt_b, unsigned short* __restrict__ pal) {
  __shared__ float A_[4][15][36];
  __shared__ float E_[4][16][36];
  __shared__ float G_[4][8][32];
  __shared__ float P_[4][8][16];
  const int tid = threadIdx.x;
  const int w = tid >> 6, l = tid & 63;
  const long s = (long)blockIdx.x * 4 + w;

  const float* ra = rawA + s * 480;
  const float* re = rawE + s * 512;
  const float* gr = g + s * 256;
  #pragma unroll
  for (int i = l; i < 120; i += 64) {
    float4 v = *(const float4*)(ra + i * 4);
    *(float4*)&A_[w][i >> 3][(i & 7) * 4] = v;
  }
  #pragma unroll
  for (int i = l; i < 128; i += 64) {
    float4 v = *(const float4*)(re + i * 4);
    *(float4*)&E_[w][i >> 3][(i & 7) * 4] = v;
  }
  {
    float4 v = *(const float4*)(gr + l * 4);
    *(float4*)&G_[w][l >> 3][(l & 7) * 4] = v;
  }
  __syncthreads();

  bool mv = false;
  if (l < 15) {
    #pragma unroll
    for (int c = 0; c < 8; ++c) {
      float4 x = *(const float4*)&A_[w][l][c * 4];
      mv |= (x.x != 0.f) | (x.y != 0.f) | (x.z != 0.f) | (x.w != 0.f);
    }
  } else if (l >= 16 && l < 32) {
    #pragma unroll
    for (int c = 0; c < 8; ++c) {
      float4 x = *(const float4*)&E_[w][l - 16][c * 4];
      mv |= (x.x != 0.f) | (x.y != 0.f) | (x.z != 0.f) | (x.w != 0.f);
    }
  }
  unsigned long long bal = __ballot(mv);
  unsigned mA = (unsigned)bal & 0x7FFFu;
  unsigned mE = (unsigned)(bal >> 16) & 0xFFFFu;
  float xa = gt_w[0] * log1pf((float)__popc(mA)) + gt_b[0];
  float spa = fmaxf(xa, 0.f) + log1pf(expf(-fabsf(xa)));
  float scaleA = 1.f / (8.f * (spa + 1.f));
  float xe = gt_w[1] * log1pf((float)__popc(mE)) + gt_b[1];
  float spe = fmaxf(xe, 0.f) + log1pf(expf(-fabsf(xe)));
  float scaleE = 1.f / (8.f * (spe + 1.f));

  {
    const int h = l >> 4, n = l & 15;
    const bool okA = (n < 15) && ((mA >> n) & 1);
    const bool okE = (mE >> n) & 1;
    const float* arow = &A_[w][n < 15 ? n : 0][0];
    const float* erow = &E_[w][n][0];
    const float* garow = &G_[w][h][0];
    const float* gerow = &G_[w][4 + h][0];
    float accA = 0.f, accE = 0.f;
    #pragma unroll
    for (int j = 0; j < 32; ++j) {
      accA = fmaf(garow[j], arow[j], accA);
      accE = fmaf(gerow[j], erow[j], accE);
    }
    float sA = okA ? accA * scaleA : -INFINITY;
    float sE = okE ? accE * scaleE : -INFINITY;
    float mAx = sA, mEx = sE;
    #pragma unroll
    for (int off = 8; off; off >>= 1) {
      mAx = fmaxf(mAx, __shfl_xor(mAx, off));
      mEx = fmaxf(mEx, __shfl_xor(mEx, off));
    }
    float eA = okA ? expf(sA - mAx) : 0.f;
    float eE = okE ? expf(sE - mEx) : 0.f;
    float suA = eA, suE = eE;
    #pragma unroll
    for (int off = 8; off; off >>= 1) {
      suA += __shfl_xor(suA, off);
      suE += __shfl_xor(suE, off);
    }
    P_[w][h][n] = eA / suA;
    P_[w][4 + h][n] = eE / suE;
  }
  __syncthreads();

  {
    const int j = l & 31, hh = l >> 5;
    unsigned short* po = pal + s * 256 + hh * 32 + j;
    #pragma unroll
    for (int r = 0; r < 2; ++r) {
      const int ha = r * 2 + hh;
      float a0 = 0.f, a1 = 0.f;
      #pragma unroll
      for (int n = 0; n < 15; ++n)
        a0 = fmaf(P_[w][ha][n], A_[w][n][j], a0);
      #pragma unroll
      for (int n = 0; n < 16; ++n)
        a1 = fmaf(P_[w][4 + ha][n], E_[w][n][j], a1);
      po[r * 64] = f2bf(a0);
      po[128 + r * 64] = f2bf(a1);
    }
  }
}

// ---------------- fused CLN+CLN+LN3 -> u (bf16 out) ----------------
__global__ __launch_bounds__(256) void k_clnln(
    const float* __restrict__ aA, const float* __restrict__ aE,
    const float* __restrict__ qsrc, const float* __restrict__ gbu,
    const float* __restrict__ g, const float* __restrict__ b,
    unsigned short* __restrict__ UB) {
  int w = threadIdx.x >> 6, l = threadIdx.x & 63;
  long s = (long)blockIdx.x * 4 + w;
  int d = l * 4;
  float4 vA = *(const float4*)(aA + s * 256 + d);
  float4 vE = *(const float4*)(aE + s * 256 + d);
  float4 vq = *(const float4*)(qsrc + s * 256 + d);
  const float* gbr = gbu + s * 1024;
  float sumA = vA.x + vA.y + vA.z + vA.w;
  float ssqA = vA.x*vA.x + vA.y*vA.y + vA.z*vA.z + vA.w*vA.w;
  float sumE = vE.x + vE.y + vE.z + vE.w;
  float ssqE = vE.x*vE.x + vE.y*vE.y + vE.z*vE.z + vE.w*vE.w;
  #pragma unroll
  for (int off = 32; off > 0; off >>= 1) {
    sumA += __shfl_xor(sumA, off); ssqA += __shfl_xor(ssqA, off);
    sumE += __shfl_xor(sumE, off); ssqE += __shfl_xor(ssqE, off);
  }
  float muA = sumA * (1.f / 256.f);
  float rstdA = rsqrtf(ssqA * (1.f / 256.f) - muA * muA + 1e-5f);
  float muE = sumE * (1.f / 256.f);
  float rstdE = rsqrtf(ssqE * (1.f / 256.f) - muE * muE + 1e-5f);

  float4 gA4 = *(const float4*)(gbr + d);
  float4 bA4 = *(const float4*)(gbr + 256 + d);
  float4 gE4 = *(const float4*)(gbr + 512 + d);
  float4 bE4 = *(const float4*)(gbr + 768 + d);
  float4 zA, zE;
  zA.x = (1.f + gA4.x) * ((vA.x - muA) * rstdA) + bA4.x;
  zA.y = (1.f + gA4.y) * ((vA.y - muA) * rstdA) + bA4.y;
  zA.z = (1.f + gA4.z) * ((vA.z - muA) * rstdA) + bA4.z;
  zA.w = (1.f + gA4.w) * ((vA.w - muA) * rstdA) + bA4.w;
  zE.x = (1.f + gE4.x) * ((vE.x - muE) * rstdE) + bE4.x;
  zE.y = (1.f + gE4.y) * ((vE.y - muE) * rstdE) + bE4.y;
  zE.z = (1.f + gE4.z) * ((vE.z - muE) * rstdE) + bE4.z;
  zE.w = (1.f + gE4.w) * ((vE.w - muE) * rstdE) + bE4.w;

  float sum = vq.x+vq.y+vq.z+vq.w + zA.x+zA.y+zA.z+zA.w + zE.x+zE.y+zE.z+zE.w;
  float ssq = vq.x*vq.x+vq.y*vq.y+vq.z*vq.z+vq.w*vq.w
            + zA.x*zA.x+zA.y*zA.y+zA.z*zA.z+zA.w*zA.w
            + zE.x*zE.x+zE.y*zE.y+zE.z*zE.z+zE.w*zE.w;
  #pragma unroll
  for (int off = 32; off > 0; off >>= 1) {
    sum += __shfl_xor(sum, off); ssq += __shfl_xor(ssq, off);
  }
  float mu = sum * (1.f / 768.f);
  float rstd = rsqrtf(ssq * (1.f / 768.f) - mu * mu + 1e-5f);

  float4 g0 = *(const float4*)(g + d),       b0 = *(const float4*)(b + d);
  float4 g1 = *(const float4*)(g + 256 + d), b1 = *(const float4*)(b + 256 + d);
  float4 g2 = *(const float4*)(g + 512 + d), b2 = *(const float4*)(b + 512 + d);
  unsigned short* ur = UB + s * 768;
  u16x4 o;
  o.x = f2bf((vq.x - mu) * rstd * g0.x + b0.x);
  o.y = f2bf((vq.y - mu) * rstd * g0.y + b0.y);
  o.z = f2bf((vq.z - mu) * rstd * g0.z + b0.z);
  o.w = f2bf((vq.w - mu) * rstd * g0.w + b0.w);
  *(u16x4*)&ur[d] = o;
  o.x = f2bf((zA.x - mu) * rstd * g1.x + b1.x);
  o.y = f2bf((zA.y - mu) * rstd * g1.y + b1.y);
  o.z = f2bf((zA.z - mu) * rstd * g1.z + b1.z);
  o.w = f2bf((zA.w - mu) * rstd * g1.w + b1.w);
  *(u16x4*)&ur[256 + d] = o;
  o.x = f2bf((zE.x - mu) * rstd * g2.x + b2.x);
  o.y = f2bf((zE.y - mu) * rstd * g2.y + b2.y);
  o.z = f2bf((zE.z - mu) * rstd * g2.z + b2.z);
  o.w = f2bf((zE.w - mu) * rstd * g2.w + b2.w);
  *(u16x4*)&ur[512 + d] = o;
}

// ---------------- heads epilogue ----------------
__global__ __launch_bounds__(256) void k_heads2(
    const float* __restrict__ OB, const float* __restrict__ eraw,
    const float* __restrict__ log_tau, float* __restrict__ Qout) {
  __shared__ float obs[16][48];
  const int tid = threadIdx.x;
  const long s0 = (long)blockIdx.x * 16;
  for (int idx = tid; idx < 768; idx += 256)
    obs[idx / 48][idx % 48] = OB[(s0 + idx / 48) * 128 + idx % 48];
  __syncthreads();
  const int w = tid >> 4, i = tid & 15;
  const long s = s0 + w;
  const float itm = 1.f / (expf(log_tau[0]) + 1e-6f);
  const float its = 1.f / (expf(log_tau[1]) + 1e-6f);
  const float V = obs[w][0];
  const float* er = eraw + s * 512 + i * 32;
  bool valid = false; float acc = 0.f;
  #pragma unroll
  for (int jb = 0; jb < 8; ++jb) {
    float4 e4 = *(const float4*)(er + jb * 4);
    valid |= (e4.x != 0.f) | (e4.y != 0.f) | (e4.z != 0.f) | (e4.w != 0.f);
    acc += obs[w][9 + jb * 4 + 0] * e4.x + obs[w][9 + jb * 4 + 1] * e4.y +
           obs[w][9 + jb * 4 + 2] * e4.z + obs[w][9 + jb * 4 + 3] * e4.w;
  }
  float a = (acc + obs[w][41]) * 0.0625f;
  float sa = valid ? a : 0.f;
  float cv = valid ? 1.f : 0.f;
  #pragma unroll
  for (int off = 8; off > 0; off >>= 1) {
    sa += __shfl_xor(sa, off);
    cv += __shfl_xor(cv, off);
  }
  float me = sa / fmaxf(cv, 1.f);
  Qout[s * 22 + 6 + i] = V + obs[w][2] + (valid ? (a - me) * its : -1e30f * its);
  if (i < 6) {
    float mean = 0.f;
    #pragma unroll
    for (int t = 0; t < 6; ++t) mean += obs[w][3 + t];
    mean *= (1.f / 6.f);
    Qout[s * 22 + i] = V + obs[w][1] + (obs[w][3 + i] - mean) * 0.0625f * itm;
  }
}

// ---------------- launch ----------------
extern "C" void kernel_launch(void* const* d_in, const int* in_sizes, int n_in,
                              void* d_out, int out_size, void* d_ws, size_t ws_size,
                              hipStream_t stream) {
  const float* own_raw   = (const float*)d_in[0];
  const float* ally_raw  = (const float*)d_in[1];
  const float* enemy_raw = (const float*)d_in[2];
  const float* hidden    = (const float*)d_in[3];
  const float* W_own     = (const float*)d_in[4];
  const float* b_own     = (const float*)d_in[5];
  const float* W_ally    = (const float*)d_in[6];
  const float* b_ally    = (const float*)d_in[7];
  const float* W_enemy   = (const float*)d_in[8];
  const float* b_enemy   = (const float*)d_in[9];
  const float* gt_w      = (const float*)d_in[10];
  const float* gt_b      = (const float*)d_in[11];
  const float* attnA_W   = (const float*)d_in[12];
  const float* attnA_b   = (const float*)d_in[13];
  const float* attnE_W   = (const float*)d_in[14];
  const float* attnE_b   = (const float*)d_in[15];
  const float* clnA_W    = (const float*)d_in[16];
  const float* clnA_b    = (const float*)d_in[17];
  const float* clnE_W    = (const float*)d_in[18];
  const float* clnE_b    = (const float*)d_in[19];
  const float* ln3_g     = (const float*)d_in[20];
  const float* ln3_b     = (const float*)d_in[21];
  const float* gru_Wih   = (const float*)d_in[22];
  const float* gru_Whh   = (const float*)d_in[23];
  const float* gru_bih   = (const float*)d_in[24];
  const float* gru_bhh   = (const float*)d_in[25];
  const float* Wv_head   = (const float*)d_in[26];
  const float* bv_head   = (const float*)d_in[27];
  const float* Wtb       = (const float*)d_in[28];
  const float* btb       = (const float*)d_in[29];
  const float* log_tau   = (const float*)d_in[30];
  const float* Wmq       = (const float*)d_in[31];
  const float* bmq       = (const float*)d_in[32];
  const float* protos    = (const float*)d_in[33];
  const float* Wqs       = (const float*)d_in[34];
  const float* bqs       = (const float*)d_in[35];
  const float* Wke       = (const float*)d_in[36];
  const float* bke       = (const float*)d_in[37];

  float* ws  = (float*)d_ws;
  float* out = (float*)d_out;
  float* hout = out + HOFF;
  unsigned short* WB   = (unsigned short*)hout;            // bf16 weight cache
  unsigned short* qsb  = (unsigned short*)(ws + BUF2_OFF); // q_src bf16
  unsigned short* palb = (unsigned short*)(ws + BUF2_OFF); // pal bf16 (after qsb dead)
  unsigned short* WHD  = (unsigned short*)ws;              // heads weights
  unsigned short* wgru = (unsigned short*)(ws + BUF1_OFF); // WGRU (after core2)
  unsigned short* ub   = (unsigned short*)(ws + UB_OFF);   // u bf16

  k_fuseA<<<416, 256, 0, stream>>>(attnA_W, attnA_b, attnE_W, attnE_b,
                                   W_ally, b_ally, W_enemy, b_enemy, Wke, bke,
                                   clnA_W, clnE_W, ws, WB);
  k_fuseB<<<559, 256, 0, stream>>>(protos, Wmq, bmq, Wqs, bqs,
                                   attnA_W, attnA_b, attnE_W, attnE_b,
                                   clnA_b, clnE_b, ws, WB);
  k_fuse4<<<129, 256, 0, stream>>>(Wv_head, bv_head, Wtb, btb, ws, WHD);

  // q_src (f32 + bf16)
  k_densek<30, 256><<<dim3(BN/64, 4), 256, 0, stream>>>(own_raw, W_own, b_own,
                                                        ws + QSRC_OFF, qsb);

  // merged: g (256) + cln gamma/beta (1024) in one 1280-out GEMM
  k_mm_qs<<<dim3(10, 128), 256, 0, stream>>>(qsb, WB, ws + BMG_OFF,
                                             ws + GBUF_OFF, ws + GB_OFF);

  // merged attention core -> pal (bf16)
  k_core2<<<BN/4, 256, 0, stream>>>(ally_raw, enemy_raw, ws + GBUF_OFF,
                                    gt_w, gt_b, palb);

  // GRU folded weights (into BUF1, now dead) + bias
  k_gruw<<<1028, 256, 0, stream>>>(gru_Wih, gru_Whh, gru_bih, gru_bhh,
                                   wgru, ws + BGRU_OFF);

  // aout = pal @ PV + bpj (both branches, one launch)
  k_mm_pv<<<dim3(4, 128), 256, 0, stream>>>(palb, WB + PJA_S, ws + BPJA_OFF,
                                            ws + AOUTA_OFF, ws + AOUTE_OFF);

  // fused cln+cln+ln3 -> u bf16
  k_clnln<<<BN/4, 256, 0, stream>>>(ws + AOUTA_OFF, ws + AOUTE_OFF, ws + QSRC_OFF,
                                    ws + GB_OFF, ln3_g, ln3_b, ub);

  // GRU mega-GEMM v2 -> h
  k_gru2<<<dim3(8, 128), 256, 0, stream>>>(ub, hidden, wgru, ws + BGRU_OFF, hout);

  // heads: OB = h @ WHD.T, then epilogue
  k_mm<256, 256, 128, 1><<<dim3(1, 128), 256, 0, stream>>>(hout, WHD, ws + BHD_OFF, ws + OB_OFF);
  k_heads2<<<BN/16, 256, 0, stream>>>(ws + OB_OFF, enemy_raw, log_tau, out);
}

// Round 8
// 219.431 us; speedup vs baseline: 12.9814x; 1.0007x over previous
//
#include <hip/hip_runtime.h>
#include <math.h>

#define BN 16384

typedef float f32x4 __attribute__((ext_vector_type(4)));
typedef short bf16x8v __attribute__((ext_vector_type(8)));
typedef unsigned short u16x8 __attribute__((ext_vector_type(8)));
typedef unsigned short u16x4 __attribute__((ext_vector_type(4)));

static __device__ inline unsigned short f2bf(float f) {
  unsigned u = __float_as_uint(f);
  return (unsigned short)((u + 0x8000u) >> 16);
}

// async global->LDS, 16B per lane, dest = wave-uniform base + lane*16
#define GLDS(gp, lp) __builtin_amdgcn_global_load_lds( \
    (const __attribute__((address_space(1))) unsigned int*)(gp), \
    (__attribute__((address_space(3))) unsigned int*)(lp), 16, 0, 0)

// ---------------- workspace float offsets ----------------
#define WKA_OFF   0
#define WVA_OFF   8192
#define WKE_OFF   16384
#define WVE_OFF   24576
#define WKEF_OFF  32768
#define BKA_OFF   40960
#define BVA_OFF   41216
#define BKE_OFF   41472
#define BVE_OFF   41728
#define BKEF_OFF  41984
#define WMP_OFF   43008
#define BMP_OFF   44544
#define G_OFF     45056
#define BG_OFF    53248
#define WQB_OFF   53312
#define SC0_OFF   53568
#define BMG_OFF   53632   /* 256: folded g bias */
#define CLB_OFF   53888   /* 1024: clnA_b ++ clnE_b */
#define BPJA_OFF  57088   /* 256 */
#define BPJE_OFF  57344   /* 256 (contiguous) */
#define BGRU_OFF  57600   /* 1024 folded GRU bias */
#define BHD_OFF   16384   /* 128 heads bias (over dead WKE) */

#define QSRC_OFF  65536
#define BUF1_OFF  (QSRC_OFF + BN*256)
#define BUF2_OFF  (BUF1_OFF + BN*256)
#define BUF3_OFF  (BUF2_OFF + BN*256)
#define BUF4_OFF  (BUF3_OFF + BN*256)
#define BUF5_OFF  (BUF4_OFF + BN*256)

#define GBUF_OFF  BUF1_OFF
#define AOUTA_OFF BUF3_OFF
#define AOUTE_OFF BUF4_OFF
#define GB_OFF    BUF5_OFF
#define OB_OFF    BUF1_OFF
#define UB_OFF    (BUF1_OFF + 524288)

#define HOFF      (BN*22)

// bf16 weight cache in d_out's h-region
#define MGB_S 0
#define CLA_S 65536
#define CLE_S 196608
#define PJA_S 327680
#define PJE_S 360448

// ---------------- fuseA: fuse1 + cln weight cvt ----------------
__global__ __launch_bounds__(256) void k_fuseA(
    const float* __restrict__ attnA_W, const float* __restrict__ attnA_b,
    const float* __restrict__ attnE_W, const float* __restrict__ attnE_b,
    const float* __restrict__ W_ally,  const float* __restrict__ b_ally,
    const float* __restrict__ W_enemy, const float* __restrict__ b_enemy,
    const float* __restrict__ Wke,     const float* __restrict__ bke,
    const float* __restrict__ clnA_W,  const float* __restrict__ clnE_W,
    float* __restrict__ FW, unsigned short* __restrict__ WBc) {
  int g = blockIdx.x * 256 + threadIdx.x;
  if (g < 40960) {
    int m = g >> 13;
    int r = g & 8191;
    int d = r >> 5, j = r & 31;
    const float *Wout, *Win, *bin, *bout; float *dst, *dstb;
    switch (m) {
      case 0: Wout = attnA_W + 65536;  Win = W_ally;  bin = b_ally;  bout = attnA_b + 256; dst = FW + WKA_OFF;  dstb = FW + BKA_OFF;  break;
      case 1: Wout = attnA_W + 131072; Win = W_ally;  bin = b_ally;  bout = attnA_b + 512; dst = FW + WVA_OFF;  dstb = FW + BVA_OFF;  break;
      case 2: Wout = attnE_W + 65536;  Win = W_enemy; bin = b_enemy; bout = attnE_b + 256; dst = FW + WKE_OFF;  dstb = FW + BKE_OFF;  break;
      case 3: Wout = attnE_W + 131072; Win = W_enemy; bin = b_enemy; bout = attnE_b + 512; dst = FW + WVE_OFF;  dstb = FW + BVE_OFF;  break;
      default:Wout = Wke;              Win = W_enemy; bin = b_enemy; bout = bke;           dst = FW + WKEF_OFF; dstb = FW + BKEF_OFF; break;
    }
    float acc = 0.f;
    for (int c = 0; c < 256; ++c) acc += Wout[d*256 + c] * Win[c*32 + j];
    dst[d*32 + j] = acc;
    if (j == 0) {
      float b = bout[d];
      for (int c = 0; c < 256; ++c) b += Wout[d*256 + c] * bin[c];
      dstb[d] = b;
    }
  } else {
    int t = g - 40960;
    if (t < 65536) {
      int e = t * 4;
      const float* src = (e < 131072) ? clnA_W : clnE_W;
      int off = (e < 131072) ? 0 : 131072;
      float4 v = *(const float4*)(src + (e - off));
      u16x4 b; b.x = f2bf(v.x); b.y = f2bf(v.y); b.z = f2bf(v.z); b.w = f2bf(v.w);
      *(u16x4*)&WBc[CLA_S + e] = b;
    }
  }
}

// ---------------- fuseB: fuse2 + fuse3 + fuse5 ----------------
__global__ __launch_bounds__(256) void k_fuseB(
    const float* __restrict__ protos, const float* __restrict__ Wmq,
    const float* __restrict__ bmq,    const float* __restrict__ Wqs,
    const float* __restrict__ bqs,
    const float* __restrict__ attnA_W, const float* __restrict__ attnA_b,
    const float* __restrict__ attnE_W, const float* __restrict__ attnE_b,
    const float* __restrict__ clnA_b,  const float* __restrict__ clnE_b,
    float* __restrict__ FW, unsigned short* __restrict__ WBc) {
  int g = blockIdx.x * 256 + threadIdx.x;
  const float* WKe_f = FW + WKEF_OFF;
  const float* bKe_f = FW + BKEF_OFF;
  if (g < 10240) {
    if (g < 1536) {
      int i = g >> 8, c = g & 255;
      float acc = 0.f;
      for (int d = 0; d < 256; ++d) acc += protos[i*256 + d] * Wmq[d*256 + c];
      FW[WMP_OFF + i*256 + c] = acc;
    } else if (g < 9728) {
      int r = g - 1536;
      int j = r >> 8, c = r & 255;
      float acc = 0.f;
      for (int d = 0; d < 256; ++d) acc += WKe_f[d*32 + j] * Wqs[d*256 + c];
      FW[G_OFF + j*256 + c] = acc;
    } else if (g < 9984) {
      int c = g - 9728;
      float acc = 0.f;
      for (int d = 0; d < 256; ++d) acc += Wqs[d*256 + c] * bKe_f[d];
      FW[WQB_OFF + c] = acc;
    } else if (g < 9990) {
      int i = g - 9984;
      float acc = 0.f;
      for (int d = 0; d < 256; ++d) acc += protos[i*256 + d] * bmq[d];
      FW[BMP_OFF + i] = acc;
    } else if (g < 10022) {
      int j = g - 9990;
      float acc = 0.f;
      for (int d = 0; d < 256; ++d) acc += WKe_f[d*32 + j] * bqs[d];
      FW[BG_OFF + j] = acc;
    } else if (g == 10022) {
      float acc = 0.f;
      for (int d = 0; d < 256; ++d) acc += bqs[d] * bKe_f[d];
      FW[SC0_OFF] = acc;
    }
  } else if (g < 77056) {
    int t = g - 10240;
    if (t < 65536) {
      int r = t >> 8, c = t & 255;
      int br = r >> 7, jj = r & 127, h = jj >> 5, jc = jj & 31;
      const float* W0 = br ? attnE_W : attnA_W;
      const float* Wk = FW + (br ? WKE_OFF : WKA_OFF);
      float acc = 0.f;
      for (int d = 0; d < 64; ++d)
        acc += W0[(h*64+d)*256 + c] * Wk[(h*64+d)*32 + jc];
      WBc[MGB_S + r*256 + c] = f2bf(acc);
    } else if (t < 65792) {
      int r = t - 65536;
      int br = r >> 7, jj = r & 127, h = jj >> 5, jc = jj & 31;
      const float* b0 = br ? attnE_b : attnA_b;
      const float* Wk = FW + (br ? WKE_OFF : WKA_OFF);
      float acc = 0.f;
      for (int d = 0; d < 64; ++d) acc += b0[h*64+d] * Wk[(h*64+d)*32 + jc];
      FW[BMG_OFF + r] = acc;
    } else {
      int c = t - 65792;
      FW[CLB_OFF + c] = (c < 512) ? clnA_b[c] : clnE_b[c - 512];
    }
  } else {
    int t = g - 77056;
    if (t < 65536) {
      int br = t >> 15;
      int r0 = t & 32767;
      int o = r0 >> 7, r = r0 & 127, h = r >> 5, j = r & 31;
      const float* Wp = (br ? attnE_W : attnA_W) + 196608;
      const float* Wv = FW + (br ? WVE_OFF : WVA_OFF);
      float acc = 0.f;
      for (int d = 0; d < 64; ++d)
        acc += Wp[o*256 + h*64 + d] * Wv[(h*64+d)*32 + j];
      WBc[(br ? PJE_S : PJA_S) + o*128 + r] = f2bf(acc);
    } else if (t < 66048) {
      int r0 = t - 65536;
      int br = r0 >> 8, c = r0 & 255;
      const float* Wp = (br ? attnE_W : attnA_W) + 196608;
      const float* bv = FW + (br ? BVE_OFF : BVA_OFF);
      const float* pb = (br ? attnE_b : attnA_b) + 768;
      float acc = pb[c];
      for (int d = 0; d < 256; ++d) acc += Wp[c*256 + d] * bv[d];
      FW[(br ? BPJE_OFF : BPJA_OFF) + c] = acc;
    }
  }
}

// ---------------- heads fold ----------------
__global__ __launch_bounds__(256) void k_fuse4(
    const float* __restrict__ Wv_head, const float* __restrict__ bv_head,
    const float* __restrict__ Wtb, const float* __restrict__ btb,
    float* __restrict__ FW, unsigned short* __restrict__ WHD) {
  int g = blockIdx.x * 256 + threadIdx.x;
  if (g < 32768) {
    int r = g >> 8, c = g & 255;
    float v;
    if (r == 0)       v = Wv_head[c];
    else if (r == 1)  v = Wtb[c];
    else if (r == 2)  v = Wtb[256 + c];
    else if (r < 9)   v = FW[WMP_OFF + (r - 3) * 256 + c];
    else if (r < 41)  v = FW[G_OFF + (r - 9) * 256 + c];
    else if (r == 41) v = FW[WQB_OFF + c];
    else              v = 0.f;
    WHD[r * 256 + c] = f2bf(v);
  } else if (g < 32896) {
    int r = g - 32768;
    float v;
    if (r == 0)       v = bv_head[0];
    else if (r == 1)  v = btb[0];
    else if (r == 2)  v = btb[1];
    else if (r < 9)   v = FW[BMP_OFF + r - 3];
    else if (r < 41)  v = FW[BG_OFF + r - 9];
    else if (r == 41) v = FW[SC0_OFF];
    else              v = 0.f;
    FW[BHD_OFF + r] = v;
  }
}

// ---------------- GRU fused weight fold ----------------
__global__ __launch_bounds__(256) void k_gruw(
    const float* __restrict__ Wih, const float* __restrict__ Whh,
    const float* __restrict__ bih, const float* __restrict__ bhh,
    unsigned short* __restrict__ WG, float* __restrict__ BG) {
  int t = blockIdx.x * 256 + threadIdx.x;
  if (t < 262144) {
    int e4 = t * 4;
    int p = e4 >> 10, c = e4 & 1023;
    int X = p >> 8, df = (p >> 6) & 3, g = (p >> 4) & 3, i = p & 15;
    int d = X * 64 + df * 16 + i;
    float4 v;
    if (c < 768) {
      if (g == 3) v = make_float4(0.f, 0.f, 0.f, 0.f);
      else        v = *(const float4*)(Wih + (long)(g * 256 + d) * 768 + c);
    } else {
      int ch = c - 768;
      if (g == 2) v = make_float4(0.f, 0.f, 0.f, 0.f);
      else {
        int row = (g == 3 ? 512 : g * 256) + d;
        v = *(const float4*)(Whh + (long)row * 256 + ch);
      }
    }
    u16x4 b; b.x = f2bf(v.x); b.y = f2bf(v.y); b.z = f2bf(v.z); b.w = f2bf(v.w);
    *(u16x4*)&WG[e4] = b;
  } else if (t < 263168) {
    int p = t - 262144;
    int X = p >> 8, df = (p >> 6) & 3, g = (p >> 4) & 3, i = p & 15;
    int d = X * 64 + df * 16 + i;
    float v;
    if (g == 0)      v = bih[d] + bhh[d];
    else if (g == 1) v = bih[256 + d] + bhh[256 + d];
    else if (g == 2) v = bih[512 + d];
    else             v = bhh[512 + d];
    BG[p] = v;
  }
}

// ---------------- small-K dense (K=30) ----------------
template<int K, int NOUT>
__global__ __launch_bounds__(256) void k_densek(
    const float* __restrict__ A, const float* __restrict__ W,
    const float* __restrict__ bias, float* __restrict__ C,
    unsigned short* __restrict__ Cb) {
  constexpr int KB = 32;
  __shared__ float As[64][36];
  const int tid = threadIdx.x;
  const int s0 = blockIdx.x * 64;
  const int o0 = blockIdx.y * 64;
  const int ox = (tid & 15) * 4;
  const int sy = (tid >> 4) * 4;
  float acc[4][4] = {};
  const float* Abase = A + (long)s0 * K;
  for (int idx = tid; idx < 64 * KB; idx += 256) {
    int s = idx >> 5, c = idx & 31;
    As[s][c] = (c < K) ? Abase[(long)s * K + c] : 0.f;
  }
  __syncthreads();
  for (int kk = 0; kk < KB; kk += 4) {
    float a4[4][4];
    #pragma unroll
    for (int sj = 0; sj < 4; ++sj)
      *(float4*)a4[sj] = *(const float4*)&As[sy + sj][kk];
    #pragma unroll
    for (int oi = 0; oi < 4; ++oi) {
      float w4[4];
      #pragma unroll
      for (int kx = 0; kx < 4; ++kx) {
        int k = kk + kx;
        w4[kx] = (k < K) ? W[(long)(o0 + ox + oi) * K + k] : 0.f;
      }
      #pragma unroll
      for (int sj = 0; sj < 4; ++sj)
        #pragma unroll
        for (int kx = 0; kx < 4; ++kx)
          acc[sj][oi] = fmaf(a4[sj][kx], w4[kx], acc[sj][oi]);
    }
  }
  #pragma unroll
  for (int sj = 0; sj < 4; ++sj) {
    float4 o4;
    o4.x = acc[sj][0] + bias[o0 + ox + 0];
    o4.y = acc[sj][1] + bias[o0 + ox + 1];
    o4.z = acc[sj][2] + bias[o0 + ox + 2];
    o4.w = acc[sj][3] + bias[o0 + ox + 3];
    *(float4*)&C[(long)(s0 + sy + sj) * NOUT + o0 + ox] = o4;
    u16x4 b4; b4.x = f2bf(o4.x); b4.y = f2bf(o4.y); b4.z = f2bf(o4.z); b4.w = f2bf(o4.w);
    *(u16x4*)&Cb[(long)(s0 + sy + sj) * NOUT + o0 + ox] = b4;
  }
}

// ---- shared MFMA machinery ----
#define MM_PROLOG(GDX)                                                        \
  __shared__ __align__(16) unsigned short As[4096];                           \
  __shared__ __align__(16) unsigned short Ws[4096];                           \
  const int tid = threadIdx.x;                                                \
  const int pid = blockIdx.y * (GDX) + blockIdx.x;                            \
  const int bx = (pid >> 3) % (GDX);                                          \
  const int by = ((pid >> 3) / (GDX)) * 8 + (pid & 7);                        \
  const long s0 = (long)by * 128;                                             \
  const int wv = tid >> 6, l = tid & 63;                                      \
  const int wm = (wv >> 1) * 64, wn = (wv & 1) * 64;                          \
  const int lr = l & 15, lk = l >> 4;                                         \
  const int wrow = tid >> 2;                                                  \
  const int wslot = tid & 3;                                                  \
  (void)wrow; (void)wslot;                                                    \
  f32x4 acc[4][4] = {};

#define MM_MFMA_STEP                                                          \
  {                                                                           \
    bf16x8v af[4], bw[4];                                                     \
    _Pragma("unroll")                                                         \
    for (int m = 0; m < 4; ++m) {                                             \
      const int r = wm + m * 16 + lr;                                         \
      af[m] = *(const bf16x8v*)&As[r * 32 + ((lk ^ (r & 3)) * 8)];            \
    }                                                                         \
    _Pragma("unroll")                                                         \
    for (int n = 0; n < 4; ++n) {                                             \
      const int r = wn + n * 16 + lr;                                         \
      bw[n] = *(const bf16x8v*)&Ws[r * 32 + ((lk ^ (r & 3)) * 8)];            \
    }                                                                         \
    _Pragma("unroll")                                                         \
    for (int m = 0; m < 4; ++m)                                               \
      _Pragma("unroll")                                                       \
      for (int n = 0; n < 4; ++n)                                             \
        acc[m][n] = __builtin_amdgcn_mfma_f32_16x16x32_bf16(af[m], bw[n], acc[m][n], 0, 0, 0); \
  }

// ---------------- generic MFMA dense (f32 A, reg-staged) for heads OB ----------------
template<int K, int LDA, int NOUT, int GDX>
__global__ __launch_bounds__(256) void k_mm(
    const float* __restrict__ Aff, const unsigned short* __restrict__ W,
    const float* __restrict__ bias, float* __restrict__ C) {
  constexpr int NCH = K / 32;
  MM_PROLOG(GDX)
  const int o0 = bx * 128;
  const int q = wslot;
  u16x8 pw[2];
  float4 pa_f[2][2];
  const unsigned short* Wb = W + (long)o0 * K;
  #pragma unroll
  for (int p = 0; p < 2; ++p) {
    const int r = wrow + 64 * p;
    pw[p] = *(const u16x8*)(Wb + (long)r * K + wslot * 8);
    const float* Af = Aff + (s0 + r) * LDA + q * 4;
    pa_f[p][0] = *(const float4*)(Af);
    pa_f[p][1] = *(const float4*)(Af + 16);
  }
  for (int ch = 0; ch < NCH; ++ch) {
    if (ch) __syncthreads();
    #pragma unroll
    for (int p = 0; p < 2; ++p) {
      const int r = wrow + 64 * p;
      const int ps = (wslot ^ (r & 3)) * 8;
      *(u16x8*)&Ws[r * 32 + ps] = pw[p];
      #pragma unroll
      for (int j = 0; j < 2; ++j) {
        float4 v = pa_f[p][j];
        unsigned long long pk =
            (unsigned long long)f2bf(v.x) |
            ((unsigned long long)f2bf(v.y) << 16) |
            ((unsigned long long)f2bf(v.z) << 32) |
            ((unsigned long long)f2bf(v.w) << 48);
        const int slot = (j * 2 + (q >> 1)) ^ (r & 3);
        *(unsigned long long*)&As[r * 32 + slot * 8 + (q & 1) * 4] = pk;
      }
    }
    __syncthreads();
    if (ch + 1 < NCH) {
      const int k0 = (ch + 1) * 32;
      #pragma unroll
      for (int p = 0; p < 2; ++p) {
        const int r = wrow + 64 * p;
        pw[p] = *(const u16x8*)(Wb + (long)r * K + k0 + wslot * 8);
        const float* Af = Aff + (s0 + r) * LDA + k0 + q * 4;
        pa_f[p][0] = *(const float4*)(Af);
        pa_f[p][1] = *(const float4*)(Af + 16);
      }
    }
    MM_MFMA_STEP
  }
  #pragma unroll
  for (int n = 0; n < 4; ++n) {
    const float b = bias[o0 + wn + n * 16 + lr];
    #pragma unroll
    for (int m = 0; m < 4; ++m) {
      const long rowb = s0 + wm + m * 16 + lk * 4;
      #pragma unroll
      for (int r = 0; r < 4; ++r)
        C[(rowb + r) * (long)NOUT + o0 + wn + n * 16 + lr] = acc[m][n][r] + b;
    }
  }
}

// ---------------- merged qsrc GEMM (gl_lds staging): 1280 outs ----------------
__global__ __launch_bounds__(256) void k_mm_qs(
    const unsigned short* __restrict__ Abf, const unsigned short* __restrict__ W,
    const float* __restrict__ bias, float* __restrict__ Cg, float* __restrict__ Cgb) {
  MM_PROLOG(10)
  const int o0 = bx * 128;
  const int grow = l >> 2, gslot = l & 3;
  const unsigned short* Wb = W + (long)o0 * 256;
  for (int ch = 0; ch < 8; ++ch) {
    const int k0 = ch * 32;
    if (ch) __syncthreads();
    #pragma unroll
    for (int p = 0; p < 2; ++p) {
      const int rb = wv * 32 + p * 16;
      const int r = rb + grow;
      GLDS(Abf + (s0 + r) * 256 + k0 + ((gslot ^ (r & 3)) * 8), &As[rb * 32]);
      GLDS(Wb + (long)r * 256 + k0 + ((gslot ^ (r & 3)) * 8), &Ws[rb * 32]);
    }
    __syncthreads();
    MM_MFMA_STEP
  }
  float* C; int NOUT, ob;
  if (bx < 2) { C = Cg;  NOUT = 256;  ob = bx * 128; }
  else        { C = Cgb; NOUT = 1024; ob = (bx - 2) * 128; }
  #pragma unroll
  for (int n = 0; n < 4; ++n) {
    const float b = bias[o0 + wn + n * 16 + lr];
    #pragma unroll
    for (int m = 0; m < 4; ++m) {
      const long rowb = s0 + wm + m * 16 + lk * 4;
      #pragma unroll
      for (int r = 0; r < 4; ++r)
        C[(rowb + r) * (long)NOUT + ob + wn + n * 16 + lr] = acc[m][n][r] + b;
    }
  }
}

// ---------------- merged pal@PV GEMM (gl_lds staging, both branches, K=128) ----------------
__global__ __launch_bounds__(256) void k_mm_pv(
    const unsigned short* __restrict__ pal, const unsigned short* __restrict__ W,
    const float* __restrict__ bias, float* __restrict__ CA, float* __restrict__ CE) {
  MM_PROLOG(4)
  const int o0 = bx * 128;
  const int br = bx >> 1;
  const int grow = l >> 2, gslot = l & 3;
  const unsigned short* Abf = pal + br * 128;
  const unsigned short* Wb = W + (long)o0 * 128;
  for (int ch = 0; ch < 4; ++ch) {
    const int k0 = ch * 32;
    if (ch) __syncthreads();
    #pragma unroll
    for (int p = 0; p < 2; ++p) {
      const int rb = wv * 32 + p * 16;
      const int r = rb + grow;
      GLDS(Abf + (s0 + r) * 256 + k0 + ((gslot ^ (r & 3)) * 8), &As[rb * 32]);
      GLDS(Wb + (long)r * 128 + k0 + ((gslot ^ (r & 3)) * 8), &Ws[rb * 32]);
    }
    __syncthreads();
    MM_MFMA_STEP
  }
  float* C = br ? CE : CA;
  const int ob = (bx & 1) * 128;
  #pragma unroll
  for (int n = 0; n < 4; ++n) {
    const float b = bias[o0 + wn + n * 16 + lr];
    #pragma unroll
    for (int m = 0; m < 4; ++m) {
      const long rowb = s0 + wm + m * 16 + lk * 4;
      #pragma unroll
      for (int r = 0; r < 4; ++r)
        C[(rowb + r) * 256 + ob + wn + n * 16 + lr] = acc[m][n][r] + b;
    }
  }
}

// ---------------- GRU mega-GEMM v3: gl_lds staging, gate=fragment epilogue -> h ----------------
__global__ __launch_bounds__(256) void k_gru3(
    const unsigned short* __restrict__ UB, const float* __restrict__ hid,
    const unsigned short* __restrict__ WG, const float* __restrict__ BG,
    float* __restrict__ hout) {
  MM_PROLOG(8)
  const int grow = l >> 2, gslot = l & 3;
  const unsigned short* Wb = WG + (long)(bx * 128) * 1024;
  for (int ch = 0; ch < 32; ++ch) {
    const int k0 = ch * 32;
    if (ch) __syncthreads();
    #pragma unroll
    for (int p = 0; p < 2; ++p) {
      const int rb = wv * 32 + p * 16;
      const int r = rb + grow;
      GLDS(Wb + (long)r * 1024 + k0 + ((gslot ^ (r & 3)) * 8), &Ws[rb * 32]);
    }
    if (k0 < 768) {
      #pragma unroll
      for (int p = 0; p < 2; ++p) {
        const int rb = wv * 32 + p * 16;
        const int r = rb + grow;
        GLDS(UB + (s0 + r) * 768 + k0 + ((gslot ^ (r & 3)) * 8), &As[rb * 32]);
      }
    } else {
      const int km = k0 - 768;
      #pragma unroll
      for (int p = 0; p < 2; ++p) {
        const int r = wrow + 64 * p;
        const float* Af = hid + (s0 + r) * 256 + km + wslot * 4;
        float4 v0 = *(const float4*)(Af);
        float4 v1 = *(const float4*)(Af + 16);
        #pragma unroll
        for (int j = 0; j < 2; ++j) {
          float4 v = j ? v1 : v0;
          unsigned long long pk =
              (unsigned long long)f2bf(v.x) |
              ((unsigned long long)f2bf(v.y) << 16) |
              ((unsigned long long)f2bf(v.z) << 32) |
              ((unsigned long long)f2bf(v.w) << 48);
          const int slot = (j * 2 + (wslot >> 1)) ^ (r & 3);
          *(unsigned long long*)&As[r * 32 + slot * 8 + (wslot & 1) * 4] = pk;
        }
      }
    }
    __syncthreads();
    MM_MFMA_STEP
  }
  // epilogue: fragment n == gate
  const int colb = bx * 128 + wn;
  const int d = (bx >> 1) * 64 + (((bx & 1) << 1) | (wv & 1)) * 16 + lr;
  const float bR  = BG[colb + lr];
  const float bZ  = BG[colb + 16 + lr];
  const float bNi = BG[colb + 32 + lr];
  const float bNh = BG[colb + 48 + lr];
  #pragma unroll
  for (int m = 0; m < 4; ++m) {
    const long srow = s0 + wm + m * 16 + lk * 4;
    #pragma unroll
    for (int rr = 0; rr < 4; ++rr) {
      const long s = srow + rr;
      const float r_ = 1.f / (1.f + expf(-(acc[m][0][rr] + bR)));
      const float z_ = 1.f / (1.f + expf(-(acc[m][1][rr] + bZ)));
      const float n_ = tanhf(acc[m][2][rr] + bNi + r_ * (acc[m][3][rr] + bNh));
      const float hp = hid[s * 256 + d];
      hout[s * 256 + d] = (1.f - z_) * n_ + z_ * hp;
    }
  }
}

// ---------------- merged attention core ----------------
__global__ __launch_bounds__(256) void k_core2(
    const float* __restrict__ rawA, const float* __restrict__ rawE,
    const float* __restrict__ g, const float* __restrict__ gt_w,
    const float* __restrict__ gt_b, unsigned short* __restrict__ pal) {
  __shared__ float A_[4][15][36];
  __shared__ float E_[4][16][36];
  __shared__ float G_[4][8][32];
  __shared__ float P_[4][8][16];
  const int tid = threadIdx.x;
  const int w = tid >> 6, l = tid & 63;
  const long s = (long)blockIdx.x * 4 + w;

  const float* ra = rawA + s * 480;
  const float* re = rawE + s * 512;
  const float* gr = g + s * 256;
  #pragma unroll
  for (int i = l; i < 120; i += 64) {
    float4 v = *(const float4*)(ra + i * 4);
    *(float4*)&A_[w][i >> 3][(i & 7) * 4] = v;
  }
  #pragma unroll
  for (int i = l; i < 128; i += 64) {
    float4 v = *(const float4*)(re + i * 4);
    *(float4*)&E_[w][i >> 3][(i & 7) * 4] = v;
  }
  {
    float4 v = *(const float4*)(gr + l * 4);
    *(float4*)&G_[w][l >> 3][(l & 7) * 4] = v;
  }
  __syncthreads();

  bool mv = false;
  if (l < 15) {
    #pragma unroll
    for (int c = 0; c < 8; ++c) {
      float4 x = *(const float4*)&A_[w][l][c * 4];
      mv |= (x.x != 0.f) | (x.y != 0.f) | (x.z != 0.f) | (x.w != 0.f);
    }
  } else if (l >= 16 && l < 32) {
    #pragma unroll
    for (int c = 0; c < 8; ++c) {
      float4 x = *(const float4*)&E_[w][l - 16][c * 4];
      mv |= (x.x != 0.f) | (x.y != 0.f) | (x.z != 0.f) | (x.w != 0.f);
    }
  }
  unsigned long long bal = __ballot(mv);
  unsigned mA = (unsigned)bal & 0x7FFFu;
  unsigned mE = (unsigned)(bal >> 16) & 0xFFFFu;
  float xa = gt_w[0] * log1pf((float)__popc(mA)) + gt_b[0];
  float spa = fmaxf(xa, 0.f) + log1pf(expf(-fabsf(xa)));
  float scaleA = 1.f / (8.f * (spa + 1.f));
  float xe = gt_w[1] * log1pf((float)__popc(mE)) + gt_b[1];
  float spe = fmaxf(xe, 0.f) + log1pf(expf(-fabsf(xe)));
  float scaleE = 1.f / (8.f * (spe + 1.f));

  {
    const int h = l >> 4, n = l & 15;
    const bool okA = (n < 15) && ((mA >> n) & 1);
    const bool okE = (mE >> n) & 1;
    const float* arow = &A_[w][n < 15 ? n : 0][0];
    const float* erow = &E_[w][n][0];
    const float* garow = &G_[w][h][0];
    const float* gerow = &G_[w][4 + h][0];
    float accA = 0.f, accE = 0.f;
    #pragma unroll
    for (int j = 0; j < 32; ++j) {
      accA = fmaf(garow[j], arow[j], accA);
      accE = fmaf(gerow[j], erow[j], accE);
    }
    float sA = okA ? accA * scaleA : -INFINITY;
    float sE = okE ? accE * scaleE : -INFINITY;
    float mAx = sA, mEx = sE;
    #pragma unroll
    for (int off = 8; off; off >>= 1) {
      mAx = fmaxf(mAx, __shfl_xor(mAx, off));
      mEx = fmaxf(mEx, __shfl_xor(mEx, off));
    }
    float eA = okA ? expf(sA - mAx) : 0.f;
    float eE = okE ? expf(sE - mEx) : 0.f;
    float suA = eA, suE = eE;
    #pragma unroll
    for (int off = 8; off; off >>= 1) {
      suA += __shfl_xor(suA, off);
      suE += __shfl_xor(suE, off);
    }
    P_[w][h][n] = eA / suA;
    P_[w][4 + h][n] = eE / suE;
  }
  __syncthreads();

  {
    const int j = l & 31, hh = l >> 5;
    unsigned short* po = pal + s * 256 + hh * 32 + j;
    #pragma unroll
    for (int r = 0; r < 2; ++r) {
      const int ha = r * 2 + hh;
      float a0 = 0.f, a1 = 0.f;
      #pragma unroll
      for (int n = 0; n < 15; ++n)
        a0 = fmaf(P_[w][ha][n], A_[w][n][j], a0);
      #pragma unroll
      for (int n = 0; n < 16; ++n)
        a1 = fmaf(P_[w][4 + ha][n], E_[w][n][j], a1);
      po[r * 64] = f2bf(a0);
      po[128 + r * 64] = f2bf(a1);
    }
  }
}

// ---------------- fused CLN+CLN+LN3 -> u (bf16 out) ----------------
__global__ __launch_bounds__(256) void k_clnln(
    const float* __restrict__ aA, const float* __restrict__ aE,
    const float* __restrict__ qsrc, const float* __restrict__ gbu,
    const float* __restrict__ g, const float* __restrict__ b,
    unsigned short* __restrict__ UB) {
  int w = threadIdx.x >> 6, l = threadIdx.x & 63;
  long s = (long)blockIdx.x * 4 + w;
  int d = l * 4;
  float4 vA = *(const float4*)(aA + s * 256 + d);
  float4 vE = *(const float4*)(aE + s * 256 + d);
  float4 vq = *(const float4*)(qsrc + s * 256 + d);
  const float* gbr = gbu + s * 1024;
  float sumA = vA.x + vA.y + vA.z + vA.w;
  float ssqA = vA.x*vA.x + vA.y*vA.y + vA.z*vA.z + vA.w*vA.w;
  float sumE = vE.x + vE.y + vE.z + vE.w;
  float ssqE = vE.x*vE.x + vE.y*vE.y + vE.z*vE.z + vE.w*vE.w;
  #pragma unroll
  for (int off = 32; off > 0; off >>= 1) {
    sumA += __shfl_xor(sumA, off); ssqA += __shfl_xor(ssqA, off);
    sumE += __shfl_xor(sumE, off); ssqE += __shfl_xor(ssqE, off);
  }
  float muA = sumA * (1.f / 256.f);
  float rstdA = rsqrtf(ssqA * (1.f / 256.f) - muA * muA + 1e-5f);
  float muE = sumE * (1.f / 256.f);
  float rstdE = rsqrtf(ssqE * (1.f / 256.f) - muE * muE + 1e-5f);

  float4 gA4 = *(const float4*)(gbr + d);
  float4 bA4 = *(const float4*)(gbr + 256 + d);
  float4 gE4 = *(const float4*)(gbr + 512 + d);
  float4 bE4 = *(const float4*)(gbr + 768 + d);
  float4 zA, zE;
  zA.x = (1.f + gA4.x) * ((vA.x - muA) * rstdA) + bA4.x;
  zA.y = (1.f + gA4.y) * ((vA.y - muA) * rstdA) + bA4.y;
  zA.z = (1.f + gA4.z) * ((vA.z - muA) * rstdA) + bA4.z;
  zA.w = (1.f + gA4.w) * ((vA.w - muA) * rstdA) + bA4.w;
  zE.x = (1.f + gE4.x) * ((vE.x - muE) * rstdE) + bE4.x;
  zE.y = (1.f + gE4.y) * ((vE.y - muE) * rstdE) + bE4.y;
  zE.z = (1.f + gE4.z) * ((vE.z - muE) * rstdE) + bE4.z;
  zE.w = (1.f + gE4.w) * ((vE.w - muE) * rstdE) + bE4.w;

  float sum = vq.x+vq.y+vq.z+vq.w + zA.x+zA.y+zA.z+zA.w + zE.x+zE.y+zE.z+zE.w;
  float ssq = vq.x*vq.x+vq.y*vq.y+vq.z*vq.z+vq.w*vq.w
            + zA.x*zA.x+zA.y*zA.y+zA.z*zA.z+zA.w*zA.w
            + zE.x*zE.x+zE.y*zE.y+zE.z*zE.z+zE.w*zE.w;
  #pragma unroll
  for (int off = 32; off > 0; off >>= 1) {
    sum += __shfl_xor(sum, off); ssq += __shfl_xor(ssq, off);
  }
  float mu = sum * (1.f / 768.f);
  float rstd = rsqrtf(ssq * (1.f / 768.f) - mu * mu + 1e-5f);

  float4 g0 = *(const float4*)(g + d),       b0 = *(const float4*)(b + d);
  float4 g1 = *(const float4*)(g + 256 + d), b1 = *(const float4*)(b + 256 + d);
  float4 g2 = *(const float4*)(g + 512 + d), b2 = *(const float4*)(b + 512 + d);
  unsigned short* ur = UB + s * 768;
  u16x4 o;
  o.x = f2bf((vq.x - mu) * rstd * g0.x + b0.x);
  o.y = f2bf((vq.y - mu) * rstd * g0.y + b0.y);
  o.z = f2bf((vq.z - mu) * rstd * g0.z + b0.z);
  o.w = f2bf((vq.w - mu) * rstd * g0.w + b0.w);
  *(u16x4*)&ur[d] = o;
  o.x = f2bf((zA.x - mu) * rstd * g1.x + b1.x);
  o.y = f2bf((zA.y - mu) * rstd * g1.y + b1.y);
  o.z = f2bf((zA.z - mu) * rstd * g1.z + b1.z);
  o.w = f2bf((zA.w - mu) * rstd * g1.w + b1.w);
  *(u16x4*)&ur[256 + d] = o;
  o.x = f2bf((zE.x - mu) * rstd * g2.x + b2.x);
  o.y = f2bf((zE.y - mu) * rstd * g2.y + b2.y);
  o.z = f2bf((zE.z - mu) * rstd * g2.z + b2.z);
  o.w = f2bf((zE.w - mu) * rstd * g2.w + b2.w);
  *(u16x4*)&ur[512 + d] = o;
}

// ---------------- heads epilogue ----------------
__global__ __launch_bounds__(256) void k_heads2(
    const float* __restrict__ OB, const float* __restrict__ eraw,
    const float* __restrict__ log_tau, float* __restrict__ Qout) {
  __shared__ float obs[16][48];
  const int tid = threadIdx.x;
  const long s0 = (long)blockIdx.x * 16;
  for (int idx = tid; idx < 768; idx += 256)
    obs[idx / 48][idx % 48] = OB[(s0 + idx / 48) * 128 + idx % 48];
  __syncthreads();
  const int w = tid >> 4, i = tid & 15;
  const long s = s0 + w;
  const float itm = 1.f / (expf(log_tau[0]) + 1e-6f);
  const float its = 1.f / (expf(log_tau[1]) + 1e-6f);
  const float V = obs[w][0];
  const float* er = eraw + s * 512 + i * 32;
  bool valid = false; float acc = 0.f;
  #pragma unroll
  for (int jb = 0; jb < 8; ++jb) {
    float4 e4 = *(const float4*)(er + jb * 4);
    valid |= (e4.x != 0.f) | (e4.y != 0.f) | (e4.z != 0.f) | (e4.w != 0.f);
    acc += obs[w][9 + jb * 4 + 0] * e4.x + obs[w][9 + jb * 4 + 1] * e4.y +
           obs[w][9 + jb * 4 + 2] * e4.z + obs[w][9 + jb * 4 + 3] * e4.w;
  }
  float a = (acc + obs[w][41]) * 0.0625f;
  float sa = valid ? a : 0.f;
  float cv = valid ? 1.f : 0.f;
  #pragma unroll
  for (int off = 8; off > 0; off >>= 1) {
    sa += __shfl_xor(sa, off);
    cv += __shfl_xor(cv, off);
  }
  float me = sa / fmaxf(cv, 1.f);
  Qout[s * 22 + 6 + i] = V + obs[w][2] + (valid ? (a - me) * its : -1e30f * its);
  if (i < 6) {
    float mean = 0.f;
    #pragma unroll
    for (int t = 0; t < 6; ++t) mean += obs[w][3 + t];
    mean *= (1.f / 6.f);
    Qout[s * 22 + i] = V + obs[w][1] + (obs[w][3 + i] - mean) * 0.0625f * itm;
  }
}

// ---------------- launch ----------------
extern "C" void kernel_launch(void* const* d_in, const int* in_sizes, int n_in,
                              void* d_out, int out_size, void* d_ws, size_t ws_size,
                              hipStream_t stream) {
  const float* own_raw   = (const float*)d_in[0];
  const float* ally_raw  = (const float*)d_in[1];
  const float* enemy_raw = (const float*)d_in[2];
  const float* hidden    = (const float*)d_in[3];
  const float* W_own     = (const float*)d_in[4];
  const float* b_own     = (const float*)d_in[5];
  const float* W_ally    = (const float*)d_in[6];
  const float* b_ally    = (const float*)d_in[7];
  const float* W_enemy   = (const float*)d_in[8];
  const float* b_enemy   = (const float*)d_in[9];
  const float* gt_w      = (const float*)d_in[10];
  const float* gt_b      = (const float*)d_in[11];
  const float* attnA_W   = (const float*)d_in[12];
  const float* attnA_b   = (const float*)d_in[13];
  const float* attnE_W   = (const float*)d_in[14];
  const float* attnE_b   = (const float*)d_in[15];
  const float* clnA_W    = (const float*)d_in[16];
  const float* clnA_b    = (const float*)d_in[17];
  const float* clnE_W    = (const float*)d_in[18];
  const float* clnE_b    = (const float*)d_in[19];
  const float* ln3_g     = (const float*)d_in[20];
  const float* ln3_b     = (const float*)d_in[21];
  const float* gru_Wih   = (const float*)d_in[22];
  const float* gru_Whh   = (const float*)d_in[23];
  const float* gru_bih   = (const float*)d_in[24];
  const float* gru_bhh   = (const float*)d_in[25];
  const float* Wv_head   = (const float*)d_in[26];
  const float* bv_head   = (const float*)d_in[27];
  const float* Wtb       = (const float*)d_in[28];
  const float* btb       = (const float*)d_in[29];
  const float* log_tau   = (const float*)d_in[30];
  const float* Wmq       = (const float*)d_in[31];
  const float* bmq       = (const float*)d_in[32];
  const float* protos    = (const float*)d_in[33];
  const float* Wqs       = (const float*)d_in[34];
  const float* bqs       = (const float*)d_in[35];
  const float* Wke       = (const float*)d_in[36];
  const float* bke       = (const float*)d_in[37];

  float* ws  = (float*)d_ws;
  float* out = (float*)d_out;
  float* hout = out + HOFF;
  unsigned short* WB   = (unsigned short*)hout;
  unsigned short* qsb  = (unsigned short*)(ws + BUF2_OFF);
  unsigned short* palb = (unsigned short*)(ws + BUF2_OFF);
  unsigned short* WHD  = (unsigned short*)ws;
  unsigned short* wgru = (unsigned short*)(ws + BUF1_OFF);
  unsigned short* ub   = (unsigned short*)(ws + UB_OFF);

  k_fuseA<<<416, 256, 0, stream>>>(attnA_W, attnA_b, attnE_W, attnE_b,
                                   W_ally, b_ally, W_enemy, b_enemy, Wke, bke,
                                   clnA_W, clnE_W, ws, WB);
  k_fuseB<<<559, 256, 0, stream>>>(protos, Wmq, bmq, Wqs, bqs,
                                   attnA_W, attnA_b, attnE_W, attnE_b,
                                   clnA_b, clnE_b, ws, WB);
  k_fuse4<<<129, 256, 0, stream>>>(Wv_head, bv_head, Wtb, btb, ws, WHD);

  // q_src (f32 + bf16)
  k_densek<30, 256><<<dim3(BN/64, 4), 256, 0, stream>>>(own_raw, W_own, b_own,
                                                        ws + QSRC_OFF, qsb);

  // merged: g (256) + cln gamma/beta (1024)
  k_mm_qs<<<dim3(10, 128), 256, 0, stream>>>(qsb, WB, ws + BMG_OFF,
                                             ws + GBUF_OFF, ws + GB_OFF);

  // merged attention core -> pal (bf16)
  k_core2<<<BN/4, 256, 0, stream>>>(ally_raw, enemy_raw, ws + GBUF_OFF,
                                    gt_w, gt_b, palb);

  // GRU folded weights (into BUF1, now dead) + bias
  k_gruw<<<1028, 256, 0, stream>>>(gru_Wih, gru_Whh, gru_bih, gru_bhh,
                                   wgru, ws + BGRU_OFF);

  // aout = pal @ PV + bpj (both branches)
  k_mm_pv<<<dim3(4, 128), 256, 0, stream>>>(palb, WB + PJA_S, ws + BPJA_OFF,
                                            ws + AOUTA_OFF, ws + AOUTE_OFF);

  // fused cln+cln+ln3 -> u bf16
  k_clnln<<<BN/4, 256, 0, stream>>>(ws + AOUTA_OFF, ws + AOUTE_OFF, ws + QSRC_OFF,
                                    ws + GB_OFF, ln3_g, ln3_b, ub);

  // GRU mega-GEMM v3 -> h
  k_gru3<<<dim3(8, 128), 256, 0, stream>>>(ub, hidden, wgru, ws + BGRU_OFF, hout);

  // heads: OB = h @ WHD.T, then epilogue
  k_mm<256, 256, 128, 1><<<dim3(1, 128), 256, 0, stream>>>(hout, WHD, ws + BHD_OFF, ws + OB_OFF);
  k_heads2<<<BN/16, 256, 0, stream>>>(ws + OB_OFF, enemy_raw, log_tau, out);
}